// Round 5
// baseline (3185.099 us; speedup 1.0000x reference)
//
#include <hip/hip_runtime.h>
#include <hip/hip_bf16.h>
#include <math.h>

typedef __hip_bfloat16 bf16;

#define Tt 2048
#define Dd 1024
#define Hh 16

__device__ __forceinline__ float b2f(bf16 v){ return __bfloat162float(v); }
__device__ __forceinline__ bf16  f2b(float v){ return __float2bfloat16(v); }

__device__ __forceinline__ int seg_t(int lr, int t0, int Lm1){ return t0 + (lr & Lm1); }
__device__ __forceinline__ size_t seg_grow(int lr, int b0, int t0, int Llog2, int Lm1){
  return ((size_t)(b0 + (lr >> Llog2)) * Tt) + (size_t)seg_t(lr, t0, Lm1);
}

// ---------------------------------------------------------------- dtype detect
// Interpret first 8192 16-bit slots of raw x as bf16: exponent >= 0xC0 (|v|>=2^65)
// never occurs in genuine bf16 activations; occurs ~25% per slot if data is f32.
__global__ __launch_bounds__(256) void k_detect(const unsigned short* __restrict__ xs,
                                                int* __restrict__ flag){
  __shared__ int bad;
  if(threadIdx.x == 0) bad = 0;
  __syncthreads();
  int local = 0;
  for(int i = threadIdx.x; i < 8192; i += 256){
    unsigned e = (xs[i] >> 7) & 0xFF;
    if(e >= 0xC0) local++;
  }
  if(local) atomicAdd(&bad, local);
  __syncthreads();
  if(threadIdx.x == 0) flag[0] = (bad > 16) ? 1 : 0;   // 1 = inputs are float32
}

// ---------------------------------------------------------------- canonicalize to bf16
__global__ __launch_bounds__(256) void k_conv(const void* __restrict__ src,
                                              bf16* __restrict__ dst, int n,
                                              const int* __restrict__ flag){
  int i = blockIdx.x * 256 + threadIdx.x;
  if(i >= n) return;
  if(flag[0]) dst[i] = f2b(((const float*)src)[i]);
  else        dst[i] = ((const bf16*)src)[i];
}

// ---------------------------------------------------------------- GEMM
constexpr int EPI_BF16 = 0, EPI_TANH = 1, EPI_SILU = 2, EPI_MIX = 3, EPI_DECAY = 4;
#define BM 64
#define BN 64
#define BK 16

template<int EPI, bool AFUSE, bool CGLOBAL>
__global__ __launch_bounds__(256) void gemm_ep(
    const bf16* __restrict__ A, int lda,
    const bf16* __restrict__ Bm, int ldb,
    void* __restrict__ Cv, int ldc,
    int Mdim, int Ndim, int Kdim,
    const bf16* __restrict__ xg, const bf16* __restrict__ e_w,
    int b0, int t0, int Llog2, const int* __restrict__ oflag){
  const int Lm1 = (1 << Llog2) - 1;
  __shared__ float As[BM][BK + 1];
  __shared__ float Bs[BK][BN + 4];
  int tid = threadIdx.x;
  int tx = tid & 15, ty = tid >> 4;
  int bm = blockIdx.y * BM, bn = blockIdx.x * BN;
  float acc[4][4] = {};
  for(int kb = 0; kb < Kdim; kb += BK){
    {
      int lr = tid >> 2;
      int lc = (tid & 3) * 4;
      int gr = bm + lr;
      #pragma unroll
      for(int q = 0; q < 4; q++){
        int gc = kb + lc + q;
        float av = 0.f;
        if(gr < Mdim && gc < Kdim){
          if constexpr(AFUSE){
            size_t grow = seg_grow(gr, b0, t0, Llog2, Lm1);
            int tl = seg_t(gr, t0, Lm1);
            float xc = b2f(xg[grow * Dd + gc]);
            float xp = tl ? b2f(xg[(grow - 1) * Dd + gc]) : 0.f;
            av = xc + (xp - xc) * b2f(e_w[gc]);
          } else {
            av = b2f(A[(size_t)gr * lda + gc]);
          }
        }
        As[lr][lc + q] = av;
      }
    }
    {
      int lr = tid >> 4;
      int lc = (tid & 15) * 4;
      #pragma unroll
      for(int q = 0; q < 4; q++){
        int gr = kb + lr; int gc = bn + lc + q;
        Bs[lr][lc + q] = (gr < Kdim && gc < Ndim) ? b2f(Bm[(size_t)gr * ldb + gc]) : 0.f;
      }
    }
    __syncthreads();
    #pragma unroll
    for(int kk = 0; kk < BK; kk++){
      float ar[4], br[4];
      #pragma unroll
      for(int q = 0; q < 4; q++) ar[q] = As[ty * 4 + q][kk];
      #pragma unroll
      for(int q = 0; q < 4; q++) br[q] = Bs[kk][tx * 4 + q];
      #pragma unroll
      for(int mi = 0; mi < 4; mi++)
        #pragma unroll
        for(int ni = 0; ni < 4; ni++)
          acc[mi][ni] += ar[mi] * br[ni];
    }
    __syncthreads();
  }
  #pragma unroll
  for(int mi = 0; mi < 4; mi++){
    int row = bm + ty * 4 + mi;
    if(row >= Mdim) continue;
    #pragma unroll
    for(int ni = 0; ni < 4; ni++){
      int col = bn + tx * 4 + ni;
      if(col >= Ndim) continue;
      float vacc = acc[mi][ni];
      size_t off = (size_t)row * ldc + col;
      if constexpr(EPI == EPI_BF16){
        if constexpr(CGLOBAL){
          size_t grow = seg_grow(row, b0, t0, Llog2, Lm1);
          if(oflag[0]) ((float*)Cv)[grow * Dd + col] = vacc;
          else         ((bf16*)Cv)[grow * Dd + col] = f2b(vacc);
        } else {
          ((bf16*)Cv)[off] = f2b(vacc);
        }
      } else if constexpr(EPI == EPI_TANH){
        ((bf16*)Cv)[off] = f2b(tanhf(vacc));
      } else if constexpr(EPI == EPI_SILU){
        ((bf16*)Cv)[off] = f2b(vacc / (1.f + expf(-vacc)));
      } else if constexpr(EPI == EPI_MIX){
        size_t grow = seg_grow(row, b0, t0, Llog2, Lm1);
        int tl = seg_t(row, t0, Lm1);
        float xc = b2f(xg[grow * Dd + col]);
        float xp = tl ? b2f(xg[(grow - 1) * Dd + col]) : 0.f;
        ((bf16*)Cv)[off] = f2b(xc + (xp - xc) * (b2f(e_w[col]) + vacc));
      } else { // EPI_DECAY
        float td = b2f(e_w[col]) + vacc;
        ((float*)Cv)[off] = fmaxf(-expf(td), -5.2983173665480363f);
      }
    }
  }
}

// ---------------------------------------------------------------- cumsum (in place wlog->wcum) + wse
__global__ __launch_bounds__(256) void k_cumsum(float* __restrict__ wd,
                                                float* __restrict__ wse,
                                                int nlog2){
  int blk = blockIdx.x;
  int dg = blk & 3; int rest = blk >> 2;
  int nmask = (1 << nlog2) - 1;
  int ln = rest & nmask; int bp = rest >> nlog2;
  int d = dg * 256 + threadIdx.x;
  size_t rowbase = (((size_t)bp << nlog2) + ln) * 128;
  size_t base = rowbase * Dd + d;
  float c = 0.f;
  for(int t = 0; t < 128; t++){
    size_t ix = base + (size_t)t * Dd;
    c += wd[ix];
    wd[ix] = c;
  }
  int h = d >> 6, k0 = d & 63;
  wse[((((size_t)bp * Hh + h) << nlog2) | ln) * 64 + k0] = __expf(fminf(c, 0.f));
}

// ---------------------------------------------------------------- chunk1: wkv = (k*exp(ws-cum))^T @ v
__global__ __launch_bounds__(256) void k_chunk1(const bf16* __restrict__ kb,
                                                const bf16* __restrict__ vb,
                                                const float* __restrict__ wcum,
                                                float* __restrict__ wkv,
                                                int nlog2){
  __shared__ __align__(16) char smem[65536];
  bf16*  kt = (bf16*)smem;
  bf16*  vt = (bf16*)(smem + 16384);
  float* cs = (float*)(smem + 32768);
  int tid = threadIdx.x, blk = blockIdx.x;
  int nmask = (1 << nlog2) - 1;
  int ln = blk & nmask; int rest = blk >> nlog2;
  int h = rest & 15; int bp = rest >> 4;
  size_t rowbase = (((size_t)bp << nlog2) + ln) * 128;
  size_t gbase = rowbase * Dd + h * 64;
  for(int r = 0; r < 32; r++){
    int idx = r * 256 + tid;
    int t0 = idx >> 6, k0 = idx & 63;
    size_t gi = gbase + (size_t)t0 * Dd + k0;
    kt[idx] = kb[gi];
    vt[idx] = vb[gi];
    cs[idx] = wcum[gi];
  }
  __syncthreads();
  for(int r = 0; r < 32; r++){
    int idx = r * 256 + tid;
    int k0 = idx & 63;
    kt[idx] = f2b(b2f(kt[idx]) * __expf(fminf(cs[127 * 64 + k0] - cs[idx], 0.f)));
  }
  __syncthreads();
  int tx = tid & 15, ty = tid >> 4;
  float acc[4][4] = {};
  for(int t = 0; t < 128; t++){
    float kr[4], vr[4];
    #pragma unroll
    for(int q = 0; q < 4; q++) kr[q] = b2f(kt[t * 64 + ty * 4 + q]);
    #pragma unroll
    for(int q = 0; q < 4; q++) vr[q] = b2f(vt[t * 64 + tx * 4 + q]);
    #pragma unroll
    for(int i2 = 0; i2 < 4; i2++)
      #pragma unroll
      for(int j2 = 0; j2 < 4; j2++)
        acc[i2][j2] += kr[i2] * vr[j2];
  }
  size_t obase = (size_t)blk * 4096;
  #pragma unroll
  for(int i2 = 0; i2 < 4; i2++)
    #pragma unroll
    for(int j2 = 0; j2 < 4; j2++)
      wkv[obase + (ty * 4 + i2) * 64 + tx * 4 + j2] = acc[i2][j2];
}

// ---------------------------------------------------------------- state scan (wkv -> states, separate buffers)
__global__ __launch_bounds__(256) void k_scan(const float* __restrict__ wkv,
                                              float* __restrict__ states,
                                              const float* __restrict__ wse,
                                              float* __restrict__ st,
                                              int b0, int firstseg, int nlog2){
  int blk = blockIdx.x;                // nb*16: (bp, h)
  int h = blk & 15, bp = blk >> 4;
  int tid = threadIdx.x;
  size_t stbase = ((size_t)(b0 + bp) * Hh + h) * 4096;
  int nloc = 1 << nlog2;
  float s[16];
  #pragma unroll
  for(int r = 0; r < 16; r++)
    s[r] = firstseg ? 0.f : st[stbase + r * 256 + tid];
  for(int ln = 0; ln < nloc; ln++){
    size_t idx = (((size_t)bp * Hh + h) << nlog2) | ln;
    size_t base = idx * 4096;
    const float* wsp = wse + idx * 64;
    #pragma unroll
    for(int r = 0; r < 16; r++){
      int e = r * 256 + tid;
      states[base + e] = s[r];
      s[r] = s[r] * wsp[e >> 6] + wkv[base + e];
    }
  }
  #pragma unroll
  for(int r = 0; r < 16; r++)
    st[stbase + r * 256 + tid] = s[r];
}

// ---------------------------------------------------------------- chunk2: intra attention + state term
__global__ __launch_bounds__(256) void k_chunk2(
    const bf16* __restrict__ rb, const bf16* __restrict__ kb,
    const bf16* __restrict__ vb, const float* __restrict__ wcum,
    const float* __restrict__ states, const bf16* __restrict__ u,
    float* __restrict__ outw, int nlog2){
  __shared__ __align__(16) char smem[65536];
  bf16*  kt = (bf16*)smem;
  bf16*  rt = (bf16*)(smem + 16384);
  float* cs = (float*)(smem + 32768);
  int tid = threadIdx.x, blk = blockIdx.x;
  int nmask = (1 << nlog2) - 1;
  int ln = blk & nmask; int rest = blk >> nlog2;
  int h = rest & 15; int bp = rest >> 4;
  size_t rowbase = (((size_t)bp << nlog2) + ln) * 128;
  size_t gbase = rowbase * Dd + h * 64;
  for(int r = 0; r < 32; r++){
    int idx = r * 256 + tid;
    int t0 = idx >> 6, k0 = idx & 63;
    size_t gi = gbase + (size_t)t0 * Dd + k0;
    kt[idx] = kb[gi];
    rt[idx] = rb[gi];
    cs[idx] = wcum[gi];
  }
  __syncthreads();
  int i = tid >> 1, hf = tid & 1;
  float rwreg[32];
  #pragma unroll
  for(int k2 = 0; k2 < 32; k2++){
    int kk = hf * 32 + k2;
    float cp = i ? cs[(i - 1) * 64 + kk] : 0.f;
    rwreg[k2] = b2f(rt[i * 64 + kk]) * __expf(fminf(cp, 0.f));
  }
  float a[64];
  {
    const float* ci = (i > 0) ? &cs[(i - 1) * 64] : cs;
    const bf16*  ri = &rt[i * 64];
    for(int j = 0; j < 64; j++){
      int jj = hf * 64 + j;
      float s = 0.f;
      if(jj < i){
        const bf16*  kj = &kt[jj * 64];
        const float* cj = &cs[jj * 64];
        for(int k = 0; k < 64; k++)
          s += b2f(ri[k]) * b2f(kj[k]) * __expf(fminf(ci[k] - cj[k], 0.f));
      } else if(jj == i){
        const bf16* kj = &kt[i * 64];
        for(int k = 0; k < 64; k++)
          s += b2f(ri[k]) * b2f(u[h * 64 + k]) * b2f(kj[k]);
      }
      a[j] = s;
    }
  }
  __syncthreads();
  bf16*  vt  = (bf16*)smem;            // over kt
  float* ssm = (float*)(smem + 16384); // over rt
  for(int r = 0; r < 32; r++){
    int idx = r * 256 + tid;
    int t0 = idx >> 6, k0 = idx & 63;
    vt[idx] = vb[gbase + (size_t)t0 * Dd + k0];
  }
  for(int r = 0; r < 16; r++){
    int idx = r * 256 + tid;
    ssm[idx] = states[(size_t)blk * 4096 + idx];
  }
  __syncthreads();
  for(int v = 0; v < 64; v++){
    float p = 0.f;
    #pragma unroll
    for(int j = 0; j < 64; j++)
      p += a[j] * b2f(vt[(hf * 64 + j) * 64 + v]);
    #pragma unroll
    for(int k2 = 0; k2 < 32; k2++)
      p += rwreg[k2] * ssm[(hf * 32 + k2) * 64 + v];
    float tot = p + __shfl_xor(p, 1);
    if(hf == 0) outw[gbase + (size_t)i * Dd + v] = tot;
  }
}

// ---------------------------------------------------------------- groupnorm(64) + gate
__global__ __launch_bounds__(256) void k_norm(const float* __restrict__ outw,
                                              const bf16* __restrict__ gb,
                                              const bf16* __restrict__ lnw,
                                              const bf16* __restrict__ lnb,
                                              bf16* __restrict__ gated){
  int lr = blockIdx.x;
  int wv = threadIdx.x >> 6, lane = threadIdx.x & 63;
  for(int hh = wv; hh < Hh; hh += 4){
    size_t ix = (size_t)lr * Dd + hh * 64 + lane;
    float xv = outw[ix];
    float s1 = xv, s2 = xv * xv;
    #pragma unroll
    for(int off = 32; off > 0; off >>= 1){
      s1 += __shfl_xor(s1, off);
      s2 += __shfl_xor(s2, off);
    }
    float mu  = s1 * 0.015625f;
    float var = s2 * 0.015625f - mu * mu;
    float inv = rsqrtf(var + 6.4e-4f);
    float og  = (xv - mu) * inv * b2f(lnw[hh * 64 + lane]) + b2f(lnb[hh * 64 + lane]);
    gated[ix] = f2b(og * b2f(gb[ix]));
  }
}

// ---------------------------------------------------------------- host
extern "C" void kernel_launch(void* const* d_in, const int* in_sizes, int n_in,
                              void* d_out, int out_size, void* d_ws, size_t ws_size,
                              hipStream_t stream){
  char* W = (char*)d_ws;
  size_t cur = 0;
  auto carve = [&](size_t bytes) -> char* {
    char* p = W + cur;
    cur = (cur + bytes + 255) & ~(size_t)255;
    return p;
  };

  // ---- flag + canonical bf16 copies of all inputs
  int* flag = (int*)carve(4096);
  static const int NEL[20] = {8388608, 1024, 1024, 1024, 1024, 1024, 1024,
                              163840, 163840, 1024, 65536, 65536, 1024,
                              1048576, 1048576, 1048576, 1048576, 1048576,
                              1024, 1024};
  bf16* canon[20];
  for(int i = 0; i < 20; i++) canon[i] = (bf16*)carve((size_t)NEL[i] * 2);

  k_detect<<<dim3(1), 256, 0, stream>>>((const unsigned short*)d_in[0], flag);
  for(int i = 0; i < 20; i++)
    k_conv<<<dim3((NEL[i] + 255) / 256), 256, 0, stream>>>(d_in[i], canon[i], NEL[i], flag);

  const bf16* xp   = canon[0];
  const bf16* tmx  = canon[1];
  const bf16* maas[5] = {canon[2], canon[3], canon[4], canon[5], canon[6]};
  const bf16* w1p  = canon[7];
  const bf16* w2p  = canon[8];
  const bf16* tdec = canon[9];
  const bf16* dw1  = canon[10];
  const bf16* dw2  = canon[11];
  const bf16* up   = canon[12];
  const bf16* Wr   = canon[13];
  const bf16* Wk   = canon[14];
  const bf16* Wv   = canon[15];
  const bf16* Wg   = canon[16];
  const bf16* Wo   = canon[17];
  const bf16* lnwp = canon[18];
  const bf16* lnbp = canon[19];

  float* st = (float*)carve(1u << 20);   // WKV carry state, persists across segments
  size_t FIXED = cur;

  // ---- adaptive segmenting, NO aliases: 25,056 B/row + ~64 KB carve padding
  const size_t UNIT = 25056, PAD = 65536;
  int nb, L;
  if(ws_size >= FIXED + (size_t)8192 * UNIT + PAD){ nb = 4; L = 2048; }
  else {
    nb = 1; L = 2048;
    while(L > 128 && ws_size < FIXED + (size_t)L * UNIT + PAD) L >>= 1;
  }
  const int Llog2 = __builtin_ctz((unsigned)L);
  const int nlog2 = Llog2 - 7;
  const int M     = nb * L;
  const size_t Mr = (size_t)M;

  bf16*  xxx    = (bf16*) carve(Mr * 320);
  bf16*  ww1    = (bf16*) carve(Mr * 128);
  float* wse    = (float*)carve(Mr * 32);
  bf16*  mix    = (bf16*) carve(Mr * 2048);
  bf16*  kbuf   = (bf16*) carve(Mr * 2048);
  bf16*  vbuf   = (bf16*) carve(Mr * 2048);
  bf16*  rbuf   = (bf16*) carve(Mr * 2048);
  bf16*  gbuf   = (bf16*) carve(Mr * 2048);
  float* wdec   = (float*)carve(Mr * 4096);
  float* wkv    = (float*)carve(Mr * 2048);
  float* states = (float*)carve(Mr * 2048);
  float* outw   = (float*)carve(Mr * 4096);
  bf16*  gated  = (bf16*) carve(Mr * 2048);

  for(int b0 = 0; b0 < 4; b0 += nb){
    for(int t0 = 0; t0 < Tt; t0 += L){
      // 1. xxx = tanh( (x + (shift-x)*tmx) @ w1 )
      gemm_ep<EPI_TANH, true, false><<<dim3(3, M/64), 256, 0, stream>>>(
          xp, Dd, w1p, 160, xxx, 160, M, 160, Dd, xp, tmx, b0, t0, Llog2, flag);
      // 2. per-channel mix -> consumer; c order: w,k,v,r,g
      for(int c = 0; c < 5; c++){
        gemm_ep<EPI_MIX, false, false><<<dim3(16, M/64), 256, 0, stream>>>(
            xxx + c * 32, 160, w2p + (size_t)c * 32 * 1024, 1024,
            mix, 1024, M, 1024, 32, xp, maas[c], b0, t0, Llog2, flag);
        if(c == 0){
          gemm_ep<EPI_TANH, false, false><<<dim3(1, M/64), 256, 0, stream>>>(
              mix, 1024, dw1, 64, ww1, 64, M, 64, 1024, nullptr, nullptr, 0, 0, Llog2, flag);
          gemm_ep<EPI_DECAY, false, false><<<dim3(16, M/64), 256, 0, stream>>>(
              ww1, 64, dw2, 1024, wdec, 1024, M, 1024, 64, nullptr, tdec, 0, 0, Llog2, flag);
        } else if(c == 1){
          gemm_ep<EPI_BF16, false, false><<<dim3(16, M/64), 256, 0, stream>>>(
              mix, 1024, Wk, 1024, kbuf, 1024, M, 1024, 1024, nullptr, nullptr, 0, 0, Llog2, flag);
        } else if(c == 2){
          gemm_ep<EPI_BF16, false, false><<<dim3(16, M/64), 256, 0, stream>>>(
              mix, 1024, Wv, 1024, vbuf, 1024, M, 1024, 1024, nullptr, nullptr, 0, 0, Llog2, flag);
        } else if(c == 3){
          gemm_ep<EPI_BF16, false, false><<<dim3(16, M/64), 256, 0, stream>>>(
              mix, 1024, Wr, 1024, rbuf, 1024, M, 1024, 1024, nullptr, nullptr, 0, 0, Llog2, flag);
        } else {
          gemm_ep<EPI_SILU, false, false><<<dim3(16, M/64), 256, 0, stream>>>(
              mix, 1024, Wg, 1024, gbuf, 1024, M, 1024, 1024, nullptr, nullptr, 0, 0, Llog2, flag);
        }
      }
      // 3. chunked WKV (segment-local, carry in st)
      int nloc = 1 << nlog2;
      k_cumsum<<<dim3(nb * nloc * 4), 256, 0, stream>>>(wdec, wse, nlog2);
      k_chunk1<<<dim3(nb * 16 * nloc), 256, 0, stream>>>(kbuf, vbuf, wdec, wkv, nlog2);
      k_scan<<<dim3(nb * 16), 256, 0, stream>>>(wkv, states, wse, st, b0, (t0 == 0) ? 1 : 0, nlog2);
      k_chunk2<<<dim3(nb * 16 * nloc), 256, 0, stream>>>(rbuf, kbuf, vbuf, wdec, states, up, outw, nlog2);
      // 4. groupnorm + gate, output projection (dtype per flag)
      k_norm<<<dim3(M), 256, 0, stream>>>(outw, gbuf, lnwp, lnbp, gated);
      gemm_ep<EPI_BF16, false, true><<<dim3(16, M/64), 256, 0, stream>>>(
          gated, 1024, Wo, 1024, d_out, 1024, M, 1024, 1024, nullptr, nullptr, b0, t0, Llog2, flag);
    }
  }
}

// Round 6
// 1997.982 us; speedup vs baseline: 1.5942x; 1.5942x over previous
//
#include <hip/hip_runtime.h>
#include <hip/hip_bf16.h>
#include <math.h>

typedef __hip_bfloat16 bf16;
typedef __attribute__((ext_vector_type(8))) short short8;
typedef __attribute__((ext_vector_type(4))) float f32x4;

#define Tt 2048
#define Dd 1024
#define Hh 16

__device__ __forceinline__ float b2f(bf16 v){ return __bfloat162float(v); }
__device__ __forceinline__ bf16  f2b(float v){ return __float2bfloat16(v); }

__device__ __forceinline__ int seg_t(int lr, int t0, int Lm1){ return t0 + (lr & Lm1); }
__device__ __forceinline__ size_t seg_grow(int lr, int b0, int t0, int Llog2, int Lm1){
  return ((size_t)(b0 + (lr >> Llog2)) * Tt) + (size_t)seg_t(lr, t0, Lm1);
}

// ---------------------------------------------------------------- dtype detect
__global__ __launch_bounds__(256) void k_detect(const unsigned short* __restrict__ xs,
                                                int* __restrict__ flag){
  __shared__ int bad;
  if(threadIdx.x == 0) bad = 0;
  __syncthreads();
  int local = 0;
  for(int i = threadIdx.x; i < 8192; i += 256){
    unsigned e = (xs[i] >> 7) & 0xFF;
    if(e >= 0xC0) local++;
  }
  if(local) atomicAdd(&bad, local);
  __syncthreads();
  if(threadIdx.x == 0) flag[0] = (bad > 16) ? 1 : 0;   // 1 = inputs are float32
}

// ---------------------------------------------------------------- canonicalize to bf16
__global__ __launch_bounds__(256) void k_conv(const void* __restrict__ src,
                                              bf16* __restrict__ dst, int n,
                                              const int* __restrict__ flag){
  int i = blockIdx.x * 256 + threadIdx.x;
  if(i >= n) return;
  if(flag[0]) dst[i] = f2b(((const float*)src)[i]);
  else        dst[i] = ((const bf16*)src)[i];
}

// ---------------------------------------------------------------- 1024x1024 bf16 transpose
__global__ __launch_bounds__(256) void k_transpose(const bf16* __restrict__ src,
                                                   bf16* __restrict__ dst){
  __shared__ bf16 tile[32][33];
  int bx = blockIdx.x * 32, by = blockIdx.y * 32;
  int tx = threadIdx.x & 31, ty = threadIdx.x >> 5;   // 32 x 8
  for(int r = ty; r < 32; r += 8)
    tile[r][tx] = src[(size_t)(by + r) * 1024 + bx + tx];
  __syncthreads();
  for(int r = ty; r < 32; r += 8)
    dst[(size_t)(bx + r) * 1024 + by + tx] = tile[tx][r];
}

// ---------------------------------------------------------------- MFMA GEMM  C[M][1024] = A[M][1024] @ Bt^T
// Bt is [N=1024][K=1024] pre-transposed. 128x128 tile, BK=32, 2x2 waves,
// each wave 64x64 via 4x4 mfma_f32_16x16x32_bf16.
// Layouts (m89/m91-verified): A/B frag [idx=lane&15][k=quad*8+j];
// C/D: row = quad*4+reg, col = lane&15.
constexpr int GEPI_BF16 = 0, GEPI_SILU = 1, GEPI_OUT = 2;

template<int EPI>
__global__ __launch_bounds__(256) void gemm_mfma(
    const bf16* __restrict__ A,
    const bf16* __restrict__ Bt,
    void* __restrict__ Cv,
    const int* __restrict__ oflag,
    int rowoff){                       // global row offset for C (GEPI_OUT)
  __shared__ short As[128 * 40];
  __shared__ short Bs[128 * 40];
  int tid = threadIdx.x;
  int bn = blockIdx.x * 128;
  int bm = blockIdx.y * 128;
  int w = tid >> 6, lane = tid & 63;
  int wm = (w & 1) * 64, wn = (w >> 1) * 64;
  int m16 = lane & 15, quad = lane >> 4;

  f32x4 acc[4][4];
  #pragma unroll
  for(int mi = 0; mi < 4; mi++)
    #pragma unroll
    for(int ni = 0; ni < 4; ni++)
      acc[mi][ni] = (f32x4){0.f, 0.f, 0.f, 0.f};

  int srow = tid >> 2;            // 0..63
  int sk8  = (tid & 3) * 8;       // 0,8,16,24
  const bf16* Ag = A  + (size_t)(bm + srow) * 1024 + sk8;
  const bf16* Bg = Bt + (size_t)(bn + srow) * 1024 + sk8;
  short* Aw = As + srow * 40 + sk8;
  short* Bw = Bs + srow * 40 + sk8;

  for(int kb = 0; kb < 1024; kb += 32){
    #pragma unroll
    for(int rep = 0; rep < 2; rep++){
      *(short8*)(Aw + rep * 64 * 40) = *(const short8*)(Ag + (size_t)rep * 64 * 1024 + kb);
      *(short8*)(Bw + rep * 64 * 40) = *(const short8*)(Bg + (size_t)rep * 64 * 1024 + kb);
    }
    __syncthreads();
    short8 af[4], bfr[4];
    #pragma unroll
    for(int mi = 0; mi < 4; mi++)
      af[mi] = *(const short8*)(As + (wm + mi * 16 + m16) * 40 + quad * 8);
    #pragma unroll
    for(int ni = 0; ni < 4; ni++)
      bfr[ni] = *(const short8*)(Bs + (wn + ni * 16 + m16) * 40 + quad * 8);
    #pragma unroll
    for(int mi = 0; mi < 4; mi++)
      #pragma unroll
      for(int ni = 0; ni < 4; ni++)
        acc[mi][ni] = __builtin_amdgcn_mfma_f32_16x16x32_bf16(af[mi], bfr[ni], acc[mi][ni], 0, 0, 0);
    __syncthreads();
  }
  #pragma unroll
  for(int mi = 0; mi < 4; mi++){
    #pragma unroll
    for(int ni = 0; ni < 4; ni++){
      #pragma unroll
      for(int r = 0; r < 4; r++){
        int row = bm + wm + mi * 16 + quad * 4 + r;
        int col = bn + wn + ni * 16 + m16;
        float v = acc[mi][ni][r];
        if constexpr(EPI == GEPI_BF16){
          ((bf16*)Cv)[(size_t)row * 1024 + col] = f2b(v);
        } else if constexpr(EPI == GEPI_SILU){
          ((bf16*)Cv)[(size_t)row * 1024 + col] = f2b(v / (1.f + expf(-v)));
        } else { // GEPI_OUT
          size_t off = (size_t)(row + rowoff) * 1024 + col;
          if(oflag[0]) ((float*)Cv)[off] = v;
          else         ((bf16*)Cv)[off]  = f2b(v);
        }
      }
    }
  }
}

// ---------------------------------------------------------------- small VALU GEMM
constexpr int EPI_BF16 = 0, EPI_TANH = 1, EPI_SILU = 2, EPI_MIX = 3, EPI_DECAY = 4, EPI_OUTV = 5;
#define BM 64
#define BN 64
#define BK 16

template<int EPI, bool AFUSE>
__global__ __launch_bounds__(256) void gemm_ep(
    const bf16* __restrict__ A, int lda,
    const bf16* __restrict__ Bm, int ldb,
    void* __restrict__ Cv, int ldc,
    int Mdim, int Ndim, int Kdim,
    const bf16* __restrict__ xg, const bf16* __restrict__ e_w,
    int b0, int t0, int Llog2, const int* __restrict__ oflag){
  const int Lm1 = (1 << Llog2) - 1;
  __shared__ float As[BM][BK + 1];
  __shared__ float Bs[BK][BN + 4];
  int tid = threadIdx.x;
  int tx = tid & 15, ty = tid >> 4;
  int bm = blockIdx.y * BM, bn = blockIdx.x * BN;
  float acc[4][4] = {};
  for(int kb = 0; kb < Kdim; kb += BK){
    {
      int lr = tid >> 2;
      int lc = (tid & 3) * 4;
      int gr = bm + lr;
      #pragma unroll
      for(int q = 0; q < 4; q++){
        int gc = kb + lc + q;
        float av = 0.f;
        if(gr < Mdim && gc < Kdim){
          if constexpr(AFUSE){
            size_t grow = seg_grow(gr, b0, t0, Llog2, Lm1);
            int tl = seg_t(gr, t0, Lm1);
            float xc = b2f(xg[grow * Dd + gc]);
            float xp = tl ? b2f(xg[(grow - 1) * Dd + gc]) : 0.f;
            av = xc + (xp - xc) * b2f(e_w[gc]);
          } else {
            av = b2f(A[(size_t)gr * lda + gc]);
          }
        }
        As[lr][lc + q] = av;
      }
    }
    {
      int lr = tid >> 4;
      int lc = (tid & 15) * 4;
      #pragma unroll
      for(int q = 0; q < 4; q++){
        int gr = kb + lr; int gc = bn + lc + q;
        Bs[lr][lc + q] = (gr < Kdim && gc < Ndim) ? b2f(Bm[(size_t)gr * ldb + gc]) : 0.f;
      }
    }
    __syncthreads();
    #pragma unroll
    for(int kk = 0; kk < BK; kk++){
      float ar[4], br[4];
      #pragma unroll
      for(int q = 0; q < 4; q++) ar[q] = As[ty * 4 + q][kk];
      #pragma unroll
      for(int q = 0; q < 4; q++) br[q] = Bs[kk][tx * 4 + q];
      #pragma unroll
      for(int mi = 0; mi < 4; mi++)
        #pragma unroll
        for(int ni = 0; ni < 4; ni++)
          acc[mi][ni] += ar[mi] * br[ni];
    }
    __syncthreads();
  }
  #pragma unroll
  for(int mi = 0; mi < 4; mi++){
    int row = bm + ty * 4 + mi;
    if(row >= Mdim) continue;
    #pragma unroll
    for(int ni = 0; ni < 4; ni++){
      int col = bn + tx * 4 + ni;
      if(col >= Ndim) continue;
      float vacc = acc[mi][ni];
      size_t off = (size_t)row * ldc + col;
      if constexpr(EPI == EPI_BF16){
        ((bf16*)Cv)[off] = f2b(vacc);
      } else if constexpr(EPI == EPI_TANH){
        ((bf16*)Cv)[off] = f2b(tanhf(vacc));
      } else if constexpr(EPI == EPI_SILU){
        ((bf16*)Cv)[off] = f2b(vacc / (1.f + expf(-vacc)));
      } else if constexpr(EPI == EPI_MIX){
        size_t grow = seg_grow(row, b0, t0, Llog2, Lm1);
        int tl = seg_t(row, t0, Lm1);
        float xc = b2f(xg[grow * Dd + col]);
        float xp = tl ? b2f(xg[(grow - 1) * Dd + col]) : 0.f;
        ((bf16*)Cv)[off] = f2b(xc + (xp - xc) * (b2f(e_w[col]) + vacc));
      } else if constexpr(EPI == EPI_DECAY){
        float td = b2f(e_w[col]) + vacc;
        ((float*)Cv)[off] = fmaxf(-expf(td), -5.2983173665480363f);
      } else { // EPI_OUTV: global row map, dtype per flag
        size_t grow = seg_grow(row, b0, t0, Llog2, Lm1);
        size_t go = grow * Dd + col;
        if(oflag[0]) ((float*)Cv)[go] = vacc;
        else         ((bf16*)Cv)[go]  = f2b(vacc);
      }
    }
  }
}

// ---------------------------------------------------------------- cumsum (in place wlog->wcum) + wse
__global__ __launch_bounds__(256) void k_cumsum(float* __restrict__ wd,
                                                float* __restrict__ wse,
                                                int nlog2){
  int blk = blockIdx.x;
  int dg = blk & 3; int rest = blk >> 2;
  int nmask = (1 << nlog2) - 1;
  int ln = rest & nmask; int bp = rest >> nlog2;
  int d = dg * 256 + threadIdx.x;
  size_t rowbase = (((size_t)bp << nlog2) + ln) * 128;
  size_t base = rowbase * Dd + d;
  float c = 0.f;
  for(int t = 0; t < 128; t++){
    size_t ix = base + (size_t)t * Dd;
    c += wd[ix];
    wd[ix] = c;
  }
  int h = d >> 6, k0 = d & 63;
  wse[((((size_t)bp * Hh + h) << nlog2) | ln) * 64 + k0] = __expf(fminf(c, 0.f));
}

// ---------------------------------------------------------------- chunk1: wkv = (k*exp(ws-cum))^T @ v
__global__ __launch_bounds__(256) void k_chunk1(const bf16* __restrict__ kb,
                                                const bf16* __restrict__ vb,
                                                const float* __restrict__ wcum,
                                                float* __restrict__ wkv,
                                                int nlog2){
  __shared__ __align__(16) char smem[65536];
  bf16*  kt = (bf16*)smem;
  bf16*  vt = (bf16*)(smem + 16384);
  float* cs = (float*)(smem + 32768);
  int tid = threadIdx.x, blk = blockIdx.x;
  int nmask = (1 << nlog2) - 1;
  int ln = blk & nmask; int rest = blk >> nlog2;
  int h = rest & 15; int bp = rest >> 4;
  size_t rowbase = (((size_t)bp << nlog2) + ln) * 128;
  size_t gbase = rowbase * Dd + h * 64;
  for(int r = 0; r < 32; r++){
    int idx = r * 256 + tid;
    int t0 = idx >> 6, k0 = idx & 63;
    size_t gi = gbase + (size_t)t0 * Dd + k0;
    kt[idx] = kb[gi];
    vt[idx] = vb[gi];
    cs[idx] = wcum[gi];
  }
  __syncthreads();
  for(int r = 0; r < 32; r++){
    int idx = r * 256 + tid;
    int k0 = idx & 63;
    kt[idx] = f2b(b2f(kt[idx]) * __expf(fminf(cs[127 * 64 + k0] - cs[idx], 0.f)));
  }
  __syncthreads();
  int tx = tid & 15, ty = tid >> 4;
  float acc[4][4] = {};
  for(int t = 0; t < 128; t++){
    float kr[4], vr[4];
    #pragma unroll
    for(int q = 0; q < 4; q++) kr[q] = b2f(kt[t * 64 + ty * 4 + q]);
    #pragma unroll
    for(int q = 0; q < 4; q++) vr[q] = b2f(vt[t * 64 + tx * 4 + q]);
    #pragma unroll
    for(int i2 = 0; i2 < 4; i2++)
      #pragma unroll
      for(int j2 = 0; j2 < 4; j2++)
        acc[i2][j2] += kr[i2] * vr[j2];
  }
  size_t obase = (size_t)blk * 4096;
  #pragma unroll
  for(int i2 = 0; i2 < 4; i2++)
    #pragma unroll
    for(int j2 = 0; j2 < 4; j2++)
      wkv[obase + (ty * 4 + i2) * 64 + tx * 4 + j2] = acc[i2][j2];
}

// ---------------------------------------------------------------- state scan, in place, carry in st
__global__ __launch_bounds__(256) void k_scan(float* __restrict__ buf,
                                              const float* __restrict__ wse,
                                              float* __restrict__ st,
                                              int b0, int firstseg, int nlog2){
  int blk = blockIdx.x;                // nb*16: (bp, h)
  int h = blk & 15, bp = blk >> 4;
  int tid = threadIdx.x;
  size_t stbase = ((size_t)(b0 + bp) * Hh + h) * 4096;
  int nloc = 1 << nlog2;
  float s[16];
  #pragma unroll
  for(int r = 0; r < 16; r++)
    s[r] = firstseg ? 0.f : st[stbase + r * 256 + tid];
  for(int ln = 0; ln < nloc; ln++){
    size_t idx = (((size_t)bp * Hh + h) << nlog2) | ln;
    size_t base = idx * 4096;
    const float* wsp = wse + idx * 64;
    #pragma unroll
    for(int r = 0; r < 16; r++){
      int e = r * 256 + tid;
      float tmp = buf[base + e];      // read wkv BEFORE overwrite
      buf[base + e] = s[r];           // emit pre-update state
      s[r] = s[r] * wsp[e >> 6] + tmp;
    }
  }
  #pragma unroll
  for(int r = 0; r < 16; r++)
    st[stbase + r * 256 + tid] = s[r];
}

// ---------------------------------------------------------------- chunk2 (loop-interchanged)
__global__ __launch_bounds__(256) void k_chunk2(
    const bf16* __restrict__ rb, const bf16* __restrict__ kb,
    const bf16* __restrict__ vb, const float* __restrict__ wcum,
    const float* __restrict__ states, const bf16* __restrict__ u,
    float* __restrict__ outw, int nlog2){
  __shared__ __align__(16) char smem[65536];
  bf16*  kt = (bf16*)smem;
  bf16*  rt = (bf16*)(smem + 16384);
  float* cs = (float*)(smem + 32768);
  int tid = threadIdx.x, blk = blockIdx.x;
  int nmask = (1 << nlog2) - 1;
  int ln = blk & nmask; int rest = blk >> nlog2;
  int h = rest & 15; int bp = rest >> 4;
  size_t rowbase = (((size_t)bp << nlog2) + ln) * 128;
  size_t gbase = rowbase * Dd + h * 64;
  for(int r = 0; r < 32; r++){
    int idx = r * 256 + tid;
    int t0 = idx >> 6, k0 = idx & 63;
    size_t gi = gbase + (size_t)t0 * Dd + k0;
    kt[idx] = kb[gi];
    rt[idx] = rb[gi];
    cs[idx] = wcum[gi];
  }
  __syncthreads();
  int i = tid >> 1, hf = tid & 1;
  float rwreg[32];
  #pragma unroll
  for(int k2 = 0; k2 < 32; k2++){
    int kk = hf * 32 + k2;
    float cp = i ? cs[(i - 1) * 64 + kk] : 0.f;
    rwreg[k2] = b2f(rt[i * 64 + kk]) * __expf(fminf(cp, 0.f));
  }
  float a[64];
  #pragma unroll
  for(int j = 0; j < 64; j++) a[j] = 0.f;
  {
    const bf16*  ri = &rt[i * 64];
    const float* ci = (i > 0) ? &cs[(i - 1) * 64] : cs;
    for(int k = 0; k < 64; k++){
      float rk  = b2f(ri[k]);               // per-lane read, hoisted: 64 total
      float cik = i ? ci[k] : 0.f;          // per-lane read, hoisted
      #pragma unroll
      for(int j = 0; j < 64; j++){
        int jj = hf * 64 + j;
        if(jj < i)
          a[j] += rk * b2f(kt[jj * 64 + k]) * __expf(fminf(cik - cs[jj * 64 + k], 0.f));
      }
    }
    int jd = i - hf * 64;                   // diagonal term (owner half only)
    if(jd >= 0 && jd < 64){
      float s = 0.f;
      const bf16* kj = &kt[i * 64];
      for(int k = 0; k < 64; k++)
        s += b2f(ri[k]) * b2f(u[h * 64 + k]) * b2f(kj[k]);
      a[jd] = s;
    }
  }
  __syncthreads();
  bf16*  vt  = (bf16*)smem;            // over kt
  float* ssm = (float*)(smem + 16384); // over rt
  for(int r = 0; r < 32; r++){
    int idx = r * 256 + tid;
    int t0 = idx >> 6, k0 = idx & 63;
    vt[idx] = vb[gbase + (size_t)t0 * Dd + k0];
  }
  for(int r = 0; r < 16; r++){
    int idx = r * 256 + tid;
    ssm[idx] = states[(size_t)blk * 4096 + idx];
  }
  __syncthreads();
  for(int v = 0; v < 64; v++){
    float p = 0.f;
    #pragma unroll
    for(int j = 0; j < 64; j++)
      p += a[j] * b2f(vt[(hf * 64 + j) * 64 + v]);
    #pragma unroll
    for(int k2 = 0; k2 < 32; k2++)
      p += rwreg[k2] * ssm[(hf * 32 + k2) * 64 + v];
    float tot = p + __shfl_xor(p, 1);
    if(hf == 0) outw[gbase + (size_t)i * Dd + v] = tot;
  }
}

// ---------------------------------------------------------------- groupnorm(64) + gate
__global__ __launch_bounds__(256) void k_norm(const float* __restrict__ outw,
                                              const bf16* __restrict__ gb,
                                              const bf16* __restrict__ lnw,
                                              const bf16* __restrict__ lnb,
                                              bf16* __restrict__ gated){
  int lr = blockIdx.x;
  int wv = threadIdx.x >> 6, lane = threadIdx.x & 63;
  for(int hh = wv; hh < Hh; hh += 4){
    size_t ix = (size_t)lr * Dd + hh * 64 + lane;
    float xv = outw[ix];
    float s1 = xv, s2 = xv * xv;
    #pragma unroll
    for(int off = 32; off > 0; off >>= 1){
      s1 += __shfl_xor(s1, off);
      s2 += __shfl_xor(s2, off);
    }
    float mu  = s1 * 0.015625f;
    float var = s2 * 0.015625f - mu * mu;
    float inv = rsqrtf(var + 6.4e-4f);
    float og  = (xv - mu) * inv * b2f(lnw[hh * 64 + lane]) + b2f(lnb[hh * 64 + lane]);
    gated[ix] = f2b(og * b2f(gb[ix]));
  }
}

// ---------------------------------------------------------------- host
extern "C" void kernel_launch(void* const* d_in, const int* in_sizes, int n_in,
                              void* d_out, int out_size, void* d_ws, size_t ws_size,
                              hipStream_t stream){
  char* W = (char*)d_ws;
  size_t cur = 0;
  auto carve = [&](size_t bytes) -> char* {
    char* p = W + cur;
    cur = (cur + bytes + 255) & ~(size_t)255;
    return p;
  };

  int* flag = (int*)carve(4096);
  static const int NEL[20] = {8388608, 1024, 1024, 1024, 1024, 1024, 1024,
                              163840, 163840, 1024, 65536, 65536, 1024,
                              1048576, 1048576, 1048576, 1048576, 1048576,
                              1024, 1024};
  bf16* canon[20];
  for(int i = 0; i < 20; i++) canon[i] = (bf16*)carve((size_t)NEL[i] * 2);

  k_detect<<<dim3(1), 256, 0, stream>>>((const unsigned short*)d_in[0], flag);
  for(int i = 0; i < 20; i++)
    k_conv<<<dim3((NEL[i] + 255) / 256), 256, 0, stream>>>(d_in[i], canon[i], NEL[i], flag);

  const bf16* xp   = canon[0];
  const bf16* tmx  = canon[1];
  const bf16* maas[5] = {canon[2], canon[3], canon[4], canon[5], canon[6]};
  const bf16* w1p  = canon[7];
  const bf16* w2p  = canon[8];
  const bf16* tdec = canon[9];
  const bf16* dw1  = canon[10];
  const bf16* dw2  = canon[11];
  const bf16* up   = canon[12];
  const bf16* lnwp = canon[18];
  const bf16* lnbp = canon[19];

  bf16* WrT = (bf16*)carve(2097152);
  bf16* WkT = (bf16*)carve(2097152);
  bf16* WvT = (bf16*)carve(2097152);
  bf16* WgT = (bf16*)carve(2097152);
  bf16* WoT = (bf16*)carve(2097152);
  k_transpose<<<dim3(32, 32), 256, 0, stream>>>(canon[13], WrT);
  k_transpose<<<dim3(32, 32), 256, 0, stream>>>(canon[14], WkT);
  k_transpose<<<dim3(32, 32), 256, 0, stream>>>(canon[15], WvT);
  k_transpose<<<dim3(32, 32), 256, 0, stream>>>(canon[16], WgT);
  k_transpose<<<dim3(32, 32), 256, 0, stream>>>(canon[17], WoT);

  float* st = (float*)carve(1u << 20);
  size_t FIXED = cur;

  const size_t UNIT = 16864, PAD = 65536;
  int nb, L;
  if(ws_size >= FIXED + (size_t)8192 * UNIT + PAD){ nb = 4; L = 2048; }
  else {
    nb = 1; L = 2048;
    while(L > 128 && ws_size < FIXED + (size_t)L * UNIT + PAD) L >>= 1;
  }
  const int Llog2 = __builtin_ctz((unsigned)L);
  const int nlog2 = Llog2 - 7;
  const int M     = nb * L;
  const size_t Mr = (size_t)M;

  bf16*  xxx    = (bf16*) carve(Mr * 320);
  bf16*  ww1    = (bf16*) carve(Mr * 128);
  float* wse    = (float*)carve(Mr * 32);
  bf16*  mix    = (bf16*) carve(Mr * 2048);
  bf16*  kbuf   = (bf16*) carve(Mr * 2048);
  bf16*  vbuf   = (bf16*) carve(Mr * 2048);
  bf16*  rbuf   = (bf16*) carve(Mr * 2048);
  bf16*  gbuf   = (bf16*) carve(Mr * 2048);
  float* wdec   = (float*)carve(Mr * 4096);
  float* wkvst  = (float*)carve(Mr * 2048);
  float* outw   = wdec;   // chunk2 LDS-stages its wcum tile before overwriting
  bf16*  gated  = mix;    // mix dead after last consumer GEMM

  for(int b0 = 0; b0 < 4; b0 += nb){
    for(int t0 = 0; t0 < Tt; t0 += L){
      gemm_ep<EPI_TANH, true><<<dim3(3, M/64), 256, 0, stream>>>(
          xp, Dd, w1p, 160, xxx, 160, M, 160, Dd, xp, tmx, b0, t0, Llog2, flag);
      for(int c = 0; c < 5; c++){
        gemm_ep<EPI_MIX, false><<<dim3(16, M/64), 256, 0, stream>>>(
            xxx + c * 32, 160, w2p + (size_t)c * 32 * 1024, 1024,
            mix, 1024, M, 1024, 32, xp, maas[c], b0, t0, Llog2, flag);
        if(c == 0){
          gemm_ep<EPI_TANH, false><<<dim3(1, M/64), 256, 0, stream>>>(
              mix, 1024, dw1, 64, ww1, 64, M, 64, 1024, nullptr, nullptr, 0, 0, Llog2, flag);
          gemm_ep<EPI_DECAY, false><<<dim3(16, M/64), 256, 0, stream>>>(
              ww1, 64, dw2, 1024, wdec, 1024, M, 1024, 64, nullptr, tdec, 0, 0, Llog2, flag);
        } else if(c == 1){
          gemm_mfma<GEPI_BF16><<<dim3(8, M/128), 256, 0, stream>>>(mix, WkT, kbuf, flag, 0);
        } else if(c == 2){
          gemm_mfma<GEPI_BF16><<<dim3(8, M/128), 256, 0, stream>>>(mix, WvT, vbuf, flag, 0);
        } else if(c == 3){
          gemm_mfma<GEPI_BF16><<<dim3(8, M/128), 256, 0, stream>>>(mix, WrT, rbuf, flag, 0);
        } else {
          gemm_mfma<GEPI_SILU><<<dim3(8, M/128), 256, 0, stream>>>(mix, WgT, gbuf, flag, 0);
        }
      }
      int nloc = 1 << nlog2;
      k_cumsum<<<dim3(nb * nloc * 4), 256, 0, stream>>>(wdec, wse, nlog2);
      k_chunk1<<<dim3(nb * 16 * nloc), 256, 0, stream>>>(kbuf, vbuf, wdec, wkvst, nlog2);
      k_scan<<<dim3(nb * 16), 256, 0, stream>>>(wkvst, wse, st, b0, (t0 == 0) ? 1 : 0, nlog2);
      k_chunk2<<<dim3(nb * 16 * nloc), 256, 0, stream>>>(rbuf, kbuf, vbuf, wdec, wkvst, up, outw, nlog2);
      k_norm<<<dim3(M), 256, 0, stream>>>(outw, gbuf, lnwp, lnbp, gated);
      if(L == Tt){
        // segment rows are contiguous in d_out: global row offset = b0*Tt
        gemm_mfma<GEPI_OUT><<<dim3(8, M/128), 256, 0, stream>>>(gated, WoT, d_out, flag, b0 * Tt);
      } else {
        gemm_ep<EPI_OUTV, false><<<dim3(16, M/64), 256, 0, stream>>>(
            gated, 1024, canon[17], 1024, d_out, 1024, M, 1024, 1024,
            nullptr, nullptr, b0, t0, Llog2, flag);
      }
    }
  }
}

// Round 7
// 1698.333 us; speedup vs baseline: 1.8754x; 1.1764x over previous
//
#include <hip/hip_runtime.h>
#include <hip/hip_bf16.h>
#include <math.h>

typedef __hip_bfloat16 bf16;
typedef __attribute__((ext_vector_type(8))) short short8;
typedef __attribute__((ext_vector_type(4))) float f32x4;

#define Tt 2048
#define Dd 1024
#define Hh 16

__device__ __forceinline__ float b2f(bf16 v){ return __bfloat162float(v); }
__device__ __forceinline__ bf16  f2b(float v){ return __float2bfloat16(v); }

__device__ __forceinline__ int seg_t(int lr, int t0, int Lm1){ return t0 + (lr & Lm1); }
__device__ __forceinline__ size_t seg_grow(int lr, int b0, int t0, int Llog2, int Lm1){
  return ((size_t)(b0 + (lr >> Llog2)) * Tt) + (size_t)seg_t(lr, t0, Lm1);
}

// ---------------------------------------------------------------- dtype detect
__global__ __launch_bounds__(256) void k_detect(const unsigned short* __restrict__ xs,
                                                int* __restrict__ flag){
  __shared__ int bad;
  if(threadIdx.x == 0) bad = 0;
  __syncthreads();
  int local = 0;
  for(int i = threadIdx.x; i < 8192; i += 256){
    unsigned e = (xs[i] >> 7) & 0xFF;
    if(e >= 0xC0) local++;
  }
  if(local) atomicAdd(&bad, local);
  __syncthreads();
  if(threadIdx.x == 0) flag[0] = (bad > 16) ? 1 : 0;   // 1 = inputs are float32
}

// ---------------------------------------------------------------- canonicalize to bf16
__global__ __launch_bounds__(256) void k_conv(const void* __restrict__ src,
                                              bf16* __restrict__ dst, int n,
                                              const int* __restrict__ flag){
  int i = blockIdx.x * 256 + threadIdx.x;
  if(i >= n) return;
  if(flag[0]) dst[i] = f2b(((const float*)src)[i]);
  else        dst[i] = ((const bf16*)src)[i];
}

// ---------------------------------------------------------------- 1024x1024 bf16 transpose
__global__ __launch_bounds__(256) void k_transpose(const bf16* __restrict__ src,
                                                   bf16* __restrict__ dst){
  __shared__ bf16 tile[32][33];
  int bx = blockIdx.x * 32, by = blockIdx.y * 32;
  int tx = threadIdx.x & 31, ty = threadIdx.x >> 5;   // 32 x 8
  for(int r = ty; r < 32; r += 8)
    tile[r][tx] = src[(size_t)(by + r) * 1024 + bx + tx];
  __syncthreads();
  for(int r = ty; r < 32; r += 8)
    dst[(size_t)(bx + r) * 1024 + by + tx] = tile[tx][r];
}

// ---------------------------------------------------------------- MFMA GEMM  C[M][1024] = A[M][1024] @ Bt^T
constexpr int GEPI_BF16 = 0, GEPI_SILU = 1, GEPI_OUT = 2;

template<int EPI>
__global__ __launch_bounds__(256) void gemm_mfma(
    const bf16* __restrict__ A,
    const bf16* __restrict__ Bt,
    void* __restrict__ Cv,
    const int* __restrict__ oflag,
    int rowoff){
  __shared__ short As[128 * 40];
  __shared__ short Bs[128 * 40];
  int tid = threadIdx.x;
  int bn = blockIdx.x * 128;
  int bm = blockIdx.y * 128;
  int w = tid >> 6, lane = tid & 63;
  int wm = (w & 1) * 64, wn = (w >> 1) * 64;
  int m16 = lane & 15, quad = lane >> 4;

  f32x4 acc[4][4];
  #pragma unroll
  for(int mi = 0; mi < 4; mi++)
    #pragma unroll
    for(int ni = 0; ni < 4; ni++)
      acc[mi][ni] = (f32x4){0.f, 0.f, 0.f, 0.f};

  int srow = tid >> 2;
  int sk8  = (tid & 3) * 8;
  const bf16* Ag = A  + (size_t)(bm + srow) * 1024 + sk8;
  const bf16* Bg = Bt + (size_t)(bn + srow) * 1024 + sk8;
  short* Aw = As + srow * 40 + sk8;
  short* Bw = Bs + srow * 40 + sk8;

  for(int kb = 0; kb < 1024; kb += 32){
    #pragma unroll
    for(int rep = 0; rep < 2; rep++){
      *(short8*)(Aw + rep * 64 * 40) = *(const short8*)(Ag + (size_t)rep * 64 * 1024 + kb);
      *(short8*)(Bw + rep * 64 * 40) = *(const short8*)(Bg + (size_t)rep * 64 * 1024 + kb);
    }
    __syncthreads();
    short8 af[4], bfr[4];
    #pragma unroll
    for(int mi = 0; mi < 4; mi++)
      af[mi] = *(const short8*)(As + (wm + mi * 16 + m16) * 40 + quad * 8);
    #pragma unroll
    for(int ni = 0; ni < 4; ni++)
      bfr[ni] = *(const short8*)(Bs + (wn + ni * 16 + m16) * 40 + quad * 8);
    #pragma unroll
    for(int mi = 0; mi < 4; mi++)
      #pragma unroll
      for(int ni = 0; ni < 4; ni++)
        acc[mi][ni] = __builtin_amdgcn_mfma_f32_16x16x32_bf16(af[mi], bfr[ni], acc[mi][ni], 0, 0, 0);
    __syncthreads();
  }
  #pragma unroll
  for(int mi = 0; mi < 4; mi++){
    #pragma unroll
    for(int ni = 0; ni < 4; ni++){
      #pragma unroll
      for(int r = 0; r < 4; r++){
        int row = bm + wm + mi * 16 + quad * 4 + r;
        int col = bn + wn + ni * 16 + m16;
        float v = acc[mi][ni][r];
        if constexpr(EPI == GEPI_BF16){
          ((bf16*)Cv)[(size_t)row * 1024 + col] = f2b(v);
        } else if constexpr(EPI == GEPI_SILU){
          ((bf16*)Cv)[(size_t)row * 1024 + col] = f2b(v / (1.f + expf(-v)));
        } else { // GEPI_OUT
          size_t off = (size_t)(row + rowoff) * 1024 + col;
          if(oflag[0]) ((float*)Cv)[off] = v;
          else         ((bf16*)Cv)[off]  = f2b(v);
        }
      }
    }
  }
}

// ---------------------------------------------------------------- small VALU GEMM
constexpr int EPI_BF16 = 0, EPI_TANH = 1, EPI_SILU = 2, EPI_MIX = 3, EPI_DECAY = 4, EPI_OUTV = 5;
#define BM 64
#define BN 64
#define BK 16

template<int EPI, bool AFUSE>
__global__ __launch_bounds__(256) void gemm_ep(
    const bf16* __restrict__ A, int lda,
    const bf16* __restrict__ Bm, int ldb,
    void* __restrict__ Cv, int ldc,
    int Mdim, int Ndim, int Kdim,
    const bf16* __restrict__ xg, const bf16* __restrict__ e_w,
    int b0, int t0, int Llog2, const int* __restrict__ oflag){
  const int Lm1 = (1 << Llog2) - 1;
  __shared__ float As[BM][BK + 1];
  __shared__ float Bs[BK][BN + 4];
  int tid = threadIdx.x;
  int tx = tid & 15, ty = tid >> 4;
  int bm = blockIdx.y * BM, bn = blockIdx.x * BN;
  float acc[4][4] = {};
  for(int kb = 0; kb < Kdim; kb += BK){
    {
      int lr = tid >> 2;
      int lc = (tid & 3) * 4;
      int gr = bm + lr;
      #pragma unroll
      for(int q = 0; q < 4; q++){
        int gc = kb + lc + q;
        float av = 0.f;
        if(gr < Mdim && gc < Kdim){
          if constexpr(AFUSE){
            size_t grow = seg_grow(gr, b0, t0, Llog2, Lm1);
            int tl = seg_t(gr, t0, Lm1);
            float xc = b2f(xg[grow * Dd + gc]);
            float xp = tl ? b2f(xg[(grow - 1) * Dd + gc]) : 0.f;
            av = xc + (xp - xc) * b2f(e_w[gc]);
          } else {
            av = b2f(A[(size_t)gr * lda + gc]);
          }
        }
        As[lr][lc + q] = av;
      }
    }
    {
      int lr = tid >> 4;
      int lc = (tid & 15) * 4;
      #pragma unroll
      for(int q = 0; q < 4; q++){
        int gr = kb + lr; int gc = bn + lc + q;
        Bs[lr][lc + q] = (gr < Kdim && gc < Ndim) ? b2f(Bm[(size_t)gr * ldb + gc]) : 0.f;
      }
    }
    __syncthreads();
    #pragma unroll
    for(int kk = 0; kk < BK; kk++){
      float ar[4], br[4];
      #pragma unroll
      for(int q = 0; q < 4; q++) ar[q] = As[ty * 4 + q][kk];
      #pragma unroll
      for(int q = 0; q < 4; q++) br[q] = Bs[kk][tx * 4 + q];
      #pragma unroll
      for(int mi = 0; mi < 4; mi++)
        #pragma unroll
        for(int ni = 0; ni < 4; ni++)
          acc[mi][ni] += ar[mi] * br[ni];
    }
    __syncthreads();
  }
  #pragma unroll
  for(int mi = 0; mi < 4; mi++){
    int row = bm + ty * 4 + mi;
    if(row >= Mdim) continue;
    #pragma unroll
    for(int ni = 0; ni < 4; ni++){
      int col = bn + tx * 4 + ni;
      if(col >= Ndim) continue;
      float vacc = acc[mi][ni];
      size_t off = (size_t)row * ldc + col;
      if constexpr(EPI == EPI_BF16){
        ((bf16*)Cv)[off] = f2b(vacc);
      } else if constexpr(EPI == EPI_TANH){
        ((bf16*)Cv)[off] = f2b(tanhf(vacc));
      } else if constexpr(EPI == EPI_SILU){
        ((bf16*)Cv)[off] = f2b(vacc / (1.f + expf(-vacc)));
      } else if constexpr(EPI == EPI_MIX){
        size_t grow = seg_grow(row, b0, t0, Llog2, Lm1);
        int tl = seg_t(row, t0, Lm1);
        float xc = b2f(xg[grow * Dd + col]);
        float xp = tl ? b2f(xg[(grow - 1) * Dd + col]) : 0.f;
        ((bf16*)Cv)[off] = f2b(xc + (xp - xc) * (b2f(e_w[col]) + vacc));
      } else if constexpr(EPI == EPI_DECAY){
        float td = b2f(e_w[col]) + vacc;
        ((float*)Cv)[off] = fmaxf(-expf(td), -5.2983173665480363f);
      } else { // EPI_OUTV
        size_t grow = seg_grow(row, b0, t0, Llog2, Lm1);
        size_t go = grow * Dd + col;
        if(oflag[0]) ((float*)Cv)[go] = vacc;
        else         ((bf16*)Cv)[go]  = f2b(vacc);
      }
    }
  }
}

// ---------------------------------------------------------------- cumsum (in place wlog->wcum) + wse
__global__ __launch_bounds__(256) void k_cumsum(float* __restrict__ wd,
                                                float* __restrict__ wse,
                                                int nlog2){
  int blk = blockIdx.x;
  int dg = blk & 3; int rest = blk >> 2;
  int nmask = (1 << nlog2) - 1;
  int ln = rest & nmask; int bp = rest >> nlog2;
  int d = dg * 256 + threadIdx.x;
  size_t rowbase = (((size_t)bp << nlog2) + ln) * 128;
  size_t base = rowbase * Dd + d;
  float c = 0.f;
  for(int t = 0; t < 128; t++){
    size_t ix = base + (size_t)t * Dd;
    c += wd[ix];
    wd[ix] = c;
  }
  int h = d >> 6, k0 = d & 63;
  wse[((((size_t)bp * Hh + h) << nlog2) | ln) * 64 + k0] = __expf(fminf(c, 0.f));
}

// ---------------------------------------------------------------- chunk1: wkv = (k*exp(ws-cum))^T @ v
__global__ __launch_bounds__(256) void k_chunk1(const bf16* __restrict__ kb,
                                                const bf16* __restrict__ vb,
                                                const float* __restrict__ wcum,
                                                float* __restrict__ wkv,
                                                int nlog2){
  __shared__ __align__(16) char smem[65536];
  bf16*  kt = (bf16*)smem;
  bf16*  vt = (bf16*)(smem + 16384);
  float* cs = (float*)(smem + 32768);
  int tid = threadIdx.x, blk = blockIdx.x;
  int nmask = (1 << nlog2) - 1;
  int ln = blk & nmask; int rest = blk >> nlog2;
  int h = rest & 15; int bp = rest >> 4;
  size_t rowbase = (((size_t)bp << nlog2) + ln) * 128;
  size_t gbase = rowbase * Dd + h * 64;
  for(int r = 0; r < 32; r++){
    int idx = r * 256 + tid;
    int t0 = idx >> 6, k0 = idx & 63;
    size_t gi = gbase + (size_t)t0 * Dd + k0;
    kt[idx] = kb[gi];
    vt[idx] = vb[gi];
    cs[idx] = wcum[gi];
  }
  __syncthreads();
  for(int r = 0; r < 32; r++){
    int idx = r * 256 + tid;
    int k0 = idx & 63;
    kt[idx] = f2b(b2f(kt[idx]) * __expf(fminf(cs[127 * 64 + k0] - cs[idx], 0.f)));
  }
  __syncthreads();
  int tx = tid & 15, ty = tid >> 4;
  float acc[4][4] = {};
  for(int t = 0; t < 128; t++){
    float kr[4], vr[4];
    #pragma unroll
    for(int q = 0; q < 4; q++) kr[q] = b2f(kt[t * 64 + ty * 4 + q]);
    #pragma unroll
    for(int q = 0; q < 4; q++) vr[q] = b2f(vt[t * 64 + tx * 4 + q]);
    #pragma unroll
    for(int i2 = 0; i2 < 4; i2++)
      #pragma unroll
      for(int j2 = 0; j2 < 4; j2++)
        acc[i2][j2] += kr[i2] * vr[j2];
  }
  size_t obase = (size_t)blk * 4096;
  #pragma unroll
  for(int i2 = 0; i2 < 4; i2++)
    #pragma unroll
    for(int j2 = 0; j2 < 4; j2++)
      wkv[obase + (ty * 4 + i2) * 64 + tx * 4 + j2] = acc[i2][j2];
}

// ---------------------------------------------------------------- state scan, in place, carry in st
__global__ __launch_bounds__(256) void k_scan(float* __restrict__ buf,
                                              const float* __restrict__ wse,
                                              float* __restrict__ st,
                                              int b0, int firstseg, int nlog2){
  int blk = blockIdx.x;
  int h = blk & 15, bp = blk >> 4;
  int tid = threadIdx.x;
  size_t stbase = ((size_t)(b0 + bp) * Hh + h) * 4096;
  int nloc = 1 << nlog2;
  float s[16];
  #pragma unroll
  for(int r = 0; r < 16; r++)
    s[r] = firstseg ? 0.f : st[stbase + r * 256 + tid];
  for(int ln = 0; ln < nloc; ln++){
    size_t idx = (((size_t)bp * Hh + h) << nlog2) | ln;
    size_t base = idx * 4096;
    const float* wsp = wse + idx * 64;
    #pragma unroll
    for(int r = 0; r < 16; r++){
      int e = r * 256 + tid;
      float tmp = buf[base + e];
      buf[base + e] = s[r];
      s[r] = s[r] * wsp[e >> 6] + tmp;
    }
  }
  #pragma unroll
  for(int r = 0; r < 16; r++)
    st[stbase + r * 256 + tid] = s[r];
}

// ---------------------------------------------------------------- chunk2: R5 j-outer structure + 8-wide j-tiling
// (hoists the per-lane conflicted LDS reads ri[k]/ci[k] out of an 8-wide j tile:
//  conflicted reads drop 8x; tile accumulator a8[8] stays in regs, a[64] written
//  SEQUENTIALLY as in R5 so the compiler keeps it in VGPRs — no scratch spill.)
__global__ __launch_bounds__(256, 2) void k_chunk2(
    const bf16* __restrict__ rb, const bf16* __restrict__ kb,
    const bf16* __restrict__ vb, const float* __restrict__ wcum,
    const float* __restrict__ states, const bf16* __restrict__ u,
    float* __restrict__ outw, int nlog2){
  __shared__ __align__(16) char smem[65536];
  bf16*  kt = (bf16*)smem;
  bf16*  rt = (bf16*)(smem + 16384);
  float* cs = (float*)(smem + 32768);
  int tid = threadIdx.x, blk = blockIdx.x;
  int nmask = (1 << nlog2) - 1;
  int ln = blk & nmask; int rest = blk >> nlog2;
  int h = rest & 15; int bp = rest >> 4;
  size_t rowbase = (((size_t)bp << nlog2) + ln) * 128;
  size_t gbase = rowbase * Dd + h * 64;
  for(int r = 0; r < 32; r++){
    int idx = r * 256 + tid;
    int t0 = idx >> 6, k0 = idx & 63;
    size_t gi = gbase + (size_t)t0 * Dd + k0;
    kt[idx] = kb[gi];
    rt[idx] = rb[gi];
    cs[idx] = wcum[gi];
  }
  __syncthreads();
  int i = tid >> 1, hf = tid & 1;
  float rwreg[32];
  #pragma unroll
  for(int k2 = 0; k2 < 32; k2++){
    int kk = hf * 32 + k2;
    float cp = i ? cs[(i - 1) * 64 + kk] : 0.f;
    rwreg[k2] = b2f(rt[i * 64 + kk]) * __expf(fminf(cp, 0.f));
  }
  float a[64];
  {
    const bf16*  ri = &rt[i * 64];
    const float* ci = (i > 0) ? &cs[(i - 1) * 64] : cs;
    for(int jt = 0; jt < 8; jt++){
      float a8[8];
      #pragma unroll
      for(int q = 0; q < 8; q++) a8[q] = 0.f;
      int jbase = hf * 64 + jt * 8;
      if(jbase < i){
        for(int k = 0; k < 64; k++){
          float rk  = b2f(ri[k]);           // per-lane read, hoisted: 8 per k total
          float cik = i ? ci[k] : 0.f;      // per-lane read, hoisted
          #pragma unroll
          for(int q = 0; q < 8; q++){
            int jj = jbase + q;
            if(jj < i)
              a8[q] += rk * b2f(kt[jj * 64 + k]) * __expf(fminf(cik - cs[jj * 64 + k], 0.f));
          }
        }
      }
      #pragma unroll
      for(int q = 0; q < 8; q++) a[jt * 8 + q] = a8[q];  // sequential write
    }
    int jd = i - hf * 64;                    // diagonal (owner half), after tiles
    if(jd >= 0 && jd < 64){
      float s = 0.f;
      const bf16* kj = &kt[i * 64];
      for(int k = 0; k < 64; k++)
        s += b2f(ri[k]) * b2f(u[h * 64 + k]) * b2f(kj[k]);
      a[jd] = s;
    }
  }
  __syncthreads();
  bf16*  vt  = (bf16*)smem;            // over kt
  float* ssm = (float*)(smem + 16384); // over rt
  for(int r = 0; r < 32; r++){
    int idx = r * 256 + tid;
    int t0 = idx >> 6, k0 = idx & 63;
    vt[idx] = vb[gbase + (size_t)t0 * Dd + k0];
  }
  for(int r = 0; r < 16; r++){
    int idx = r * 256 + tid;
    ssm[idx] = states[(size_t)blk * 4096 + idx];
  }
  __syncthreads();
  for(int v = 0; v < 64; v++){
    float p = 0.f;
    #pragma unroll
    for(int j = 0; j < 64; j++)
      p += a[j] * b2f(vt[(hf * 64 + j) * 64 + v]);
    #pragma unroll
    for(int k2 = 0; k2 < 32; k2++)
      p += rwreg[k2] * ssm[(hf * 32 + k2) * 64 + v];
    float tot = p + __shfl_xor(p, 1);
    if(hf == 0) outw[gbase + (size_t)i * Dd + v] = tot;
  }
}

// ---------------------------------------------------------------- groupnorm(64) + gate
__global__ __launch_bounds__(256) void k_norm(const float* __restrict__ outw,
                                              const bf16* __restrict__ gb,
                                              const bf16* __restrict__ lnw,
                                              const bf16* __restrict__ lnb,
                                              bf16* __restrict__ gated){
  int lr = blockIdx.x;
  int wv = threadIdx.x >> 6, lane = threadIdx.x & 63;
  for(int hh = wv; hh < Hh; hh += 4){
    size_t ix = (size_t)lr * Dd + hh * 64 + lane;
    float xv = outw[ix];
    float s1 = xv, s2 = xv * xv;
    #pragma unroll
    for(int off = 32; off > 0; off >>= 1){
      s1 += __shfl_xor(s1, off);
      s2 += __shfl_xor(s2, off);
    }
    float mu  = s1 * 0.015625f;
    float var = s2 * 0.015625f - mu * mu;
    float inv = rsqrtf(var + 6.4e-4f);
    float og  = (xv - mu) * inv * b2f(lnw[hh * 64 + lane]) + b2f(lnb[hh * 64 + lane]);
    gated[ix] = f2b(og * b2f(gb[ix]));
  }
}

// ---------------------------------------------------------------- host
extern "C" void kernel_launch(void* const* d_in, const int* in_sizes, int n_in,
                              void* d_out, int out_size, void* d_ws, size_t ws_size,
                              hipStream_t stream){
  char* W = (char*)d_ws;
  size_t cur = 0;
  auto carve = [&](size_t bytes) -> char* {
    char* p = W + cur;
    cur = (cur + bytes + 255) & ~(size_t)255;
    return p;
  };

  int* flag = (int*)carve(4096);
  static const int NEL[20] = {8388608, 1024, 1024, 1024, 1024, 1024, 1024,
                              163840, 163840, 1024, 65536, 65536, 1024,
                              1048576, 1048576, 1048576, 1048576, 1048576,
                              1024, 1024};
  bf16* canon[20];
  for(int i = 0; i < 20; i++) canon[i] = (bf16*)carve((size_t)NEL[i] * 2);

  k_detect<<<dim3(1), 256, 0, stream>>>((const unsigned short*)d_in[0], flag);
  for(int i = 0; i < 20; i++)
    k_conv<<<dim3((NEL[i] + 255) / 256), 256, 0, stream>>>(d_in[i], canon[i], NEL[i], flag);

  const bf16* xp   = canon[0];
  const bf16* tmx  = canon[1];
  const bf16* maas[5] = {canon[2], canon[3], canon[4], canon[5], canon[6]};
  const bf16* w1p  = canon[7];
  const bf16* w2p  = canon[8];
  const bf16* tdec = canon[9];
  const bf16* dw1  = canon[10];
  const bf16* dw2  = canon[11];
  const bf16* up   = canon[12];
  const bf16* lnwp = canon[18];
  const bf16* lnbp = canon[19];

  bf16* WrT = (bf16*)carve(2097152);
  bf16* WkT = (bf16*)carve(2097152);
  bf16* WvT = (bf16*)carve(2097152);
  bf16* WgT = (bf16*)carve(2097152);
  bf16* WoT = (bf16*)carve(2097152);
  k_transpose<<<dim3(32, 32), 256, 0, stream>>>(canon[13], WrT);
  k_transpose<<<dim3(32, 32), 256, 0, stream>>>(canon[14], WkT);
  k_transpose<<<dim3(32, 32), 256, 0, stream>>>(canon[15], WvT);
  k_transpose<<<dim3(32, 32), 256, 0, stream>>>(canon[16], WgT);
  k_transpose<<<dim3(32, 32), 256, 0, stream>>>(canon[17], WoT);

  float* st = (float*)carve(1u << 20);
  size_t FIXED = cur;

  const size_t UNIT = 16864, PAD = 65536;
  int nb, L;
  if(ws_size >= FIXED + (size_t)8192 * UNIT + PAD){ nb = 4; L = 2048; }
  else {
    nb = 1; L = 2048;
    while(L > 128 && ws_size < FIXED + (size_t)L * UNIT + PAD) L >>= 1;
  }
  const int Llog2 = __builtin_ctz((unsigned)L);
  const int nlog2 = Llog2 - 7;
  const int M     = nb * L;
  const size_t Mr = (size_t)M;

  bf16*  xxx    = (bf16*) carve(Mr * 320);
  bf16*  ww1    = (bf16*) carve(Mr * 128);
  float* wse    = (float*)carve(Mr * 32);
  bf16*  mix    = (bf16*) carve(Mr * 2048);
  bf16*  kbuf   = (bf16*) carve(Mr * 2048);
  bf16*  vbuf   = (bf16*) carve(Mr * 2048);
  bf16*  rbuf   = (bf16*) carve(Mr * 2048);
  bf16*  gbuf   = (bf16*) carve(Mr * 2048);
  float* wdec   = (float*)carve(Mr * 4096);
  float* wkvst  = (float*)carve(Mr * 2048);
  float* outw   = wdec;   // chunk2 LDS-stages its wcum tile before overwriting
  bf16*  gated  = mix;    // mix dead after last consumer GEMM

  for(int b0 = 0; b0 < 4; b0 += nb){
    for(int t0 = 0; t0 < Tt; t0 += L){
      gemm_ep<EPI_TANH, true><<<dim3(3, M/64), 256, 0, stream>>>(
          xp, Dd, w1p, 160, xxx, 160, M, 160, Dd, xp, tmx, b0, t0, Llog2, flag);
      for(int c = 0; c < 5; c++){
        gemm_ep<EPI_MIX, false><<<dim3(16, M/64), 256, 0, stream>>>(
            xxx + c * 32, 160, w2p + (size_t)c * 32 * 1024, 1024,
            mix, 1024, M, 1024, 32, xp, maas[c], b0, t0, Llog2, flag);
        if(c == 0){
          gemm_ep<EPI_TANH, false><<<dim3(1, M/64), 256, 0, stream>>>(
              mix, 1024, dw1, 64, ww1, 64, M, 64, 1024, nullptr, nullptr, 0, 0, Llog2, flag);
          gemm_ep<EPI_DECAY, false><<<dim3(16, M/64), 256, 0, stream>>>(
              ww1, 64, dw2, 1024, wdec, 1024, M, 1024, 64, nullptr, tdec, 0, 0, Llog2, flag);
        } else if(c == 1){
          gemm_mfma<GEPI_BF16><<<dim3(8, M/128), 256, 0, stream>>>(mix, WkT, kbuf, flag, 0);
        } else if(c == 2){
          gemm_mfma<GEPI_BF16><<<dim3(8, M/128), 256, 0, stream>>>(mix, WvT, vbuf, flag, 0);
        } else if(c == 3){
          gemm_mfma<GEPI_BF16><<<dim3(8, M/128), 256, 0, stream>>>(mix, WrT, rbuf, flag, 0);
        } else {
          gemm_mfma<GEPI_SILU><<<dim3(8, M/128), 256, 0, stream>>>(mix, WgT, gbuf, flag, 0);
        }
      }
      int nloc = 1 << nlog2;
      k_cumsum<<<dim3(nb * nloc * 4), 256, 0, stream>>>(wdec, wse, nlog2);
      k_chunk1<<<dim3(nb * 16 * nloc), 256, 0, stream>>>(kbuf, vbuf, wdec, wkvst, nlog2);
      k_scan<<<dim3(nb * 16), 256, 0, stream>>>(wkvst, wse, st, b0, (t0 == 0) ? 1 : 0, nlog2);
      k_chunk2<<<dim3(nb * 16 * nloc), 256, 0, stream>>>(rbuf, kbuf, vbuf, wdec, wkvst, up, outw, nlog2);
      k_norm<<<dim3(M), 256, 0, stream>>>(outw, gbuf, lnwp, lnbp, gated);
      if(L == Tt){
        gemm_mfma<GEPI_OUT><<<dim3(8, M/128), 256, 0, stream>>>(gated, WoT, d_out, flag, b0 * Tt);
      } else {
        gemm_ep<EPI_OUTV, false><<<dim3(16, M/64), 256, 0, stream>>>(
            gated, 1024, canon[17], 1024, d_out, 1024, M, 1024, 1024,
            nullptr, nullptr, b0, t0, Llog2, flag);
      }
    }
  }
}

// Round 8
// 1584.414 us; speedup vs baseline: 2.0103x; 1.0719x over previous
//
#include <hip/hip_runtime.h>
#include <hip/hip_bf16.h>
#include <math.h>

typedef __hip_bfloat16 bf16;
typedef __attribute__((ext_vector_type(8))) short short8;
typedef __attribute__((ext_vector_type(4))) float f32x4;

#define Tt 2048
#define Dd 1024
#define Hh 16

__device__ __forceinline__ float b2f(bf16 v){ return __bfloat162float(v); }
__device__ __forceinline__ bf16  f2b(float v){ return __float2bfloat16(v); }

__device__ __forceinline__ int seg_t(int lr, int t0, int Lm1){ return t0 + (lr & Lm1); }
__device__ __forceinline__ size_t seg_grow(int lr, int b0, int t0, int Llog2, int Lm1){
  return ((size_t)(b0 + (lr >> Llog2)) * Tt) + (size_t)seg_t(lr, t0, Lm1);
}

// ---------------------------------------------------------------- dtype detect
__global__ __launch_bounds__(256) void k_detect(const unsigned short* __restrict__ xs,
                                                int* __restrict__ flag){
  __shared__ int bad;
  if(threadIdx.x == 0) bad = 0;
  __syncthreads();
  int local = 0;
  for(int i = threadIdx.x; i < 8192; i += 256){
    unsigned e = (xs[i] >> 7) & 0xFF;
    if(e >= 0xC0) local++;
  }
  if(local) atomicAdd(&bad, local);
  __syncthreads();
  if(threadIdx.x == 0) flag[0] = (bad > 16) ? 1 : 0;   // 1 = inputs are float32
}

// ---------------------------------------------------------------- canonicalize to bf16
__global__ __launch_bounds__(256) void k_conv(const void* __restrict__ src,
                                              bf16* __restrict__ dst, int n,
                                              const int* __restrict__ flag){
  int i = blockIdx.x * 256 + threadIdx.x;
  if(i >= n) return;
  if(flag[0]) dst[i] = f2b(((const float*)src)[i]);
  else        dst[i] = ((const bf16*)src)[i];
}

// ---------------------------------------------------------------- 1024x1024 bf16 transpose
__global__ __launch_bounds__(256) void k_transpose(const bf16* __restrict__ src,
                                                   bf16* __restrict__ dst){
  __shared__ bf16 tile[32][33];
  int bx = blockIdx.x * 32, by = blockIdx.y * 32;
  int tx = threadIdx.x & 31, ty = threadIdx.x >> 5;   // 32 x 8
  for(int r = ty; r < 32; r += 8)
    tile[r][tx] = src[(size_t)(by + r) * 1024 + bx + tx];
  __syncthreads();
  for(int r = ty; r < 32; r += 8)
    dst[(size_t)(bx + r) * 1024 + by + tx] = tile[tx][r];
}

// ---------------------------------------------------------------- MFMA GEMM  C[M][1024] = A[M][1024] @ Bt^T
constexpr int GEPI_BF16 = 0, GEPI_SILU = 1, GEPI_OUT = 2;

template<int EPI>
__global__ __launch_bounds__(256) void gemm_mfma(
    const bf16* __restrict__ A,
    const bf16* __restrict__ Bt,
    void* __restrict__ Cv,
    const int* __restrict__ oflag,
    int rowoff){
  __shared__ short As[128 * 40];
  __shared__ short Bs[128 * 40];
  int tid = threadIdx.x;
  int bn = blockIdx.x * 128;
  int bm = blockIdx.y * 128;
  int w = tid >> 6, lane = tid & 63;
  int wm = (w & 1) * 64, wn = (w >> 1) * 64;
  int m16 = lane & 15, quad = lane >> 4;

  f32x4 acc[4][4];
  #pragma unroll
  for(int mi = 0; mi < 4; mi++)
    #pragma unroll
    for(int ni = 0; ni < 4; ni++)
      acc[mi][ni] = (f32x4){0.f, 0.f, 0.f, 0.f};

  int srow = tid >> 2;
  int sk8  = (tid & 3) * 8;
  const bf16* Ag = A  + (size_t)(bm + srow) * 1024 + sk8;
  const bf16* Bg = Bt + (size_t)(bn + srow) * 1024 + sk8;
  short* Aw = As + srow * 40 + sk8;
  short* Bw = Bs + srow * 40 + sk8;

  for(int kb = 0; kb < 1024; kb += 32){
    #pragma unroll
    for(int rep = 0; rep < 2; rep++){
      *(short8*)(Aw + rep * 64 * 40) = *(const short8*)(Ag + (size_t)rep * 64 * 1024 + kb);
      *(short8*)(Bw + rep * 64 * 40) = *(const short8*)(Bg + (size_t)rep * 64 * 1024 + kb);
    }
    __syncthreads();
    short8 af[4], bfr[4];
    #pragma unroll
    for(int mi = 0; mi < 4; mi++)
      af[mi] = *(const short8*)(As + (wm + mi * 16 + m16) * 40 + quad * 8);
    #pragma unroll
    for(int ni = 0; ni < 4; ni++)
      bfr[ni] = *(const short8*)(Bs + (wn + ni * 16 + m16) * 40 + quad * 8);
    #pragma unroll
    for(int mi = 0; mi < 4; mi++)
      #pragma unroll
      for(int ni = 0; ni < 4; ni++)
        acc[mi][ni] = __builtin_amdgcn_mfma_f32_16x16x32_bf16(af[mi], bfr[ni], acc[mi][ni], 0, 0, 0);
    __syncthreads();
  }
  #pragma unroll
  for(int mi = 0; mi < 4; mi++){
    #pragma unroll
    for(int ni = 0; ni < 4; ni++){
      #pragma unroll
      for(int r = 0; r < 4; r++){
        int row = bm + wm + mi * 16 + quad * 4 + r;
        int col = bn + wn + ni * 16 + m16;
        float v = acc[mi][ni][r];
        if constexpr(EPI == GEPI_BF16){
          ((bf16*)Cv)[(size_t)row * 1024 + col] = f2b(v);
        } else if constexpr(EPI == GEPI_SILU){
          ((bf16*)Cv)[(size_t)row * 1024 + col] = f2b(v / (1.f + expf(-v)));
        } else { // GEPI_OUT
          size_t off = (size_t)(row + rowoff) * 1024 + col;
          if(oflag[0]) ((float*)Cv)[off] = v;
          else         ((bf16*)Cv)[off]  = f2b(v);
        }
      }
    }
  }
}

// ---------------------------------------------------------------- small VALU GEMM
constexpr int EPI_BF16 = 0, EPI_TANH = 1, EPI_SILU = 2, EPI_MIX = 3, EPI_DECAY = 4, EPI_OUTV = 5;
#define BM 64
#define BN 64
#define BK 16

template<int EPI, bool AFUSE>
__global__ __launch_bounds__(256) void gemm_ep(
    const bf16* __restrict__ A, int lda,
    const bf16* __restrict__ Bm, int ldb,
    void* __restrict__ Cv, int ldc,
    int Mdim, int Ndim, int Kdim,
    const bf16* __restrict__ xg, const bf16* __restrict__ e_w,
    int b0, int t0, int Llog2, const int* __restrict__ oflag){
  const int Lm1 = (1 << Llog2) - 1;
  __shared__ float As[BM][BK + 1];
  __shared__ float Bs[BK][BN + 4];
  int tid = threadIdx.x;
  int tx = tid & 15, ty = tid >> 4;
  int bm = blockIdx.y * BM, bn = blockIdx.x * BN;
  float acc[4][4] = {};
  for(int kb = 0; kb < Kdim; kb += BK){
    {
      int lr = tid >> 2;
      int lc = (tid & 3) * 4;
      int gr = bm + lr;
      #pragma unroll
      for(int q = 0; q < 4; q++){
        int gc = kb + lc + q;
        float av = 0.f;
        if(gr < Mdim && gc < Kdim){
          if constexpr(AFUSE){
            size_t grow = seg_grow(gr, b0, t0, Llog2, Lm1);
            int tl = seg_t(gr, t0, Lm1);
            float xc = b2f(xg[grow * Dd + gc]);
            float xp = tl ? b2f(xg[(grow - 1) * Dd + gc]) : 0.f;
            av = xc + (xp - xc) * b2f(e_w[gc]);
          } else {
            av = b2f(A[(size_t)gr * lda + gc]);
          }
        }
        As[lr][lc + q] = av;
      }
    }
    {
      int lr = tid >> 4;
      int lc = (tid & 15) * 4;
      #pragma unroll
      for(int q = 0; q < 4; q++){
        int gr = kb + lr; int gc = bn + lc + q;
        Bs[lr][lc + q] = (gr < Kdim && gc < Ndim) ? b2f(Bm[(size_t)gr * ldb + gc]) : 0.f;
      }
    }
    __syncthreads();
    #pragma unroll
    for(int kk = 0; kk < BK; kk++){
      float ar[4], br[4];
      #pragma unroll
      for(int q = 0; q < 4; q++) ar[q] = As[ty * 4 + q][kk];
      #pragma unroll
      for(int q = 0; q < 4; q++) br[q] = Bs[kk][tx * 4 + q];
      #pragma unroll
      for(int mi = 0; mi < 4; mi++)
        #pragma unroll
        for(int ni = 0; ni < 4; ni++)
          acc[mi][ni] += ar[mi] * br[ni];
    }
    __syncthreads();
  }
  #pragma unroll
  for(int mi = 0; mi < 4; mi++){
    int row = bm + ty * 4 + mi;
    if(row >= Mdim) continue;
    #pragma unroll
    for(int ni = 0; ni < 4; ni++){
      int col = bn + tx * 4 + ni;
      if(col >= Ndim) continue;
      float vacc = acc[mi][ni];
      size_t off = (size_t)row * ldc + col;
      if constexpr(EPI == EPI_BF16){
        ((bf16*)Cv)[off] = f2b(vacc);
      } else if constexpr(EPI == EPI_TANH){
        ((bf16*)Cv)[off] = f2b(tanhf(vacc));
      } else if constexpr(EPI == EPI_SILU){
        ((bf16*)Cv)[off] = f2b(vacc / (1.f + expf(-vacc)));
      } else if constexpr(EPI == EPI_MIX){
        size_t grow = seg_grow(row, b0, t0, Llog2, Lm1);
        int tl = seg_t(row, t0, Lm1);
        float xc = b2f(xg[grow * Dd + col]);
        float xp = tl ? b2f(xg[(grow - 1) * Dd + col]) : 0.f;
        ((bf16*)Cv)[off] = f2b(xc + (xp - xc) * (b2f(e_w[col]) + vacc));
      } else if constexpr(EPI == EPI_DECAY){
        float td = b2f(e_w[col]) + vacc;
        ((float*)Cv)[off] = fmaxf(-expf(td), -5.2983173665480363f);
      } else { // EPI_OUTV
        size_t grow = seg_grow(row, b0, t0, Llog2, Lm1);
        size_t go = grow * Dd + col;
        if(oflag[0]) ((float*)Cv)[go] = vacc;
        else         ((bf16*)Cv)[go]  = f2b(vacc);
      }
    }
  }
}

// ---------------------------------------------------------------- cumsum (in place wlog->wcum) + wse
__global__ __launch_bounds__(256) void k_cumsum(float* __restrict__ wd,
                                                float* __restrict__ wse,
                                                int nlog2){
  int blk = blockIdx.x;
  int dg = blk & 3; int rest = blk >> 2;
  int nmask = (1 << nlog2) - 1;
  int ln = rest & nmask; int bp = rest >> nlog2;
  int d = dg * 256 + threadIdx.x;
  size_t rowbase = (((size_t)bp << nlog2) + ln) * 128;
  size_t base = rowbase * Dd + d;
  float c = 0.f;
  for(int t = 0; t < 128; t++){
    size_t ix = base + (size_t)t * Dd;
    c += wd[ix];
    wd[ix] = c;
  }
  int h = d >> 6, k0 = d & 63;
  wse[((((size_t)bp * Hh + h) << nlog2) | ln) * 64 + k0] = __expf(fminf(c, 0.f));
}

// ---------------------------------------------------------------- chunk1: wkv = (k*exp(ws-cum))^T @ v
__global__ __launch_bounds__(256) void k_chunk1(const bf16* __restrict__ kb,
                                                const bf16* __restrict__ vb,
                                                const float* __restrict__ wcum,
                                                float* __restrict__ wkv,
                                                int nlog2){
  __shared__ __align__(16) char smem[65536];
  bf16*  kt = (bf16*)smem;
  bf16*  vt = (bf16*)(smem + 16384);
  float* cs = (float*)(smem + 32768);
  int tid = threadIdx.x, blk = blockIdx.x;
  int nmask = (1 << nlog2) - 1;
  int ln = blk & nmask; int rest = blk >> nlog2;
  int h = rest & 15; int bp = rest >> 4;
  size_t rowbase = (((size_t)bp << nlog2) + ln) * 128;
  size_t gbase = rowbase * Dd + h * 64;
  for(int r = 0; r < 32; r++){
    int idx = r * 256 + tid;
    int t0 = idx >> 6, k0 = idx & 63;
    size_t gi = gbase + (size_t)t0 * Dd + k0;
    kt[idx] = kb[gi];
    vt[idx] = vb[gi];
    cs[idx] = wcum[gi];
  }
  __syncthreads();
  for(int r = 0; r < 32; r++){
    int idx = r * 256 + tid;
    int k0 = idx & 63;
    kt[idx] = f2b(b2f(kt[idx]) * __expf(fminf(cs[127 * 64 + k0] - cs[idx], 0.f)));
  }
  __syncthreads();
  int tx = tid & 15, ty = tid >> 4;
  float acc[4][4] = {};
  for(int t = 0; t < 128; t++){
    float kr[4], vr[4];
    #pragma unroll
    for(int q = 0; q < 4; q++) kr[q] = b2f(kt[t * 64 + ty * 4 + q]);
    #pragma unroll
    for(int q = 0; q < 4; q++) vr[q] = b2f(vt[t * 64 + tx * 4 + q]);
    #pragma unroll
    for(int i2 = 0; i2 < 4; i2++)
      #pragma unroll
      for(int j2 = 0; j2 < 4; j2++)
        acc[i2][j2] += kr[i2] * vr[j2];
  }
  size_t obase = (size_t)blk * 4096;
  #pragma unroll
  for(int i2 = 0; i2 < 4; i2++)
    #pragma unroll
    for(int j2 = 0; j2 < 4; j2++)
      wkv[obase + (ty * 4 + i2) * 64 + tx * 4 + j2] = acc[i2][j2];
}

// ---------------------------------------------------------------- state scan, in place, carry in st
__global__ __launch_bounds__(256) void k_scan(float* __restrict__ buf,
                                              const float* __restrict__ wse,
                                              float* __restrict__ st,
                                              int b0, int firstseg, int nlog2){
  int blk = blockIdx.x;
  int h = blk & 15, bp = blk >> 4;
  int tid = threadIdx.x;
  size_t stbase = ((size_t)(b0 + bp) * Hh + h) * 4096;
  int nloc = 1 << nlog2;
  float s[16];
  #pragma unroll
  for(int r = 0; r < 16; r++)
    s[r] = firstseg ? 0.f : st[stbase + r * 256 + tid];
  for(int ln = 0; ln < nloc; ln++){
    size_t idx = (((size_t)bp * Hh + h) << nlog2) | ln;
    size_t base = idx * 4096;
    const float* wsp = wse + idx * 64;
    #pragma unroll
    for(int r = 0; r < 16; r++){
      int e = r * 256 + tid;
      float tmp = buf[base + e];
      buf[base + e] = s[r];
      s[r] = s[r] * wsp[e >> 6] + tmp;
    }
  }
  #pragma unroll
  for(int r = 0; r < 16; r++)
    st[stbase + r * 256 + tid] = s[r];
}

// ---------------------------------------------------------------- chunk2: TRANSPOSED LDS layout
// Per-lane-indexed arrays (r, wcum) stored transposed [k][i] so column reads
// become bank-parallel (banks 0..31) instead of 32-way single-bank serial.
// Wave-uniform reads (kt[jj], cs_T[.,jj]) remain broadcasts. Same math as R7.
__global__ __launch_bounds__(256, 2) void k_chunk2(
    const bf16* __restrict__ rb, const bf16* __restrict__ kb,
    const bf16* __restrict__ vb, const float* __restrict__ wcum,
    const float* __restrict__ states, const bf16* __restrict__ u,
    float* __restrict__ outw, int nlog2){
  __shared__ __align__(16) char smem[65536];
  bf16*  kt   = (bf16*)smem;             // [128][64] row-major
  bf16*  rt_T = (bf16*)(smem + 16384);   // [64][128] transposed: rt_T[k*128+i]
  float* cs_T = (float*)(smem + 32768);  // [64][128] transposed: cs_T[k*128+i]
  int tid = threadIdx.x, blk = blockIdx.x;
  int nmask = (1 << nlog2) - 1;
  int ln = blk & nmask; int rest = blk >> nlog2;
  int h = rest & 15; int bp = rest >> 4;
  size_t rowbase = (((size_t)bp << nlog2) + ln) * 128;
  size_t gbase = rowbase * Dd + h * 64;
  for(int r = 0; r < 32; r++){
    int idx = r * 256 + tid;
    int t0 = idx >> 6, k0 = idx & 63;
    size_t gi = gbase + (size_t)t0 * Dd + k0;
    kt[t0 * 64 + k0]   = kb[gi];
    rt_T[k0 * 128 + t0] = rb[gi];
    cs_T[k0 * 128 + t0] = wcum[gi];
  }
  __syncthreads();
  int i = tid >> 1, hf = tid & 1;
  float rwreg[32];
  #pragma unroll
  for(int k2 = 0; k2 < 32; k2++){
    int kk = hf * 32 + k2;
    float cp = i ? cs_T[kk * 128 + (i - 1)] : 0.f;
    rwreg[k2] = b2f(rt_T[kk * 128 + i]) * __expf(fminf(cp, 0.f));
  }
  float a[64];
  {
    for(int jt = 0; jt < 8; jt++){
      float a8[8];
      #pragma unroll
      for(int q = 0; q < 8; q++) a8[q] = 0.f;
      int jbase = hf * 64 + jt * 8;
      if(jbase < i){
        for(int k = 0; k < 64; k++){
          float rk  = b2f(rt_T[k * 128 + i]);              // bank-parallel
          float cik = i ? cs_T[k * 128 + (i - 1)] : 0.f;   // bank-parallel
          #pragma unroll
          for(int q = 0; q < 8; q++){
            int jj = jbase + q;
            if(jj < i)
              a8[q] += rk * b2f(kt[jj * 64 + k]) * __expf(fminf(cik - cs_T[k * 128 + jj], 0.f));
          }
        }
      }
      #pragma unroll
      for(int q = 0; q < 8; q++) a[jt * 8 + q] = a8[q];    // sequential write
    }
    int jd = i - hf * 64;                    // diagonal (owner half)
    if(jd >= 0 && jd < 64){
      float s = 0.f;
      for(int k = 0; k < 64; k++)
        s += b2f(rt_T[k * 128 + i]) * b2f(u[h * 64 + k]) * b2f(kt[i * 64 + k]);
      a[jd] = s;
    }
  }
  __syncthreads();
  bf16*  vt  = (bf16*)smem;            // over kt
  float* ssm = (float*)(smem + 16384); // over rt_T
  for(int r = 0; r < 32; r++){
    int idx = r * 256 + tid;
    int t0 = idx >> 6, k0 = idx & 63;
    vt[idx] = vb[gbase + (size_t)t0 * Dd + k0];
  }
  for(int r = 0; r < 16; r++){
    int idx = r * 256 + tid;
    ssm[idx] = states[(size_t)blk * 4096 + idx];
  }
  __syncthreads();
  for(int v = 0; v < 64; v++){
    float p = 0.f;
    #pragma unroll
    for(int j = 0; j < 64; j++)
      p += a[j] * b2f(vt[(hf * 64 + j) * 64 + v]);
    #pragma unroll
    for(int k2 = 0; k2 < 32; k2++)
      p += rwreg[k2] * ssm[(hf * 32 + k2) * 64 + v];
    float tot = p + __shfl_xor(p, 1);
    if(hf == 0) outw[gbase + (size_t)i * Dd + v] = tot;
  }
}

// ---------------------------------------------------------------- groupnorm(64) + gate
__global__ __launch_bounds__(256) void k_norm(const float* __restrict__ outw,
                                              const bf16* __restrict__ gb,
                                              const bf16* __restrict__ lnw,
                                              const bf16* __restrict__ lnb,
                                              bf16* __restrict__ gated){
  int lr = blockIdx.x;
  int wv = threadIdx.x >> 6, lane = threadIdx.x & 63;
  for(int hh = wv; hh < Hh; hh += 4){
    size_t ix = (size_t)lr * Dd + hh * 64 + lane;
    float xv = outw[ix];
    float s1 = xv, s2 = xv * xv;
    #pragma unroll
    for(int off = 32; off > 0; off >>= 1){
      s1 += __shfl_xor(s1, off);
      s2 += __shfl_xor(s2, off);
    }
    float mu  = s1 * 0.015625f;
    float var = s2 * 0.015625f - mu * mu;
    float inv = rsqrtf(var + 6.4e-4f);
    float og  = (xv - mu) * inv * b2f(lnw[hh * 64 + lane]) + b2f(lnb[hh * 64 + lane]);
    gated[ix] = f2b(og * b2f(gb[ix]));
  }
}

// ---------------------------------------------------------------- host
extern "C" void kernel_launch(void* const* d_in, const int* in_sizes, int n_in,
                              void* d_out, int out_size, void* d_ws, size_t ws_size,
                              hipStream_t stream){
  char* W = (char*)d_ws;
  size_t cur = 0;
  auto carve = [&](size_t bytes) -> char* {
    char* p = W + cur;
    cur = (cur + bytes + 255) & ~(size_t)255;
    return p;
  };

  int* flag = (int*)carve(4096);
  static const int NEL[20] = {8388608, 1024, 1024, 1024, 1024, 1024, 1024,
                              163840, 163840, 1024, 65536, 65536, 1024,
                              1048576, 1048576, 1048576, 1048576, 1048576,
                              1024, 1024};
  bf16* canon[20];
  for(int i = 0; i < 20; i++) canon[i] = (bf16*)carve((size_t)NEL[i] * 2);

  k_detect<<<dim3(1), 256, 0, stream>>>((const unsigned short*)d_in[0], flag);
  for(int i = 0; i < 20; i++)
    k_conv<<<dim3((NEL[i] + 255) / 256), 256, 0, stream>>>(d_in[i], canon[i], NEL[i], flag);

  const bf16* xp   = canon[0];
  const bf16* tmx  = canon[1];
  const bf16* maas[5] = {canon[2], canon[3], canon[4], canon[5], canon[6]};
  const bf16* w1p  = canon[7];
  const bf16* w2p  = canon[8];
  const bf16* tdec = canon[9];
  const bf16* dw1  = canon[10];
  const bf16* dw2  = canon[11];
  const bf16* up   = canon[12];
  const bf16* lnwp = canon[18];
  const bf16* lnbp = canon[19];

  bf16* WrT = (bf16*)carve(2097152);
  bf16* WkT = (bf16*)carve(2097152);
  bf16* WvT = (bf16*)carve(2097152);
  bf16* WgT = (bf16*)carve(2097152);
  bf16* WoT = (bf16*)carve(2097152);
  k_transpose<<<dim3(32, 32), 256, 0, stream>>>(canon[13], WrT);
  k_transpose<<<dim3(32, 32), 256, 0, stream>>>(canon[14], WkT);
  k_transpose<<<dim3(32, 32), 256, 0, stream>>>(canon[15], WvT);
  k_transpose<<<dim3(32, 32), 256, 0, stream>>>(canon[16], WgT);
  k_transpose<<<dim3(32, 32), 256, 0, stream>>>(canon[17], WoT);

  float* st = (float*)carve(1u << 20);
  size_t FIXED = cur;

  const size_t UNIT = 16864, PAD = 65536;
  int nb, L;
  if(ws_size >= FIXED + (size_t)8192 * UNIT + PAD){ nb = 4; L = 2048; }
  else {
    nb = 1; L = 2048;
    while(L > 128 && ws_size < FIXED + (size_t)L * UNIT + PAD) L >>= 1;
  }
  const int Llog2 = __builtin_ctz((unsigned)L);
  const int nlog2 = Llog2 - 7;
  const int M     = nb * L;
  const size_t Mr = (size_t)M;

  bf16*  xxx    = (bf16*) carve(Mr * 320);
  bf16*  ww1    = (bf16*) carve(Mr * 128);
  float* wse    = (float*)carve(Mr * 32);
  bf16*  mix    = (bf16*) carve(Mr * 2048);
  bf16*  kbuf   = (bf16*) carve(Mr * 2048);
  bf16*  vbuf   = (bf16*) carve(Mr * 2048);
  bf16*  rbuf   = (bf16*) carve(Mr * 2048);
  bf16*  gbuf   = (bf16*) carve(Mr * 2048);
  float* wdec   = (float*)carve(Mr * 4096);
  float* wkvst  = (float*)carve(Mr * 2048);
  float* outw   = wdec;   // chunk2 LDS-stages its wcum tile before overwriting
  bf16*  gated  = mix;    // mix dead after last consumer GEMM

  for(int b0 = 0; b0 < 4; b0 += nb){
    for(int t0 = 0; t0 < Tt; t0 += L){
      gemm_ep<EPI_TANH, true><<<dim3(3, M/64), 256, 0, stream>>>(
          xp, Dd, w1p, 160, xxx, 160, M, 160, Dd, xp, tmx, b0, t0, Llog2, flag);
      for(int c = 0; c < 5; c++){
        gemm_ep<EPI_MIX, false><<<dim3(16, M/64), 256, 0, stream>>>(
            xxx + c * 32, 160, w2p + (size_t)c * 32 * 1024, 1024,
            mix, 1024, M, 1024, 32, xp, maas[c], b0, t0, Llog2, flag);
        if(c == 0){
          gemm_ep<EPI_TANH, false><<<dim3(1, M/64), 256, 0, stream>>>(
              mix, 1024, dw1, 64, ww1, 64, M, 64, 1024, nullptr, nullptr, 0, 0, Llog2, flag);
          gemm_ep<EPI_DECAY, false><<<dim3(16, M/64), 256, 0, stream>>>(
              ww1, 64, dw2, 1024, wdec, 1024, M, 1024, 64, nullptr, tdec, 0, 0, Llog2, flag);
        } else if(c == 1){
          gemm_mfma<GEPI_BF16><<<dim3(8, M/128), 256, 0, stream>>>(mix, WkT, kbuf, flag, 0);
        } else if(c == 2){
          gemm_mfma<GEPI_BF16><<<dim3(8, M/128), 256, 0, stream>>>(mix, WvT, vbuf, flag, 0);
        } else if(c == 3){
          gemm_mfma<GEPI_BF16><<<dim3(8, M/128), 256, 0, stream>>>(mix, WrT, rbuf, flag, 0);
        } else {
          gemm_mfma<GEPI_SILU><<<dim3(8, M/128), 256, 0, stream>>>(mix, WgT, gbuf, flag, 0);
        }
      }
      int nloc = 1 << nlog2;
      k_cumsum<<<dim3(nb * nloc * 4), 256, 0, stream>>>(wdec, wse, nlog2);
      k_chunk1<<<dim3(nb * 16 * nloc), 256, 0, stream>>>(kbuf, vbuf, wdec, wkvst, nlog2);
      k_scan<<<dim3(nb * 16), 256, 0, stream>>>(wkvst, wse, st, b0, (t0 == 0) ? 1 : 0, nlog2);
      k_chunk2<<<dim3(nb * 16 * nloc), 256, 0, stream>>>(rbuf, kbuf, vbuf, wdec, wkvst, up, outw, nlog2);
      k_norm<<<dim3(M), 256, 0, stream>>>(outw, gbuf, lnwp, lnbp, gated);
      if(L == Tt){
        gemm_mfma<GEPI_OUT><<<dim3(8, M/128), 256, 0, stream>>>(gated, WoT, d_out, flag, b0 * Tt);
      } else {
        gemm_ep<EPI_OUTV, false><<<dim3(16, M/64), 256, 0, stream>>>(
            gated, 1024, canon[17], 1024, d_out, 1024, M, 1024, 1024,
            nullptr, nullptr, b0, t0, Llog2, flag);
      }
    }
  }
}

// Round 9
// 996.634 us; speedup vs baseline: 3.1959x; 1.5898x over previous
//
#include <hip/hip_runtime.h>
#include <hip/hip_bf16.h>
#include <math.h>

typedef __hip_bfloat16 bf16;
typedef __attribute__((ext_vector_type(8))) short short8;
typedef __attribute__((ext_vector_type(4))) float f32x4;

#define Tt 2048
#define Dd 1024
#define Hh 16

__device__ __forceinline__ float b2f(bf16 v){ return __bfloat162float(v); }
__device__ __forceinline__ bf16  f2b(float v){ return __float2bfloat16(v); }

__device__ __forceinline__ int seg_t(int lr, int t0, int Lm1){ return t0 + (lr & Lm1); }
__device__ __forceinline__ size_t seg_grow(int lr, int b0, int t0, int Llog2, int Lm1){
  return ((size_t)(b0 + (lr >> Llog2)) * Tt) + (size_t)seg_t(lr, t0, Lm1);
}

// ---------------------------------------------------------------- dtype detect
__global__ __launch_bounds__(256) void k_detect(const unsigned short* __restrict__ xs,
                                                int* __restrict__ flag){
  __shared__ int bad;
  if(threadIdx.x == 0) bad = 0;
  __syncthreads();
  int local = 0;
  for(int i = threadIdx.x; i < 8192; i += 256){
    unsigned e = (xs[i] >> 7) & 0xFF;
    if(e >= 0xC0) local++;
  }
  if(local) atomicAdd(&bad, local);
  __syncthreads();
  if(threadIdx.x == 0) flag[0] = (bad > 16) ? 1 : 0;   // 1 = inputs are float32
}

// ---------------------------------------------------------------- canonicalize to bf16
__global__ __launch_bounds__(256) void k_conv(const void* __restrict__ src,
                                              bf16* __restrict__ dst, int n,
                                              const int* __restrict__ flag){
  int i = blockIdx.x * 256 + threadIdx.x;
  if(i >= n) return;
  if(flag[0]) dst[i] = f2b(((const float*)src)[i]);
  else        dst[i] = ((const bf16*)src)[i];
}

// ---------------------------------------------------------------- 1024x1024 bf16 transpose
__global__ __launch_bounds__(256) void k_transpose(const bf16* __restrict__ src,
                                                   bf16* __restrict__ dst){
  __shared__ bf16 tile[32][33];
  int bx = blockIdx.x * 32, by = blockIdx.y * 32;
  int tx = threadIdx.x & 31, ty = threadIdx.x >> 5;   // 32 x 8
  for(int r = ty; r < 32; r += 8)
    tile[r][tx] = src[(size_t)(by + r) * 1024 + bx + tx];
  __syncthreads();
  for(int r = ty; r < 32; r += 8)
    dst[(size_t)(bx + r) * 1024 + by + tx] = tile[tx][r];
}

// ---------------------------------------------------------------- MFMA GEMM  C[M][1024] = A[M][1024] @ Bt^T
constexpr int GEPI_BF16 = 0, GEPI_SILU = 1, GEPI_OUT = 2;

template<int EPI>
__global__ __launch_bounds__(256) void gemm_mfma(
    const bf16* __restrict__ A,
    const bf16* __restrict__ Bt,
    void* __restrict__ Cv,
    const int* __restrict__ oflag,
    int rowoff){
  __shared__ short As[128 * 40];
  __shared__ short Bs[128 * 40];
  int tid = threadIdx.x;
  int bn = blockIdx.x * 128;
  int bm = blockIdx.y * 128;
  int w = tid >> 6, lane = tid & 63;
  int wm = (w & 1) * 64, wn = (w >> 1) * 64;
  int m16 = lane & 15, quad = lane >> 4;

  f32x4 acc[4][4];
  #pragma unroll
  for(int mi = 0; mi < 4; mi++)
    #pragma unroll
    for(int ni = 0; ni < 4; ni++)
      acc[mi][ni] = (f32x4){0.f, 0.f, 0.f, 0.f};

  int srow = tid >> 2;
  int sk8  = (tid & 3) * 8;
  const bf16* Ag = A  + (size_t)(bm + srow) * 1024 + sk8;
  const bf16* Bg = Bt + (size_t)(bn + srow) * 1024 + sk8;
  short* Aw = As + srow * 40 + sk8;
  short* Bw = Bs + srow * 40 + sk8;

  for(int kb = 0; kb < 1024; kb += 32){
    #pragma unroll
    for(int rep = 0; rep < 2; rep++){
      *(short8*)(Aw + rep * 64 * 40) = *(const short8*)(Ag + (size_t)rep * 64 * 1024 + kb);
      *(short8*)(Bw + rep * 64 * 40) = *(const short8*)(Bg + (size_t)rep * 64 * 1024 + kb);
    }
    __syncthreads();
    short8 af[4], bfr[4];
    #pragma unroll
    for(int mi = 0; mi < 4; mi++)
      af[mi] = *(const short8*)(As + (wm + mi * 16 + m16) * 40 + quad * 8);
    #pragma unroll
    for(int ni = 0; ni < 4; ni++)
      bfr[ni] = *(const short8*)(Bs + (wn + ni * 16 + m16) * 40 + quad * 8);
    #pragma unroll
    for(int mi = 0; mi < 4; mi++)
      #pragma unroll
      for(int ni = 0; ni < 4; ni++)
        acc[mi][ni] = __builtin_amdgcn_mfma_f32_16x16x32_bf16(af[mi], bfr[ni], acc[mi][ni], 0, 0, 0);
    __syncthreads();
  }
  #pragma unroll
  for(int mi = 0; mi < 4; mi++){
    #pragma unroll
    for(int ni = 0; ni < 4; ni++){
      #pragma unroll
      for(int r = 0; r < 4; r++){
        int row = bm + wm + mi * 16 + quad * 4 + r;
        int col = bn + wn + ni * 16 + m16;
        float v = acc[mi][ni][r];
        if constexpr(EPI == GEPI_BF16){
          ((bf16*)Cv)[(size_t)row * 1024 + col] = f2b(v);
        } else if constexpr(EPI == GEPI_SILU){
          ((bf16*)Cv)[(size_t)row * 1024 + col] = f2b(v / (1.f + expf(-v)));
        } else { // GEPI_OUT
          size_t off = (size_t)(row + rowoff) * 1024 + col;
          if(oflag[0]) ((float*)Cv)[off] = v;
          else         ((bf16*)Cv)[off]  = f2b(v);
        }
      }
    }
  }
}

// ---------------------------------------------------------------- small VALU GEMM
constexpr int EPI_BF16 = 0, EPI_TANH = 1, EPI_SILU = 2, EPI_MIX = 3, EPI_DECAY = 4, EPI_OUTV = 5;
#define BM 64
#define BN 64
#define BK 16

template<int EPI, bool AFUSE>
__global__ __launch_bounds__(256) void gemm_ep(
    const bf16* __restrict__ A, int lda,
    const bf16* __restrict__ Bm, int ldb,
    void* __restrict__ Cv, int ldc,
    int Mdim, int Ndim, int Kdim,
    const bf16* __restrict__ xg, const bf16* __restrict__ e_w,
    int b0, int t0, int Llog2, const int* __restrict__ oflag){
  const int Lm1 = (1 << Llog2) - 1;
  __shared__ float As[BM][BK + 1];
  __shared__ float Bs[BK][BN + 4];
  int tid = threadIdx.x;
  int tx = tid & 15, ty = tid >> 4;
  int bm = blockIdx.y * BM, bn = blockIdx.x * BN;
  float acc[4][4] = {};
  for(int kb = 0; kb < Kdim; kb += BK){
    {
      int lr = tid >> 2;
      int lc = (tid & 3) * 4;
      int gr = bm + lr;
      #pragma unroll
      for(int q = 0; q < 4; q++){
        int gc = kb + lc + q;
        float av = 0.f;
        if(gr < Mdim && gc < Kdim){
          if constexpr(AFUSE){
            size_t grow = seg_grow(gr, b0, t0, Llog2, Lm1);
            int tl = seg_t(gr, t0, Lm1);
            float xc = b2f(xg[grow * Dd + gc]);
            float xp = tl ? b2f(xg[(grow - 1) * Dd + gc]) : 0.f;
            av = xc + (xp - xc) * b2f(e_w[gc]);
          } else {
            av = b2f(A[(size_t)gr * lda + gc]);
          }
        }
        As[lr][lc + q] = av;
      }
    }
    {
      int lr = tid >> 4;
      int lc = (tid & 15) * 4;
      #pragma unroll
      for(int q = 0; q < 4; q++){
        int gr = kb + lr; int gc = bn + lc + q;
        Bs[lr][lc + q] = (gr < Kdim && gc < Ndim) ? b2f(Bm[(size_t)gr * ldb + gc]) : 0.f;
      }
    }
    __syncthreads();
    #pragma unroll
    for(int kk = 0; kk < BK; kk++){
      float ar[4], br[4];
      #pragma unroll
      for(int q = 0; q < 4; q++) ar[q] = As[ty * 4 + q][kk];
      #pragma unroll
      for(int q = 0; q < 4; q++) br[q] = Bs[kk][tx * 4 + q];
      #pragma unroll
      for(int mi = 0; mi < 4; mi++)
        #pragma unroll
        for(int ni = 0; ni < 4; ni++)
          acc[mi][ni] += ar[mi] * br[ni];
    }
    __syncthreads();
  }
  #pragma unroll
  for(int mi = 0; mi < 4; mi++){
    int row = bm + ty * 4 + mi;
    if(row >= Mdim) continue;
    #pragma unroll
    for(int ni = 0; ni < 4; ni++){
      int col = bn + tx * 4 + ni;
      if(col >= Ndim) continue;
      float vacc = acc[mi][ni];
      size_t off = (size_t)row * ldc + col;
      if constexpr(EPI == EPI_BF16){
        ((bf16*)Cv)[off] = f2b(vacc);
      } else if constexpr(EPI == EPI_TANH){
        ((bf16*)Cv)[off] = f2b(tanhf(vacc));
      } else if constexpr(EPI == EPI_SILU){
        ((bf16*)Cv)[off] = f2b(vacc / (1.f + expf(-vacc)));
      } else if constexpr(EPI == EPI_MIX){
        size_t grow = seg_grow(row, b0, t0, Llog2, Lm1);
        int tl = seg_t(row, t0, Lm1);
        float xc = b2f(xg[grow * Dd + col]);
        float xp = tl ? b2f(xg[(grow - 1) * Dd + col]) : 0.f;
        ((bf16*)Cv)[off] = f2b(xc + (xp - xc) * (b2f(e_w[col]) + vacc));
      } else if constexpr(EPI == EPI_DECAY){
        float td = b2f(e_w[col]) + vacc;
        ((float*)Cv)[off] = fmaxf(-expf(td), -5.2983173665480363f);
      } else { // EPI_OUTV
        size_t grow = seg_grow(row, b0, t0, Llog2, Lm1);
        size_t go = grow * Dd + col;
        if(oflag[0]) ((float*)Cv)[go] = vacc;
        else         ((bf16*)Cv)[go]  = f2b(vacc);
      }
    }
  }
}

// ---------------------------------------------------------------- cumsum (in place wlog->wcum) + wse
__global__ __launch_bounds__(256) void k_cumsum(float* __restrict__ wd,
                                                float* __restrict__ wse,
                                                int nlog2){
  int blk = blockIdx.x;
  int dg = blk & 3; int rest = blk >> 2;
  int nmask = (1 << nlog2) - 1;
  int ln = rest & nmask; int bp = rest >> nlog2;
  int d = dg * 256 + threadIdx.x;
  size_t rowbase = (((size_t)bp << nlog2) + ln) * 128;
  size_t base = rowbase * Dd + d;
  float c = 0.f;
  for(int t = 0; t < 128; t++){
    size_t ix = base + (size_t)t * Dd;
    c += wd[ix];
    wd[ix] = c;
  }
  int h = d >> 6, k0 = d & 63;
  wse[((((size_t)bp * Hh + h) << nlog2) | ln) * 64 + k0] = __expf(fminf(c, 0.f));
}

// ---------------------------------------------------------------- chunk1: wkv = (k*exp(ws-cum))^T @ v
__global__ __launch_bounds__(256) void k_chunk1(const bf16* __restrict__ kb,
                                                const bf16* __restrict__ vb,
                                                const float* __restrict__ wcum,
                                                float* __restrict__ wkv,
                                                int nlog2){
  __shared__ __align__(16) char smem[65536];
  bf16*  kt = (bf16*)smem;
  bf16*  vt = (bf16*)(smem + 16384);
  float* cs = (float*)(smem + 32768);
  int tid = threadIdx.x, blk = blockIdx.x;
  int nmask = (1 << nlog2) - 1;
  int ln = blk & nmask; int rest = blk >> nlog2;
  int h = rest & 15; int bp = rest >> 4;
  size_t rowbase = (((size_t)bp << nlog2) + ln) * 128;
  size_t gbase = rowbase * Dd + h * 64;
  for(int r = 0; r < 32; r++){
    int idx = r * 256 + tid;
    int t0 = idx >> 6, k0 = idx & 63;
    size_t gi = gbase + (size_t)t0 * Dd + k0;
    kt[idx] = kb[gi];
    vt[idx] = vb[gi];
    cs[idx] = wcum[gi];
  }
  __syncthreads();
  for(int r = 0; r < 32; r++){
    int idx = r * 256 + tid;
    int k0 = idx & 63;
    kt[idx] = f2b(b2f(kt[idx]) * __expf(fminf(cs[127 * 64 + k0] - cs[idx], 0.f)));
  }
  __syncthreads();
  int tx = tid & 15, ty = tid >> 4;
  float acc[4][4] = {};
  for(int t = 0; t < 128; t++){
    float kr[4], vr[4];
    #pragma unroll
    for(int q = 0; q < 4; q++) kr[q] = b2f(kt[t * 64 + ty * 4 + q]);
    #pragma unroll
    for(int q = 0; q < 4; q++) vr[q] = b2f(vt[t * 64 + tx * 4 + q]);
    #pragma unroll
    for(int i2 = 0; i2 < 4; i2++)
      #pragma unroll
      for(int j2 = 0; j2 < 4; j2++)
        acc[i2][j2] += kr[i2] * vr[j2];
  }
  size_t obase = (size_t)blk * 4096;
  #pragma unroll
  for(int i2 = 0; i2 < 4; i2++)
    #pragma unroll
    for(int j2 = 0; j2 < 4; j2++)
      wkv[obase + (ty * 4 + i2) * 64 + tx * 4 + j2] = acc[i2][j2];
}

// ---------------------------------------------------------------- state scan, in place, carry in st
__global__ __launch_bounds__(256) void k_scan(float* __restrict__ buf,
                                              const float* __restrict__ wse,
                                              float* __restrict__ st,
                                              int b0, int firstseg, int nlog2){
  int blk = blockIdx.x;
  int h = blk & 15, bp = blk >> 4;
  int tid = threadIdx.x;
  size_t stbase = ((size_t)(b0 + bp) * Hh + h) * 4096;
  int nloc = 1 << nlog2;
  float s[16];
  #pragma unroll
  for(int r = 0; r < 16; r++)
    s[r] = firstseg ? 0.f : st[stbase + r * 256 + tid];
  for(int ln = 0; ln < nloc; ln++){
    size_t idx = (((size_t)bp * Hh + h) << nlog2) | ln;
    size_t base = idx * 4096;
    const float* wsp = wse + idx * 64;
    #pragma unroll
    for(int r = 0; r < 16; r++){
      int e = r * 256 + tid;
      float tmp = buf[base + e];
      buf[base + e] = s[r];
      s[r] = s[r] * wsp[e >> 6] + tmp;
    }
  }
  #pragma unroll
  for(int r = 0; r < 16; r++)
    st[stbase + r * 256 + tid] = s[r];
}

// ---------------------------------------------------------------- chunk2: FULL MFMA rewrite
// a_ij = sum_k [r·e^(c_{i-1}-c_{B-1})]_ik [k·e^(c_{B-1}-c_j)]_jk  per 16-row tile (B=16I):
// both factors' exponents <= 0 for off-diag tiles (safe bf16); diag tile B-exponent <= +85
// (e^85 ~ 7e36 fits bf16/f32; masked upper-tri garbage discarded). Diag a_ii via extra
// raw-r x (u·k) MFMA, picking C entries where row==col. out = a@V + (r·e^{c_{i-1}})@S:
// MFMAs with V^T and S^T staged in LDS; `a` round-trips LDS per wave (flash pattern).
// Wave w owns row-tiles {w, 7-w} (balanced). outw aliases wcum -> barrier before writes.
__global__ __launch_bounds__(256) void k_chunk2(
    const bf16* __restrict__ rb, const bf16* __restrict__ kb,
    const bf16* __restrict__ vb, const float* __restrict__ wcum,
    const float* __restrict__ states, const bf16* __restrict__ u,
    float* __restrict__ outw, int nlog2){
  __shared__ __align__(16) bf16 vT[64 * 136];     // vT[v][t] = V[t][v]
  __shared__ __align__(16) bf16 sT[64 * 72];      // sT[v][k] = S[k][v]
  __shared__ __align__(16) bf16 ascr[4 * 16 * 136];
  int tid = threadIdx.x, blk = blockIdx.x;
  int nmask = (1 << nlog2) - 1;
  int ln = blk & nmask; int rest = blk >> nlog2;
  int h = rest & 15; int bp = rest >> 4;
  size_t rowbase = (((size_t)bp << nlog2) + ln) * 128;
  size_t gbase = rowbase * Dd + h * 64;
  // stage V^T, S^T
  for(int r = 0; r < 32; r++){
    int idx = r * 256 + tid;
    int t0 = idx >> 6, v0 = idx & 63;
    vT[v0 * 136 + t0] = vb[gbase + (size_t)t0 * Dd + v0];
  }
  for(int r = 0; r < 16; r++){
    int idx = r * 256 + tid;
    int k0 = idx >> 6, v0 = idx & 63;
    sT[v0 * 72 + k0] = f2b(states[(size_t)blk * 4096 + k0 * 64 + v0]);
  }
  __syncthreads();
  int w = tid >> 6, lane = tid & 63;
  int m16 = lane & 15, quad = lane >> 4;
  bf16* scr = ascr + w * (16 * 136);
  f32x4 oacc[2][4];
  #pragma unroll
  for(int a1 = 0; a1 < 2; a1++)
    #pragma unroll
    for(int a2 = 0; a2 < 4; a2++) oacc[a1][a2] = (f32x4){0.f, 0.f, 0.f, 0.f};

  for(int ii = 0; ii < 2; ii++){
    int I = ii ? (7 - w) : w;
    int B = I * 16;
    // zero scratch (16*136*2 B = 544 u64)
    for(int z = lane; z < 544; z += 64) ((unsigned long long*)scr)[z] = 0ULL;
    // A-side fragments: i = B + m16, k = ks*32 + quad*8 + c
    int i0 = B + m16;
    size_t rowi = rowbase + i0;
    short8 rf[2], af[2], rw2[2];
    float crv[2][8];
    #pragma unroll
    for(int ks = 0; ks < 2; ks++){
      int koff = h * 64 + ks * 32 + quad * 8;
      rf[ks] = *(const short8*)(rb + rowi * Dd + koff);
      float cp[8];
      if(i0 > 0){
        f32x4 c0 = *(const f32x4*)(wcum + (rowi - 1) * Dd + koff);
        f32x4 c1 = *(const f32x4*)(wcum + (rowi - 1) * Dd + koff + 4);
        #pragma unroll
        for(int c = 0; c < 4; c++){ cp[c] = c0[c]; cp[4 + c] = c1[c]; }
      } else {
        #pragma unroll
        for(int c = 0; c < 8; c++) cp[c] = 0.f;
      }
      if(B > 0){
        f32x4 c0 = *(const f32x4*)(wcum + (rowbase + B - 1) * Dd + koff);
        f32x4 c1 = *(const f32x4*)(wcum + (rowbase + B - 1) * Dd + koff + 4);
        #pragma unroll
        for(int c = 0; c < 4; c++){ crv[ks][c] = c0[c]; crv[ks][4 + c] = c1[c]; }
      } else {
        #pragma unroll
        for(int c = 0; c < 8; c++) crv[ks][c] = 0.f;
      }
      short8 av, wv;
      #pragma unroll
      for(int c = 0; c < 8; c++){
        float rv = b2f(((const bf16*)&rf[ks])[c]);
        ((bf16*)&av)[c] = f2b(rv * __expf(fminf(cp[c] - crv[ks][c], 0.f)));
        ((bf16*)&wv)[c] = f2b(rv * __expf(fminf(cp[c], 0.f)));
      }
      af[ks] = av; rw2[ks] = wv;
    }
    // off-diagonal tiles J < I (all entries valid: j <= B-1 < i)
    for(int J = 0; J < I; J++){
      f32x4 aacc = (f32x4){0.f, 0.f, 0.f, 0.f};
      #pragma unroll
      for(int ks = 0; ks < 2; ks++){
        int koff = h * 64 + ks * 32 + quad * 8;
        size_t rowj = rowbase + J * 16 + m16;
        short8 k8 = *(const short8*)(kb + rowj * Dd + koff);
        f32x4 c0 = *(const f32x4*)(wcum + rowj * Dd + koff);
        f32x4 c1 = *(const f32x4*)(wcum + rowj * Dd + koff + 4);
        short8 bfrag;
        #pragma unroll
        for(int c = 0; c < 8; c++){
          float kv = b2f(((const bf16*)&k8)[c]);
          float cj = (c < 4) ? c0[c] : c1[c - 4];
          ((bf16*)&bfrag)[c] = f2b(kv * __expf(fminf(crv[ks][c] - cj, 0.f)));
        }
        aacc = __builtin_amdgcn_mfma_f32_16x16x32_bf16(af[ks], bfrag, aacc, 0, 0, 0);
      }
      #pragma unroll
      for(int r = 0; r < 4; r++)
        scr[(quad * 4 + r) * 136 + J * 16 + m16] = f2b(aacc[r]);
    }
    // diagonal tile: masked strict-lower + separate diag (r·u·k)
    {
      f32x4 aacc = (f32x4){0.f, 0.f, 0.f, 0.f};
      f32x4 dacc = (f32x4){0.f, 0.f, 0.f, 0.f};
      #pragma unroll
      for(int ks = 0; ks < 2; ks++){
        int koff = h * 64 + ks * 32 + quad * 8;
        size_t rowj = rowbase + B + m16;
        short8 k8 = *(const short8*)(kb + rowj * Dd + koff);
        f32x4 c0 = *(const f32x4*)(wcum + rowj * Dd + koff);
        f32x4 c1 = *(const f32x4*)(wcum + rowj * Dd + koff + 4);
        short8 u8 = *(const short8*)(u + h * 64 + ks * 32 + quad * 8);
        short8 bf1, bf2;
        #pragma unroll
        for(int c = 0; c < 8; c++){
          float kv = b2f(((const bf16*)&k8)[c]);
          float cj = (c < 4) ? c0[c] : c1[c - 4];
          ((bf16*)&bf1)[c] = f2b(kv * __expf(crv[ks][c] - cj));  // exponent in [0, ~85]
          ((bf16*)&bf2)[c] = f2b(kv * b2f(((const bf16*)&u8)[c]));
        }
        aacc = __builtin_amdgcn_mfma_f32_16x16x32_bf16(af[ks], bf1, aacc, 0, 0, 0);
        dacc = __builtin_amdgcn_mfma_f32_16x16x32_bf16(rf[ks], bf2, dacc, 0, 0, 0);
      }
      #pragma unroll
      for(int r = 0; r < 4; r++){
        int row = quad * 4 + r, col = m16;
        if(col < row)       scr[row * 136 + B + col] = f2b(aacc[r]);
        else if(col == row) scr[row * 136 + B + col] = f2b(dacc[r]);
      }
    }
    // ensure same-wave scratch writes visible before frag reads
    asm volatile("s_waitcnt lgkmcnt(0)" ::: "memory");
    // PV: out_I += a_I @ V   (valid j < B+16 -> nks kslices; rest zeroed)
    int nks = (I + 2) >> 1;
    for(int ks2 = 0; ks2 < nks; ks2++){
      short8 afr = *(const short8*)(scr + m16 * 136 + ks2 * 32 + quad * 8);
      #pragma unroll
      for(int nt = 0; nt < 4; nt++){
        short8 bfr = *(const short8*)(vT + (nt * 16 + m16) * 136 + ks2 * 32 + quad * 8);
        oacc[ii][nt] = __builtin_amdgcn_mfma_f32_16x16x32_bf16(afr, bfr, oacc[ii][nt], 0, 0, 0);
      }
    }
    // state term: out_I += (r·e^{c_{i-1}}) @ S
    #pragma unroll
    for(int ks = 0; ks < 2; ks++){
      #pragma unroll
      for(int nt = 0; nt < 4; nt++){
        short8 sfr = *(const short8*)(sT + (nt * 16 + m16) * 72 + ks * 32 + quad * 8);
        oacc[ii][nt] = __builtin_amdgcn_mfma_f32_16x16x32_bf16(rw2[ks], sfr, oacc[ii][nt], 0, 0, 0);
      }
    }
  }
  __syncthreads();   // all wcum reads complete before overwriting (outw aliases wcum)
  #pragma unroll
  for(int ii = 0; ii < 2; ii++){
    int I = ii ? (7 - w) : w;
    int B = I * 16;
    #pragma unroll
    for(int nt = 0; nt < 4; nt++){
      #pragma unroll
      for(int r = 0; r < 4; r++){
        int i0 = B + quad * 4 + r;
        int v0 = nt * 16 + m16;
        outw[gbase + (size_t)i0 * Dd + v0] = oacc[ii][nt][r];
      }
    }
  }
}

// ---------------------------------------------------------------- groupnorm(64) + gate
__global__ __launch_bounds__(256) void k_norm(const float* __restrict__ outw,
                                              const bf16* __restrict__ gb,
                                              const bf16* __restrict__ lnw,
                                              const bf16* __restrict__ lnb,
                                              bf16* __restrict__ gated){
  int lr = blockIdx.x;
  int wv = threadIdx.x >> 6, lane = threadIdx.x & 63;
  for(int hh = wv; hh < Hh; hh += 4){
    size_t ix = (size_t)lr * Dd + hh * 64 + lane;
    float xv = outw[ix];
    float s1 = xv, s2 = xv * xv;
    #pragma unroll
    for(int off = 32; off > 0; off >>= 1){
      s1 += __shfl_xor(s1, off);
      s2 += __shfl_xor(s2, off);
    }
    float mu  = s1 * 0.015625f;
    float var = s2 * 0.015625f - mu * mu;
    float inv = rsqrtf(var + 6.4e-4f);
    float og  = (xv - mu) * inv * b2f(lnw[hh * 64 + lane]) + b2f(lnb[hh * 64 + lane]);
    gated[ix] = f2b(og * b2f(gb[ix]));
  }
}

// ---------------------------------------------------------------- host
extern "C" void kernel_launch(void* const* d_in, const int* in_sizes, int n_in,
                              void* d_out, int out_size, void* d_ws, size_t ws_size,
                              hipStream_t stream){
  char* W = (char*)d_ws;
  size_t cur = 0;
  auto carve = [&](size_t bytes) -> char* {
    char* p = W + cur;
    cur = (cur + bytes + 255) & ~(size_t)255;
    return p;
  };

  int* flag = (int*)carve(4096);
  static const int NEL[20] = {8388608, 1024, 1024, 1024, 1024, 1024, 1024,
                              163840, 163840, 1024, 65536, 65536, 1024,
                              1048576, 1048576, 1048576, 1048576, 1048576,
                              1024, 1024};
  bf16* canon[20];
  for(int i = 0; i < 20; i++) canon[i] = (bf16*)carve((size_t)NEL[i] * 2);

  k_detect<<<dim3(1), 256, 0, stream>>>((const unsigned short*)d_in[0], flag);
  for(int i = 0; i < 20; i++)
    k_conv<<<dim3((NEL[i] + 255) / 256), 256, 0, stream>>>(d_in[i], canon[i], NEL[i], flag);

  const bf16* xp   = canon[0];
  const bf16* tmx  = canon[1];
  const bf16* maas[5] = {canon[2], canon[3], canon[4], canon[5], canon[6]};
  const bf16* w1p  = canon[7];
  const bf16* w2p  = canon[8];
  const bf16* tdec = canon[9];
  const bf16* dw1  = canon[10];
  const bf16* dw2  = canon[11];
  const bf16* up   = canon[12];
  const bf16* lnwp = canon[18];
  const bf16* lnbp = canon[19];

  bf16* WrT = (bf16*)carve(2097152);
  bf16* WkT = (bf16*)carve(2097152);
  bf16* WvT = (bf16*)carve(2097152);
  bf16* WgT = (bf16*)carve(2097152);
  bf16* WoT = (bf16*)carve(2097152);
  k_transpose<<<dim3(32, 32), 256, 0, stream>>>(canon[13], WrT);
  k_transpose<<<dim3(32, 32), 256, 0, stream>>>(canon[14], WkT);
  k_transpose<<<dim3(32, 32), 256, 0, stream>>>(canon[15], WvT);
  k_transpose<<<dim3(32, 32), 256, 0, stream>>>(canon[16], WgT);
  k_transpose<<<dim3(32, 32), 256, 0, stream>>>(canon[17], WoT);

  float* st = (float*)carve(1u << 20);
  size_t FIXED = cur;

  const size_t UNIT = 16864, PAD = 65536;
  int nb, L;
  if(ws_size >= FIXED + (size_t)8192 * UNIT + PAD){ nb = 4; L = 2048; }
  else {
    nb = 1; L = 2048;
    while(L > 128 && ws_size < FIXED + (size_t)L * UNIT + PAD) L >>= 1;
  }
  const int Llog2 = __builtin_ctz((unsigned)L);
  const int nlog2 = Llog2 - 7;
  const int M     = nb * L;
  const size_t Mr = (size_t)M;

  bf16*  xxx    = (bf16*) carve(Mr * 320);
  bf16*  ww1    = (bf16*) carve(Mr * 128);
  float* wse    = (float*)carve(Mr * 32);
  bf16*  mix    = (bf16*) carve(Mr * 2048);
  bf16*  kbuf   = (bf16*) carve(Mr * 2048);
  bf16*  vbuf   = (bf16*) carve(Mr * 2048);
  bf16*  rbuf   = (bf16*) carve(Mr * 2048);
  bf16*  gbuf   = (bf16*) carve(Mr * 2048);
  float* wdec   = (float*)carve(Mr * 4096);
  float* wkvst  = (float*)carve(Mr * 2048);
  float* outw   = wdec;   // chunk2 drains all wcum reads (barrier) before overwriting
  bf16*  gated  = mix;    // mix dead after last consumer GEMM

  for(int b0 = 0; b0 < 4; b0 += nb){
    for(int t0 = 0; t0 < Tt; t0 += L){
      gemm_ep<EPI_TANH, true><<<dim3(3, M/64), 256, 0, stream>>>(
          xp, Dd, w1p, 160, xxx, 160, M, 160, Dd, xp, tmx, b0, t0, Llog2, flag);
      for(int c = 0; c < 5; c++){
        gemm_ep<EPI_MIX, false><<<dim3(16, M/64), 256, 0, stream>>>(
            xxx + c * 32, 160, w2p + (size_t)c * 32 * 1024, 1024,
            mix, 1024, M, 1024, 32, xp, maas[c], b0, t0, Llog2, flag);
        if(c == 0){
          gemm_ep<EPI_TANH, false><<<dim3(1, M/64), 256, 0, stream>>>(
              mix, 1024, dw1, 64, ww1, 64, M, 64, 1024, nullptr, nullptr, 0, 0, Llog2, flag);
          gemm_ep<EPI_DECAY, false><<<dim3(16, M/64), 256, 0, stream>>>(
              ww1, 64, dw2, 1024, wdec, 1024, M, 1024, 64, nullptr, tdec, 0, 0, Llog2, flag);
        } else if(c == 1){
          gemm_mfma<GEPI_BF16><<<dim3(8, M/128), 256, 0, stream>>>(mix, WkT, kbuf, flag, 0);
        } else if(c == 2){
          gemm_mfma<GEPI_BF16><<<dim3(8, M/128), 256, 0, stream>>>(mix, WvT, vbuf, flag, 0);
        } else if(c == 3){
          gemm_mfma<GEPI_BF16><<<dim3(8, M/128), 256, 0, stream>>>(mix, WrT, rbuf, flag, 0);
        } else {
          gemm_mfma<GEPI_SILU><<<dim3(8, M/128), 256, 0, stream>>>(mix, WgT, gbuf, flag, 0);
        }
      }
      int nloc = 1 << nlog2;
      k_cumsum<<<dim3(nb * nloc * 4), 256, 0, stream>>>(wdec, wse, nlog2);
      k_chunk1<<<dim3(nb * 16 * nloc), 256, 0, stream>>>(kbuf, vbuf, wdec, wkvst, nlog2);
      k_scan<<<dim3(nb * 16), 256, 0, stream>>>(wkvst, wse, st, b0, (t0 == 0) ? 1 : 0, nlog2);
      k_chunk2<<<dim3(nb * 16 * nloc), 256, 0, stream>>>(rbuf, kbuf, vbuf, wdec, wkvst, up, outw, nlog2);
      k_norm<<<dim3(M), 256, 0, stream>>>(outw, gbuf, lnwp, lnbp, gated);
      if(L == Tt){
        gemm_mfma<GEPI_OUT><<<dim3(8, M/128), 256, 0, stream>>>(gated, WoT, d_out, flag, b0 * Tt);
      } else {
        gemm_ep<EPI_OUTV, false><<<dim3(16, M/64), 256, 0, stream>>>(
            gated, 1024, canon[17], 1024, d_out, 1024, M, 1024, 1024,
            nullptr, nullptr, b0, t0, Llog2, flag);
      }
    }
  }
}

// Round 10
// 748.605 us; speedup vs baseline: 4.2547x; 1.3313x over previous
//
#include <hip/hip_runtime.h>
#include <hip/hip_bf16.h>
#include <math.h>

typedef __hip_bfloat16 bf16;
typedef __attribute__((ext_vector_type(8))) short short8;
typedef __attribute__((ext_vector_type(4))) float f32x4;

#define Tt 2048
#define Dd 1024
#define Hh 16

__device__ __forceinline__ float b2f(bf16 v){ return __bfloat162float(v); }
__device__ __forceinline__ bf16  f2b(float v){ return __float2bfloat16(v); }

__device__ __forceinline__ int seg_t(int lr, int t0, int Lm1){ return t0 + (lr & Lm1); }
__device__ __forceinline__ size_t seg_grow(int lr, int b0, int t0, int Llog2, int Lm1){
  return ((size_t)(b0 + (lr >> Llog2)) * Tt) + (size_t)seg_t(lr, t0, Lm1);
}

// ---------------------------------------------------------------- dtype detect
__global__ __launch_bounds__(256) void k_detect(const unsigned short* __restrict__ xs,
                                                int* __restrict__ flag){
  __shared__ int bad;
  if(threadIdx.x == 0) bad = 0;
  __syncthreads();
  int local = 0;
  for(int i = threadIdx.x; i < 8192; i += 256){
    unsigned e = (xs[i] >> 7) & 0xFF;
    if(e >= 0xC0) local++;
  }
  if(local) atomicAdd(&bad, local);
  __syncthreads();
  if(threadIdx.x == 0) flag[0] = (bad > 16) ? 1 : 0;   // 1 = inputs are float32
}

// ---------------------------------------------------------------- canonicalize to bf16
__global__ __launch_bounds__(256) void k_conv(const void* __restrict__ src,
                                              bf16* __restrict__ dst, int n,
                                              const int* __restrict__ flag){
  int i = blockIdx.x * 256 + threadIdx.x;
  if(i >= n) return;
  if(flag[0]) dst[i] = f2b(((const float*)src)[i]);
  else        dst[i] = ((const bf16*)src)[i];
}

// ---------------------------------------------------------------- 1024x1024 bf16 transpose
__global__ __launch_bounds__(256) void k_transpose(const bf16* __restrict__ src,
                                                   bf16* __restrict__ dst){
  __shared__ bf16 tile[32][33];
  int bx = blockIdx.x * 32, by = blockIdx.y * 32;
  int tx = threadIdx.x & 31, ty = threadIdx.x >> 5;   // 32 x 8
  for(int r = ty; r < 32; r += 8)
    tile[r][tx] = src[(size_t)(by + r) * 1024 + bx + tx];
  __syncthreads();
  for(int r = ty; r < 32; r += 8)
    dst[(size_t)(bx + r) * 1024 + by + tx] = tile[tx][r];
}

// ---------------------------------------------------------------- generic transpose+pad: dst[Npad][K] = src[K][N]^T
__global__ __launch_bounds__(256) void k_transposeP(const bf16* __restrict__ src,
                                                    bf16* __restrict__ dst,
                                                    int K, int N, int Npad){
  int idx = blockIdx.x * 256 + threadIdx.x;
  if(idx >= Npad * K) return;
  int n = idx / K, k = idx - n * K;
  dst[idx] = (n < N) ? src[(size_t)k * N + n] : f2b(0.f);
}

// ---------------------------------------------------------------- k_prep: xmx = x + (shift(x)-x)*tmx
__global__ __launch_bounds__(256) void k_prep(const bf16* __restrict__ x,
                                              const bf16* __restrict__ tmx,
                                              bf16* __restrict__ xmx,
                                              int b0, int t0, int Llog2){
  const int Lm1 = (1 << Llog2) - 1;
  int idx = blockIdx.x * 256 + threadIdx.x;
  int lr = idx >> 10, d = idx & 1023;
  size_t grow = seg_grow(lr, b0, t0, Llog2, Lm1);
  int tl = seg_t(lr, t0, Lm1);
  float xc = b2f(x[grow * Dd + d]);
  float xp = tl ? b2f(x[(grow - 1) * Dd + d]) : 0.f;
  xmx[idx] = f2b(xc + (xp - xc) * b2f(tmx[d]));
}

// ---------------------------------------------------------------- MFMA GEMM (fixed 1024x1024) — the five big projections
constexpr int GEPI_BF16 = 0, GEPI_SILU = 1, GEPI_OUT = 2;

template<int EPI>
__global__ __launch_bounds__(256) void gemm_mfma(
    const bf16* __restrict__ A,
    const bf16* __restrict__ Bt,
    void* __restrict__ Cv,
    const int* __restrict__ oflag,
    int rowoff){
  __shared__ short As[128 * 40];
  __shared__ short Bs[128 * 40];
  int tid = threadIdx.x;
  int bn = blockIdx.x * 128;
  int bm = blockIdx.y * 128;
  int w = tid >> 6, lane = tid & 63;
  int wm = (w & 1) * 64, wn = (w >> 1) * 64;
  int m16 = lane & 15, quad = lane >> 4;

  f32x4 acc[4][4];
  #pragma unroll
  for(int mi = 0; mi < 4; mi++)
    #pragma unroll
    for(int ni = 0; ni < 4; ni++)
      acc[mi][ni] = (f32x4){0.f, 0.f, 0.f, 0.f};

  int srow = tid >> 2;
  int sk8  = (tid & 3) * 8;
  const bf16* Ag = A  + (size_t)(bm + srow) * 1024 + sk8;
  const bf16* Bg = Bt + (size_t)(bn + srow) * 1024 + sk8;
  short* Aw = As + srow * 40 + sk8;
  short* Bw = Bs + srow * 40 + sk8;

  for(int kb = 0; kb < 1024; kb += 32){
    #pragma unroll
    for(int rep = 0; rep < 2; rep++){
      *(short8*)(Aw + rep * 64 * 40) = *(const short8*)(Ag + (size_t)rep * 64 * 1024 + kb);
      *(short8*)(Bw + rep * 64 * 40) = *(const short8*)(Bg + (size_t)rep * 64 * 1024 + kb);
    }
    __syncthreads();
    short8 af[4], bfr[4];
    #pragma unroll
    for(int mi = 0; mi < 4; mi++)
      af[mi] = *(const short8*)(As + (wm + mi * 16 + m16) * 40 + quad * 8);
    #pragma unroll
    for(int ni = 0; ni < 4; ni++)
      bfr[ni] = *(const short8*)(Bs + (wn + ni * 16 + m16) * 40 + quad * 8);
    #pragma unroll
    for(int mi = 0; mi < 4; mi++)
      #pragma unroll
      for(int ni = 0; ni < 4; ni++)
        acc[mi][ni] = __builtin_amdgcn_mfma_f32_16x16x32_bf16(af[mi], bfr[ni], acc[mi][ni], 0, 0, 0);
    __syncthreads();
  }
  #pragma unroll
  for(int mi = 0; mi < 4; mi++){
    #pragma unroll
    for(int ni = 0; ni < 4; ni++){
      #pragma unroll
      for(int r = 0; r < 4; r++){
        int row = bm + wm + mi * 16 + quad * 4 + r;
        int col = bn + wn + ni * 16 + m16;
        float v = acc[mi][ni][r];
        if constexpr(EPI == GEPI_BF16){
          ((bf16*)Cv)[(size_t)row * 1024 + col] = f2b(v);
        } else if constexpr(EPI == GEPI_SILU){
          ((bf16*)Cv)[(size_t)row * 1024 + col] = f2b(v / (1.f + expf(-v)));
        } else { // GEPI_OUT
          size_t off = (size_t)(row + rowoff) * 1024 + col;
          if(oflag[0]) ((float*)Cv)[off] = v;
          else         ((bf16*)Cv)[off]  = f2b(v);
        }
      }
    }
  }
}

// ---------------------------------------------------------------- generic MFMA GEMM (runtime N/K, padded Bt, edge-masked C)
// A [M][Kdim] (lda=Kdim), Bt [Npad>=ceil(N,128)*128][Kdim] zero-padded. M mult of 128, Kdim mult of 32.
constexpr int G2_TANH = 0, G2_DECAY = 1;

template<int EPI>
__global__ __launch_bounds__(256) void gemm_mfma2(
    const bf16* __restrict__ A,
    const bf16* __restrict__ Bt,
    void* __restrict__ Cv, int ldc,
    int Ndim, int Kdim,
    const bf16* __restrict__ e_w){
  __shared__ short As[128 * 40];
  __shared__ short Bs[128 * 40];
  int tid = threadIdx.x;
  int bn = blockIdx.x * 128;
  int bm = blockIdx.y * 128;
  int w = tid >> 6, lane = tid & 63;
  int wm = (w & 1) * 64, wn = (w >> 1) * 64;
  int m16 = lane & 15, quad = lane >> 4;

  f32x4 acc[4][4];
  #pragma unroll
  for(int mi = 0; mi < 4; mi++)
    #pragma unroll
    for(int ni = 0; ni < 4; ni++)
      acc[mi][ni] = (f32x4){0.f, 0.f, 0.f, 0.f};

  int srow = tid >> 2;
  int sk8  = (tid & 3) * 8;
  const bf16* Ag = A  + (size_t)(bm + srow) * Kdim + sk8;
  const bf16* Bg = Bt + (size_t)(bn + srow) * Kdim + sk8;
  short* Aw = As + srow * 40 + sk8;
  short* Bw = Bs + srow * 40 + sk8;

  for(int kb = 0; kb < Kdim; kb += 32){
    #pragma unroll
    for(int rep = 0; rep < 2; rep++){
      *(short8*)(Aw + rep * 64 * 40) = *(const short8*)(Ag + (size_t)rep * 64 * Kdim + kb);
      *(short8*)(Bw + rep * 64 * 40) = *(const short8*)(Bg + (size_t)rep * 64 * Kdim + kb);
    }
    __syncthreads();
    short8 af[4], bfr[4];
    #pragma unroll
    for(int mi = 0; mi < 4; mi++)
      af[mi] = *(const short8*)(As + (wm + mi * 16 + m16) * 40 + quad * 8);
    #pragma unroll
    for(int ni = 0; ni < 4; ni++)
      bfr[ni] = *(const short8*)(Bs + (wn + ni * 16 + m16) * 40 + quad * 8);
    #pragma unroll
    for(int mi = 0; mi < 4; mi++)
      #pragma unroll
      for(int ni = 0; ni < 4; ni++)
        acc[mi][ni] = __builtin_amdgcn_mfma_f32_16x16x32_bf16(af[mi], bfr[ni], acc[mi][ni], 0, 0, 0);
    __syncthreads();
  }
  #pragma unroll
  for(int mi = 0; mi < 4; mi++){
    #pragma unroll
    for(int ni = 0; ni < 4; ni++){
      #pragma unroll
      for(int r = 0; r < 4; r++){
        int row = bm + wm + mi * 16 + quad * 4 + r;
        int col = bn + wn + ni * 16 + m16;
        if(col >= Ndim) continue;
        float v = acc[mi][ni][r];
        size_t off = (size_t)row * ldc + col;
        if constexpr(EPI == G2_TANH){
          ((bf16*)Cv)[off] = f2b(tanhf(v));
        } else { // G2_DECAY
          float td = b2f(e_w[col]) + v;
          ((float*)Cv)[off] = fmaxf(-expf(td), -5.2983173665480363f);
        }
      }
    }
  }
}

// ---------------------------------------------------------------- small VALU GEMM (mix epilogue + segmented-out fallback)
constexpr int EPI_MIX = 3, EPI_OUTV = 5;
#define BM 64
#define BN 64
#define BK 16

template<int EPI>
__global__ __launch_bounds__(256) void gemm_ep(
    const bf16* __restrict__ A, int lda,
    const bf16* __restrict__ Bm, int ldb,
    void* __restrict__ Cv, int ldc,
    int Mdim, int Ndim, int Kdim,
    const bf16* __restrict__ xg, const bf16* __restrict__ e_w,
    int b0, int t0, int Llog2, const int* __restrict__ oflag){
  const int Lm1 = (1 << Llog2) - 1;
  __shared__ float As[BM][BK + 1];
  __shared__ float Bs[BK][BN + 4];
  int tid = threadIdx.x;
  int tx = tid & 15, ty = tid >> 4;
  int bm = blockIdx.y * BM, bn = blockIdx.x * BN;
  float acc[4][4] = {};
  for(int kb = 0; kb < Kdim; kb += BK){
    {
      int lr = tid >> 2;
      int lc = (tid & 3) * 4;
      int gr = bm + lr;
      #pragma unroll
      for(int q = 0; q < 4; q++){
        int gc = kb + lc + q;
        float av = 0.f;
        if(gr < Mdim && gc < Kdim)
          av = b2f(A[(size_t)gr * lda + gc]);
        As[lr][lc + q] = av;
      }
    }
    {
      int lr = tid >> 4;
      int lc = (tid & 15) * 4;
      #pragma unroll
      for(int q = 0; q < 4; q++){
        int gr = kb + lr; int gc = bn + lc + q;
        Bs[lr][lc + q] = (gr < Kdim && gc < Ndim) ? b2f(Bm[(size_t)gr * ldb + gc]) : 0.f;
      }
    }
    __syncthreads();
    #pragma unroll
    for(int kk = 0; kk < BK; kk++){
      float ar[4], br[4];
      #pragma unroll
      for(int q = 0; q < 4; q++) ar[q] = As[ty * 4 + q][kk];
      #pragma unroll
      for(int q = 0; q < 4; q++) br[q] = Bs[kk][tx * 4 + q];
      #pragma unroll
      for(int mi = 0; mi < 4; mi++)
        #pragma unroll
        for(int ni = 0; ni < 4; ni++)
          acc[mi][ni] += ar[mi] * br[ni];
    }
    __syncthreads();
  }
  #pragma unroll
  for(int mi = 0; mi < 4; mi++){
    int row = bm + ty * 4 + mi;
    if(row >= Mdim) continue;
    #pragma unroll
    for(int ni = 0; ni < 4; ni++){
      int col = bn + tx * 4 + ni;
      if(col >= Ndim) continue;
      float vacc = acc[mi][ni];
      size_t off = (size_t)row * ldc + col;
      if constexpr(EPI == EPI_MIX){
        size_t grow = seg_grow(row, b0, t0, Llog2, Lm1);
        int tl = seg_t(row, t0, Lm1);
        float xc = b2f(xg[grow * Dd + col]);
        float xp = tl ? b2f(xg[(grow - 1) * Dd + col]) : 0.f;
        ((bf16*)Cv)[off] = f2b(xc + (xp - xc) * (b2f(e_w[col]) + vacc));
      } else { // EPI_OUTV
        size_t grow = seg_grow(row, b0, t0, Llog2, Lm1);
        size_t go = grow * Dd + col;
        if(oflag[0]) ((float*)Cv)[go] = vacc;
        else         ((bf16*)Cv)[go]  = f2b(vacc);
      }
    }
  }
}

// ---------------------------------------------------------------- cumsum (in place wlog->wcum) + wse
__global__ __launch_bounds__(256) void k_cumsum(float* __restrict__ wd,
                                                float* __restrict__ wse,
                                                int nlog2){
  int blk = blockIdx.x;
  int dg = blk & 3; int rest = blk >> 2;
  int nmask = (1 << nlog2) - 1;
  int ln = rest & nmask; int bp = rest >> nlog2;
  int d = dg * 256 + threadIdx.x;
  size_t rowbase = (((size_t)bp << nlog2) + ln) * 128;
  size_t base = rowbase * Dd + d;
  float c = 0.f;
  for(int t = 0; t < 128; t++){
    size_t ix = base + (size_t)t * Dd;
    c += wd[ix];
    wd[ix] = c;
  }
  int h = d >> 6, k0 = d & 63;
  wse[((((size_t)bp * Hh + h) << nlog2) | ln) * 64 + k0] = __expf(fminf(c, 0.f));
}

// ---------------------------------------------------------------- chunk1 (MFMA): wkv[kk][v] = sum_t ktw[t][kk]*v[t][v]
// 64x64x128 GEMM per (b,h,chunk). ktT/vT staged transposed: frag A[m=kk][k=t], B[n=v][k=t].
__global__ __launch_bounds__(256) void k_chunk1(const bf16* __restrict__ kb,
                                                const bf16* __restrict__ vb,
                                                const float* __restrict__ wcum,
                                                float* __restrict__ wkv,
                                                int nlog2){
  __shared__ __align__(16) bf16 ktT[64 * 136];
  __shared__ __align__(16) bf16 vT2[64 * 136];
  int tid = threadIdx.x, blk = blockIdx.x;
  int nmask = (1 << nlog2) - 1;
  int ln = blk & nmask; int rest = blk >> nlog2;
  int h = rest & 15; int bp = rest >> 4;
  size_t rowbase = (((size_t)bp << nlog2) + ln) * 128;
  size_t gbase = rowbase * Dd + h * 64;
  for(int r = 0; r < 32; r++){
    int idx = r * 256 + tid;
    int t0 = idx >> 6, k0 = idx & 63;
    size_t gi = gbase + (size_t)t0 * Dd + k0;
    float c  = wcum[gi];
    float cL = wcum[gbase + (size_t)127 * Dd + k0];
    ktT[k0 * 136 + t0] = f2b(b2f(kb[gi]) * __expf(fminf(cL - c, 0.f)));
    vT2[k0 * 136 + t0] = vb[gi];
  }
  __syncthreads();
  int w = tid >> 6, lane = tid & 63;
  int m16 = lane & 15, quad = lane >> 4;
  f32x4 acc[4];
  #pragma unroll
  for(int nt = 0; nt < 4; nt++) acc[nt] = (f32x4){0.f, 0.f, 0.f, 0.f};
  #pragma unroll
  for(int ks = 0; ks < 4; ks++){
    short8 af = *(const short8*)(ktT + (w * 16 + m16) * 136 + ks * 32 + quad * 8);
    #pragma unroll
    for(int nt = 0; nt < 4; nt++){
      short8 bfr = *(const short8*)(vT2 + (nt * 16 + m16) * 136 + ks * 32 + quad * 8);
      acc[nt] = __builtin_amdgcn_mfma_f32_16x16x32_bf16(af, bfr, acc[nt], 0, 0, 0);
    }
  }
  size_t obase = (size_t)blk * 4096;
  #pragma unroll
  for(int nt = 0; nt < 4; nt++)
    #pragma unroll
    for(int r = 0; r < 4; r++)
      wkv[obase + (size_t)(w * 16 + quad * 4 + r) * 64 + nt * 16 + m16] = acc[nt][r];
}

// ---------------------------------------------------------------- state scan, in place, carry in st
__global__ __launch_bounds__(256) void k_scan(float* __restrict__ buf,
                                              const float* __restrict__ wse,
                                              float* __restrict__ st,
                                              int b0, int firstseg, int nlog2){
  int blk = blockIdx.x;
  int h = blk & 15, bp = blk >> 4;
  int tid = threadIdx.x;
  size_t stbase = ((size_t)(b0 + bp) * Hh + h) * 4096;
  int nloc = 1 << nlog2;
  float s[16];
  #pragma unroll
  for(int r = 0; r < 16; r++)
    s[r] = firstseg ? 0.f : st[stbase + r * 256 + tid];
  for(int ln = 0; ln < nloc; ln++){
    size_t idx = (((size_t)bp * Hh + h) << nlog2) | ln;
    size_t base = idx * 4096;
    const float* wsp = wse + idx * 64;
    #pragma unroll
    for(int r = 0; r < 16; r++){
      int e = r * 256 + tid;
      float tmp = buf[base + e];
      buf[base + e] = s[r];
      s[r] = s[r] * wsp[e >> 6] + tmp;
    }
  }
  #pragma unroll
  for(int r = 0; r < 16; r++)
    st[stbase + r * 256 + tid] = s[r];
}

// ---------------------------------------------------------------- chunk2: full-MFMA intra attention (R9, proven)
__global__ __launch_bounds__(256) void k_chunk2(
    const bf16* __restrict__ rb, const bf16* __restrict__ kb,
    const bf16* __restrict__ vb, const float* __restrict__ wcum,
    const float* __restrict__ states, const bf16* __restrict__ u,
    float* __restrict__ outw, int nlog2){
  __shared__ __align__(16) bf16 vT[64 * 136];
  __shared__ __align__(16) bf16 sT[64 * 72];
  __shared__ __align__(16) bf16 ascr[4 * 16 * 136];
  int tid = threadIdx.x, blk = blockIdx.x;
  int nmask = (1 << nlog2) - 1;
  int ln = blk & nmask; int rest = blk >> nlog2;
  int h = rest & 15; int bp = rest >> 4;
  size_t rowbase = (((size_t)bp << nlog2) + ln) * 128;
  size_t gbase = rowbase * Dd + h * 64;
  for(int r = 0; r < 32; r++){
    int idx = r * 256 + tid;
    int t0 = idx >> 6, v0 = idx & 63;
    vT[v0 * 136 + t0] = vb[gbase + (size_t)t0 * Dd + v0];
  }
  for(int r = 0; r < 16; r++){
    int idx = r * 256 + tid;
    int k0 = idx >> 6, v0 = idx & 63;
    sT[v0 * 72 + k0] = f2b(states[(size_t)blk * 4096 + k0 * 64 + v0]);
  }
  __syncthreads();
  int w = tid >> 6, lane = tid & 63;
  int m16 = lane & 15, quad = lane >> 4;
  bf16* scr = ascr + w * (16 * 136);
  f32x4 oacc[2][4];
  #pragma unroll
  for(int a1 = 0; a1 < 2; a1++)
    #pragma unroll
    for(int a2 = 0; a2 < 4; a2++) oacc[a1][a2] = (f32x4){0.f, 0.f, 0.f, 0.f};

  for(int ii = 0; ii < 2; ii++){
    int I = ii ? (7 - w) : w;
    int B = I * 16;
    for(int z = lane; z < 544; z += 64) ((unsigned long long*)scr)[z] = 0ULL;
    int i0 = B + m16;
    size_t rowi = rowbase + i0;
    short8 rf[2], af[2], rw2[2];
    float crv[2][8];
    #pragma unroll
    for(int ks = 0; ks < 2; ks++){
      int koff = h * 64 + ks * 32 + quad * 8;
      rf[ks] = *(const short8*)(rb + rowi * Dd + koff);
      float cp[8];
      if(i0 > 0){
        f32x4 c0 = *(const f32x4*)(wcum + (rowi - 1) * Dd + koff);
        f32x4 c1 = *(const f32x4*)(wcum + (rowi - 1) * Dd + koff + 4);
        #pragma unroll
        for(int c = 0; c < 4; c++){ cp[c] = c0[c]; cp[4 + c] = c1[c]; }
      } else {
        #pragma unroll
        for(int c = 0; c < 8; c++) cp[c] = 0.f;
      }
      if(B > 0){
        f32x4 c0 = *(const f32x4*)(wcum + (rowbase + B - 1) * Dd + koff);
        f32x4 c1 = *(const f32x4*)(wcum + (rowbase + B - 1) * Dd + koff + 4);
        #pragma unroll
        for(int c = 0; c < 4; c++){ crv[ks][c] = c0[c]; crv[ks][4 + c] = c1[c]; }
      } else {
        #pragma unroll
        for(int c = 0; c < 8; c++) crv[ks][c] = 0.f;
      }
      short8 av, wv;
      #pragma unroll
      for(int c = 0; c < 8; c++){
        float rv = b2f(((const bf16*)&rf[ks])[c]);
        ((bf16*)&av)[c] = f2b(rv * __expf(fminf(cp[c] - crv[ks][c], 0.f)));
        ((bf16*)&wv)[c] = f2b(rv * __expf(fminf(cp[c], 0.f)));
      }
      af[ks] = av; rw2[ks] = wv;
    }
    for(int J = 0; J < I; J++){
      f32x4 aacc = (f32x4){0.f, 0.f, 0.f, 0.f};
      #pragma unroll
      for(int ks = 0; ks < 2; ks++){
        int koff = h * 64 + ks * 32 + quad * 8;
        size_t rowj = rowbase + J * 16 + m16;
        short8 k8 = *(const short8*)(kb + rowj * Dd + koff);
        f32x4 c0 = *(const f32x4*)(wcum + rowj * Dd + koff);
        f32x4 c1 = *(const f32x4*)(wcum + rowj * Dd + koff + 4);
        short8 bfrag;
        #pragma unroll
        for(int c = 0; c < 8; c++){
          float kv = b2f(((const bf16*)&k8)[c]);
          float cj = (c < 4) ? c0[c] : c1[c - 4];
          ((bf16*)&bfrag)[c] = f2b(kv * __expf(fminf(crv[ks][c] - cj, 0.f)));
        }
        aacc = __builtin_amdgcn_mfma_f32_16x16x32_bf16(af[ks], bfrag, aacc, 0, 0, 0);
      }
      #pragma unroll
      for(int r = 0; r < 4; r++)
        scr[(quad * 4 + r) * 136 + J * 16 + m16] = f2b(aacc[r]);
    }
    {
      f32x4 aacc = (f32x4){0.f, 0.f, 0.f, 0.f};
      f32x4 dacc = (f32x4){0.f, 0.f, 0.f, 0.f};
      #pragma unroll
      for(int ks = 0; ks < 2; ks++){
        int koff = h * 64 + ks * 32 + quad * 8;
        size_t rowj = rowbase + B + m16;
        short8 k8 = *(const short8*)(kb + rowj * Dd + koff);
        f32x4 c0 = *(const f32x4*)(wcum + rowj * Dd + koff);
        f32x4 c1 = *(const f32x4*)(wcum + rowj * Dd + koff + 4);
        short8 u8 = *(const short8*)(u + h * 64 + ks * 32 + quad * 8);
        short8 bf1, bf2;
        #pragma unroll
        for(int c = 0; c < 8; c++){
          float kv = b2f(((const bf16*)&k8)[c]);
          float cj = (c < 4) ? c0[c] : c1[c - 4];
          ((bf16*)&bf1)[c] = f2b(kv * __expf(crv[ks][c] - cj));
          ((bf16*)&bf2)[c] = f2b(kv * b2f(((const bf16*)&u8)[c]));
        }
        aacc = __builtin_amdgcn_mfma_f32_16x16x32_bf16(af[ks], bf1, aacc, 0, 0, 0);
        dacc = __builtin_amdgcn_mfma_f32_16x16x32_bf16(rf[ks], bf2, dacc, 0, 0, 0);
      }
      #pragma unroll
      for(int r = 0; r < 4; r++){
        int row = quad * 4 + r, col = m16;
        if(col < row)       scr[row * 136 + B + col] = f2b(aacc[r]);
        else if(col == row) scr[row * 136 + B + col] = f2b(dacc[r]);
      }
    }
    asm volatile("s_waitcnt lgkmcnt(0)" ::: "memory");
    int nks = (I + 2) >> 1;
    for(int ks2 = 0; ks2 < nks; ks2++){
      short8 afr = *(const short8*)(scr + m16 * 136 + ks2 * 32 + quad * 8);
      #pragma unroll
      for(int nt = 0; nt < 4; nt++){
        short8 bfr = *(const short8*)(vT + (nt * 16 + m16) * 136 + ks2 * 32 + quad * 8);
        oacc[ii][nt] = __builtin_amdgcn_mfma_f32_16x16x32_bf16(afr, bfr, oacc[ii][nt], 0, 0, 0);
      }
    }
    #pragma unroll
    for(int ks = 0; ks < 2; ks++){
      #pragma unroll
      for(int nt = 0; nt < 4; nt++){
        short8 sfr = *(const short8*)(sT + (nt * 16 + m16) * 72 + ks * 32 + quad * 8);
        oacc[ii][nt] = __builtin_amdgcn_mfma_f32_16x16x32_bf16(rw2[ks], sfr, oacc[ii][nt], 0, 0, 0);
      }
    }
  }
  __syncthreads();
  #pragma unroll
  for(int ii = 0; ii < 2; ii++){
    int I = ii ? (7 - w) : w;
    int B = I * 16;
    #pragma unroll
    for(int nt = 0; nt < 4; nt++){
      #pragma unroll
      for(int r = 0; r < 4; r++){
        int i0 = B + quad * 4 + r;
        int v0 = nt * 16 + m16;
        outw[gbase + (size_t)i0 * Dd + v0] = oacc[ii][nt][r];
      }
    }
  }
}

// ---------------------------------------------------------------- groupnorm(64) + gate
__global__ __launch_bounds__(256) void k_norm(const float* __restrict__ outw,
                                              const bf16* __restrict__ gb,
                                              const bf16* __restrict__ lnw,
                                              const bf16* __restrict__ lnb,
                                              bf16* __restrict__ gated){
  int lr = blockIdx.x;
  int wv = threadIdx.x >> 6, lane = threadIdx.x & 63;
  for(int hh = wv; hh < Hh; hh += 4){
    size_t ix = (size_t)lr * Dd + hh * 64 + lane;
    float xv = outw[ix];
    float s1 = xv, s2 = xv * xv;
    #pragma unroll
    for(int off = 32; off > 0; off >>= 1){
      s1 += __shfl_xor(s1, off);
      s2 += __shfl_xor(s2, off);
    }
    float mu  = s1 * 0.015625f;
    float var = s2 * 0.015625f - mu * mu;
    float inv = rsqrtf(var + 6.4e-4f);
    float og  = (xv - mu) * inv * b2f(lnw[hh * 64 + lane]) + b2f(lnb[hh * 64 + lane]);
    gated[ix] = f2b(og * b2f(gb[ix]));
  }
}

// ---------------------------------------------------------------- host
extern "C" void kernel_launch(void* const* d_in, const int* in_sizes, int n_in,
                              void* d_out, int out_size, void* d_ws, size_t ws_size,
                              hipStream_t stream){
  char* W = (char*)d_ws;
  size_t cur = 0;
  auto carve = [&](size_t bytes) -> char* {
    char* p = W + cur;
    cur = (cur + bytes + 255) & ~(size_t)255;
    return p;
  };

  int* flag = (int*)carve(4096);
  static const int NEL[20] = {8388608, 1024, 1024, 1024, 1024, 1024, 1024,
                              163840, 163840, 1024, 65536, 65536, 1024,
                              1048576, 1048576, 1048576, 1048576, 1048576,
                              1024, 1024};
  bf16* canon[20];
  for(int i = 0; i < 20; i++) canon[i] = (bf16*)carve((size_t)NEL[i] * 2);

  k_detect<<<dim3(1), 256, 0, stream>>>((const unsigned short*)d_in[0], flag);
  for(int i = 0; i < 20; i++)
    k_conv<<<dim3((NEL[i] + 255) / 256), 256, 0, stream>>>(d_in[i], canon[i], NEL[i], flag);

  const bf16* xp   = canon[0];
  const bf16* tmx  = canon[1];
  const bf16* maas[5] = {canon[2], canon[3], canon[4], canon[5], canon[6]};
  const bf16* w2p  = canon[8];
  const bf16* tdec = canon[9];
  const bf16* up   = canon[12];
  const bf16* lnwp = canon[18];
  const bf16* lnbp = canon[19];

  bf16* WrT  = (bf16*)carve(2097152);
  bf16* WkT  = (bf16*)carve(2097152);
  bf16* WvT  = (bf16*)carve(2097152);
  bf16* WgT  = (bf16*)carve(2097152);
  bf16* WoT  = (bf16*)carve(2097152);
  bf16* W1T  = (bf16*)carve(256 * 1024 * 2);    // [256][1024], rows >=160 zero
  bf16* DW1T = (bf16*)carve(128 * 1024 * 2);    // [128][1024], rows >=64 zero
  bf16* DW2T = (bf16*)carve(1024 * 64 * 2);     // [1024][64]
  k_transpose<<<dim3(32, 32), 256, 0, stream>>>(canon[13], WrT);
  k_transpose<<<dim3(32, 32), 256, 0, stream>>>(canon[14], WkT);
  k_transpose<<<dim3(32, 32), 256, 0, stream>>>(canon[15], WvT);
  k_transpose<<<dim3(32, 32), 256, 0, stream>>>(canon[16], WgT);
  k_transpose<<<dim3(32, 32), 256, 0, stream>>>(canon[17], WoT);
  k_transposeP<<<dim3(1024), 256, 0, stream>>>(canon[7],  W1T,  1024, 160, 256);
  k_transposeP<<<dim3(512),  256, 0, stream>>>(canon[10], DW1T, 1024, 64, 128);
  k_transposeP<<<dim3(256),  256, 0, stream>>>(canon[11], DW2T, 64, 1024, 1024);

  float* st = (float*)carve(1u << 20);
  size_t FIXED = cur;

  // per-row bytes: xxx 512 + ww1 128 + wse 32 + xmx 2048 + mix 2048 + k/v/r/g 4*2048
  //              + wdec 4096 + wkvst 2048 = 19104
  const size_t UNIT = 19104, PAD = 65536;
  int nb, L;
  if(ws_size >= FIXED + (size_t)8192 * UNIT + PAD){ nb = 4; L = 2048; }
  else {
    nb = 1; L = 2048;
    while(L > 128 && ws_size < FIXED + (size_t)L * UNIT + PAD) L >>= 1;
  }
  const int Llog2 = __builtin_ctz((unsigned)L);
  const int nlog2 = Llog2 - 7;
  const int M     = nb * L;
  const size_t Mr = (size_t)M;

  bf16*  xxx    = (bf16*) carve(Mr * 512);     // [M][160] stored with ld 256
  bf16*  ww1    = (bf16*) carve(Mr * 128);
  float* wse    = (float*)carve(Mr * 32);
  bf16*  xmx    = (bf16*) carve(Mr * 2048);
  bf16*  mix    = (bf16*) carve(Mr * 2048);
  bf16*  kbuf   = (bf16*) carve(Mr * 2048);
  bf16*  vbuf   = (bf16*) carve(Mr * 2048);
  bf16*  rbuf   = (bf16*) carve(Mr * 2048);
  bf16*  gbuf   = (bf16*) carve(Mr * 2048);
  float* wdec   = (float*)carve(Mr * 4096);
  float* wkvst  = (float*)carve(Mr * 2048);
  float* outw   = wdec;   // chunk2 drains all wcum reads (barrier) before overwriting
  bf16*  gated  = mix;    // mix dead after last consumer GEMM

  for(int b0 = 0; b0 < 4; b0 += nb){
    for(int t0 = 0; t0 < Tt; t0 += L){
      // 1. xmx then xxx = tanh(xmx @ w1)  [MFMA, N=160 padded]
      k_prep<<<dim3(M * 4), 256, 0, stream>>>(xp, tmx, xmx, b0, t0, Llog2);
      gemm_mfma2<G2_TANH><<<dim3(2, M/128), 256, 0, stream>>>(
          xmx, W1T, xxx, 256, 160, 1024, nullptr);
      // 2. per-channel mix -> consumer; c order: w,k,v,r,g
      for(int c = 0; c < 5; c++){
        gemm_ep<EPI_MIX><<<dim3(16, M/64), 256, 0, stream>>>(
            xxx + c * 32, 256, w2p + (size_t)c * 32 * 1024, 1024,
            mix, 1024, M, 1024, 32, xp, maas[c], b0, t0, Llog2, flag);
        if(c == 0){
          gemm_mfma2<G2_TANH><<<dim3(1, M/128), 256, 0, stream>>>(
              mix, DW1T, ww1, 64, 64, 1024, nullptr);
          gemm_mfma2<G2_DECAY><<<dim3(8, M/128), 256, 0, stream>>>(
              ww1, DW2T, wdec, 1024, 1024, 64, tdec);
        } else if(c == 1){
          gemm_mfma<GEPI_BF16><<<dim3(8, M/128), 256, 0, stream>>>(mix, WkT, kbuf, flag, 0);
        } else if(c == 2){
          gemm_mfma<GEPI_BF16><<<dim3(8, M/128), 256, 0, stream>>>(mix, WvT, vbuf, flag, 0);
        } else if(c == 3){
          gemm_mfma<GEPI_BF16><<<dim3(8, M/128), 256, 0, stream>>>(mix, WrT, rbuf, flag, 0);
        } else {
          gemm_mfma<GEPI_SILU><<<dim3(8, M/128), 256, 0, stream>>>(mix, WgT, gbuf, flag, 0);
        }
      }
      // 3. chunked WKV
      int nloc = 1 << nlog2;
      k_cumsum<<<dim3(nb * nloc * 4), 256, 0, stream>>>(wdec, wse, nlog2);
      k_chunk1<<<dim3(nb * 16 * nloc), 256, 0, stream>>>(kbuf, vbuf, wdec, wkvst, nlog2);
      k_scan<<<dim3(nb * 16), 256, 0, stream>>>(wkvst, wse, st, b0, (t0 == 0) ? 1 : 0, nlog2);
      k_chunk2<<<dim3(nb * 16 * nloc), 256, 0, stream>>>(rbuf, kbuf, vbuf, wdec, wkvst, up, outw, nlog2);
      // 4. groupnorm + gate, output projection
      k_norm<<<dim3(M), 256, 0, stream>>>(outw, gbuf, lnwp, lnbp, gated);
      if(L == Tt){
        gemm_mfma<GEPI_OUT><<<dim3(8, M/128), 256, 0, stream>>>(gated, WoT, d_out, flag, b0 * Tt);
      } else {
        gemm_ep<EPI_OUTV><<<dim3(16, M/64), 256, 0, stream>>>(
            gated, 1024, canon[17], 1024, d_out, 1024, M, 1024, 1024,
            nullptr, nullptr, b0, t0, Llog2, flag);
      }
    }
  }
}

// Round 11
// 638.845 us; speedup vs baseline: 4.9857x; 1.1718x over previous
//
#include <hip/hip_runtime.h>
#include <hip/hip_bf16.h>
#include <math.h>

typedef __hip_bfloat16 bf16;
typedef __attribute__((ext_vector_type(8))) short short8;
typedef __attribute__((ext_vector_type(4))) float f32x4;

#define Tt 2048
#define Dd 1024
#define Hh 16

__device__ __forceinline__ float b2f(bf16 v){ return __bfloat162float(v); }
__device__ __forceinline__ bf16  f2b(float v){ return __float2bfloat16(v); }

__device__ __forceinline__ int seg_t(int lr, int t0, int Lm1){ return t0 + (lr & Lm1); }
__device__ __forceinline__ size_t seg_grow(int lr, int b0, int t0, int Llog2, int Lm1){
  return ((size_t)(b0 + (lr >> Llog2)) * Tt) + (size_t)seg_t(lr, t0, Lm1);
}

struct MixP { const bf16* maa[5]; bf16* dst[5]; };
struct Proj4 { const bf16* A[4]; const bf16* Bt[4]; bf16* C[4]; };

// ---------------------------------------------------------------- dtype detect
__global__ __launch_bounds__(256) void k_detect(const unsigned short* __restrict__ xs,
                                                int* __restrict__ flag){
  __shared__ int bad;
  if(threadIdx.x == 0) bad = 0;
  __syncthreads();
  int local = 0;
  for(int i = threadIdx.x; i < 8192; i += 256){
    unsigned e = (xs[i] >> 7) & 0xFF;
    if(e >= 0xC0) local++;
  }
  if(local) atomicAdd(&bad, local);
  __syncthreads();
  if(threadIdx.x == 0) flag[0] = (bad > 16) ? 1 : 0;   // 1 = inputs are float32
}

// ---------------------------------------------------------------- canonicalize to bf16
__global__ __launch_bounds__(256) void k_conv(const void* __restrict__ src,
                                              bf16* __restrict__ dst, int n,
                                              const int* __restrict__ flag){
  int i = blockIdx.x * 256 + threadIdx.x;
  if(i >= n) return;
  if(flag[0]) dst[i] = f2b(((const float*)src)[i]);
  else        dst[i] = ((const bf16*)src)[i];
}

// ---------------------------------------------------------------- 1024x1024 bf16 transpose
__global__ __launch_bounds__(256) void k_transpose(const bf16* __restrict__ src,
                                                   bf16* __restrict__ dst){
  __shared__ bf16 tile[32][33];
  int bx = blockIdx.x * 32, by = blockIdx.y * 32;
  int tx = threadIdx.x & 31, ty = threadIdx.x >> 5;   // 32 x 8
  for(int r = ty; r < 32; r += 8)
    tile[r][tx] = src[(size_t)(by + r) * 1024 + bx + tx];
  __syncthreads();
  for(int r = ty; r < 32; r += 8)
    dst[(size_t)(bx + r) * 1024 + by + tx] = tile[tx][r];
}

// ---------------------------------------------------------------- generic transpose+pad: dst[Npad][K] = src[K][N]^T
__global__ __launch_bounds__(256) void k_transposeP(const bf16* __restrict__ src,
                                                    bf16* __restrict__ dst,
                                                    int K, int N, int Npad){
  int idx = blockIdx.x * 256 + threadIdx.x;
  if(idx >= Npad * K) return;
  int n = idx / K, k = idx - n * K;
  dst[idx] = (n < N) ? src[(size_t)k * N + n] : f2b(0.f);
}

// ---------------------------------------------------------------- k_prep: xmx = x + (shift(x)-x)*tmx
__global__ __launch_bounds__(256) void k_prep(const bf16* __restrict__ x,
                                              const bf16* __restrict__ tmx,
                                              bf16* __restrict__ xmx,
                                              int b0, int t0, int Llog2){
  const int Lm1 = (1 << Llog2) - 1;
  int idx = blockIdx.x * 256 + threadIdx.x;
  int lr = idx >> 10, d = idx & 1023;
  size_t grow = seg_grow(lr, b0, t0, Llog2, Lm1);
  int tl = seg_t(lr, t0, Lm1);
  float xc = b2f(x[grow * Dd + d]);
  float xp = tl ? b2f(x[(grow - 1) * Dd + d]) : 0.f;
  xmx[idx] = f2b(xc + (xp - xc) * b2f(tmx[d]));
}

// ---------------------------------------------------------------- MFMA GEMM (fixed 1024x1024)
constexpr int GEPI_BF16 = 0, GEPI_SILU = 1, GEPI_OUT = 2;

template<int EPI>
__global__ __launch_bounds__(256) void gemm_mfma(
    const bf16* __restrict__ A,
    const bf16* __restrict__ Bt,
    void* __restrict__ Cv,
    const int* __restrict__ oflag,
    int rowoff){
  __shared__ short As[128 * 40];
  __shared__ short Bs[128 * 40];
  int tid = threadIdx.x;
  int bn = blockIdx.x * 128;
  int bm = blockIdx.y * 128;
  int w = tid >> 6, lane = tid & 63;
  int wm = (w & 1) * 64, wn = (w >> 1) * 64;
  int m16 = lane & 15, quad = lane >> 4;

  f32x4 acc[4][4];
  #pragma unroll
  for(int mi = 0; mi < 4; mi++)
    #pragma unroll
    for(int ni = 0; ni < 4; ni++)
      acc[mi][ni] = (f32x4){0.f, 0.f, 0.f, 0.f};

  int srow = tid >> 2;
  int sk8  = (tid & 3) * 8;
  const bf16* Ag = A  + (size_t)(bm + srow) * 1024 + sk8;
  const bf16* Bg = Bt + (size_t)(bn + srow) * 1024 + sk8;
  short* Aw = As + srow * 40 + sk8;
  short* Bw = Bs + srow * 40 + sk8;

  for(int kb = 0; kb < 1024; kb += 32){
    #pragma unroll
    for(int rep = 0; rep < 2; rep++){
      *(short8*)(Aw + rep * 64 * 40) = *(const short8*)(Ag + (size_t)rep * 64 * 1024 + kb);
      *(short8*)(Bw + rep * 64 * 40) = *(const short8*)(Bg + (size_t)rep * 64 * 1024 + kb);
    }
    __syncthreads();
    short8 af[4], bfr[4];
    #pragma unroll
    for(int mi = 0; mi < 4; mi++)
      af[mi] = *(const short8*)(As + (wm + mi * 16 + m16) * 40 + quad * 8);
    #pragma unroll
    for(int ni = 0; ni < 4; ni++)
      bfr[ni] = *(const short8*)(Bs + (wn + ni * 16 + m16) * 40 + quad * 8);
    #pragma unroll
    for(int mi = 0; mi < 4; mi++)
      #pragma unroll
      for(int ni = 0; ni < 4; ni++)
        acc[mi][ni] = __builtin_amdgcn_mfma_f32_16x16x32_bf16(af[mi], bfr[ni], acc[mi][ni], 0, 0, 0);
    __syncthreads();
  }
  #pragma unroll
  for(int mi = 0; mi < 4; mi++){
    #pragma unroll
    for(int ni = 0; ni < 4; ni++){
      #pragma unroll
      for(int r = 0; r < 4; r++){
        int row = bm + wm + mi * 16 + quad * 4 + r;
        int col = bn + wn + ni * 16 + m16;
        float v = acc[mi][ni][r];
        if constexpr(EPI == GEPI_BF16){
          ((bf16*)Cv)[(size_t)row * 1024 + col] = f2b(v);
        } else if constexpr(EPI == GEPI_SILU){
          ((bf16*)Cv)[(size_t)row * 1024 + col] = f2b(v / (1.f + expf(-v)));
        } else { // GEPI_OUT
          size_t off = (size_t)(row + rowoff) * 1024 + col;
          if(oflag[0]) ((float*)Cv)[off] = v;
          else         ((bf16*)Cv)[off]  = f2b(v);
        }
      }
    }
  }
}

// ---------------------------------------------------------------- 4-in-1 projection GEMM (z: 0=k,1=v,2=r,3=g/silu)
__global__ __launch_bounds__(256) void gemm_proj4(Proj4 prm){
  int z = blockIdx.z;
  const bf16* __restrict__ A  = prm.A[z];
  const bf16* __restrict__ Bt = prm.Bt[z];
  bf16* __restrict__ C        = prm.C[z];
  __shared__ short As[128 * 40];
  __shared__ short Bs[128 * 40];
  int tid = threadIdx.x;
  int bn = blockIdx.x * 128;
  int bm = blockIdx.y * 128;
  int w = tid >> 6, lane = tid & 63;
  int wm = (w & 1) * 64, wn = (w >> 1) * 64;
  int m16 = lane & 15, quad = lane >> 4;

  f32x4 acc[4][4];
  #pragma unroll
  for(int mi = 0; mi < 4; mi++)
    #pragma unroll
    for(int ni = 0; ni < 4; ni++)
      acc[mi][ni] = (f32x4){0.f, 0.f, 0.f, 0.f};

  int srow = tid >> 2;
  int sk8  = (tid & 3) * 8;
  const bf16* Ag = A  + (size_t)(bm + srow) * 1024 + sk8;
  const bf16* Bg = Bt + (size_t)(bn + srow) * 1024 + sk8;
  short* Aw = As + srow * 40 + sk8;
  short* Bw = Bs + srow * 40 + sk8;

  for(int kb = 0; kb < 1024; kb += 32){
    #pragma unroll
    for(int rep = 0; rep < 2; rep++){
      *(short8*)(Aw + rep * 64 * 40) = *(const short8*)(Ag + (size_t)rep * 64 * 1024 + kb);
      *(short8*)(Bw + rep * 64 * 40) = *(const short8*)(Bg + (size_t)rep * 64 * 1024 + kb);
    }
    __syncthreads();
    short8 af[4], bfr[4];
    #pragma unroll
    for(int mi = 0; mi < 4; mi++)
      af[mi] = *(const short8*)(As + (wm + mi * 16 + m16) * 40 + quad * 8);
    #pragma unroll
    for(int ni = 0; ni < 4; ni++)
      bfr[ni] = *(const short8*)(Bs + (wn + ni * 16 + m16) * 40 + quad * 8);
    #pragma unroll
    for(int mi = 0; mi < 4; mi++)
      #pragma unroll
      for(int ni = 0; ni < 4; ni++)
        acc[mi][ni] = __builtin_amdgcn_mfma_f32_16x16x32_bf16(af[mi], bfr[ni], acc[mi][ni], 0, 0, 0);
    __syncthreads();
  }
  bool silu = (z == 3);
  #pragma unroll
  for(int mi = 0; mi < 4; mi++){
    #pragma unroll
    for(int ni = 0; ni < 4; ni++){
      #pragma unroll
      for(int r = 0; r < 4; r++){
        int row = bm + wm + mi * 16 + quad * 4 + r;
        int col = bn + wn + ni * 16 + m16;
        float v = acc[mi][ni][r];
        if(silu) v = v / (1.f + expf(-v));
        C[(size_t)row * 1024 + col] = f2b(v);
      }
    }
  }
}

// ---------------------------------------------------------------- fused 5-channel mix (K=32 MFMA + mix epilogue)
// mix_c = x + (shift(x)-x) * (maa_c[col] + (xxx_c @ w2_c)[row][col])
__global__ __launch_bounds__(256) void gemm_mix(
    const bf16* __restrict__ xxx,   // [M][160] ld 256
    const bf16* __restrict__ w2T,   // [5][1024][32]
    const bf16* __restrict__ xg,
    MixP prm, int b0, int t0, int Llog2){
  const int Lm1 = (1 << Llog2) - 1;
  int c = blockIdx.z;
  __shared__ short As[128 * 40];
  __shared__ short Bs[128 * 40];
  int tid = threadIdx.x;
  int bn = blockIdx.x * 128;
  int bm = blockIdx.y * 128;
  int w = tid >> 6, lane = tid & 63;
  int wm = (w & 1) * 64, wn = (w >> 1) * 64;
  int m16 = lane & 15, quad = lane >> 4;

  int srow = tid >> 2;
  int sk8  = (tid & 3) * 8;
  #pragma unroll
  for(int rep = 0; rep < 2; rep++){
    *(short8*)(As + (srow + rep * 64) * 40 + sk8) =
        *(const short8*)(xxx + (size_t)(bm + srow + rep * 64) * 256 + c * 32 + sk8);
    *(short8*)(Bs + (srow + rep * 64) * 40 + sk8) =
        *(const short8*)(w2T + (size_t)c * 32768 + (size_t)(bn + srow + rep * 64) * 32 + sk8);
  }
  __syncthreads();
  f32x4 acc[4][4];
  short8 af[4], bfr[4];
  #pragma unroll
  for(int mi = 0; mi < 4; mi++)
    af[mi] = *(const short8*)(As + (wm + mi * 16 + m16) * 40 + quad * 8);
  #pragma unroll
  for(int ni = 0; ni < 4; ni++)
    bfr[ni] = *(const short8*)(Bs + (wn + ni * 16 + m16) * 40 + quad * 8);
  #pragma unroll
  for(int mi = 0; mi < 4; mi++)
    #pragma unroll
    for(int ni = 0; ni < 4; ni++)
      acc[mi][ni] = __builtin_amdgcn_mfma_f32_16x16x32_bf16(
          af[mi], bfr[ni], (f32x4){0.f, 0.f, 0.f, 0.f}, 0, 0, 0);

  const bf16* maa = prm.maa[c];
  bf16* dst = prm.dst[c];
  #pragma unroll
  for(int mi = 0; mi < 4; mi++){
    #pragma unroll
    for(int ni = 0; ni < 4; ni++){
      #pragma unroll
      for(int r = 0; r < 4; r++){
        int row = bm + wm + mi * 16 + quad * 4 + r;
        int col = bn + wn + ni * 16 + m16;
        size_t grow = seg_grow(row, b0, t0, Llog2, Lm1);
        int tl = seg_t(row, t0, Lm1);
        float xc = b2f(xg[grow * Dd + col]);
        float xp = tl ? b2f(xg[(grow - 1) * Dd + col]) : 0.f;
        dst[(size_t)row * 1024 + col] =
            f2b(xc + (xp - xc) * (b2f(maa[col]) + acc[mi][ni][r]));
      }
    }
  }
}

// ---------------------------------------------------------------- generic MFMA GEMM (runtime N/K, padded Bt, edge-masked C)
constexpr int G2_TANH = 0, G2_DECAY = 1;

template<int EPI>
__global__ __launch_bounds__(256) void gemm_mfma2(
    const bf16* __restrict__ A,
    const bf16* __restrict__ Bt,
    void* __restrict__ Cv, int ldc,
    int Ndim, int Kdim,
    const bf16* __restrict__ e_w){
  __shared__ short As[128 * 40];
  __shared__ short Bs[128 * 40];
  int tid = threadIdx.x;
  int bn = blockIdx.x * 128;
  int bm = blockIdx.y * 128;
  int w = tid >> 6, lane = tid & 63;
  int wm = (w & 1) * 64, wn = (w >> 1) * 64;
  int m16 = lane & 15, quad = lane >> 4;

  f32x4 acc[4][4];
  #pragma unroll
  for(int mi = 0; mi < 4; mi++)
    #pragma unroll
    for(int ni = 0; ni < 4; ni++)
      acc[mi][ni] = (f32x4){0.f, 0.f, 0.f, 0.f};

  int srow = tid >> 2;
  int sk8  = (tid & 3) * 8;
  const bf16* Ag = A  + (size_t)(bm + srow) * Kdim + sk8;
  const bf16* Bg = Bt + (size_t)(bn + srow) * Kdim + sk8;
  short* Aw = As + srow * 40 + sk8;
  short* Bw = Bs + srow * 40 + sk8;

  for(int kb = 0; kb < Kdim; kb += 32){
    #pragma unroll
    for(int rep = 0; rep < 2; rep++){
      *(short8*)(Aw + rep * 64 * 40) = *(const short8*)(Ag + (size_t)rep * 64 * Kdim + kb);
      *(short8*)(Bw + rep * 64 * 40) = *(const short8*)(Bg + (size_t)rep * 64 * Kdim + kb);
    }
    __syncthreads();
    short8 af[4], bfr[4];
    #pragma unroll
    for(int mi = 0; mi < 4; mi++)
      af[mi] = *(const short8*)(As + (wm + mi * 16 + m16) * 40 + quad * 8);
    #pragma unroll
    for(int ni = 0; ni < 4; ni++)
      bfr[ni] = *(const short8*)(Bs + (wn + ni * 16 + m16) * 40 + quad * 8);
    #pragma unroll
    for(int mi = 0; mi < 4; mi++)
      #pragma unroll
      for(int ni = 0; ni < 4; ni++)
        acc[mi][ni] = __builtin_amdgcn_mfma_f32_16x16x32_bf16(af[mi], bfr[ni], acc[mi][ni], 0, 0, 0);
    __syncthreads();
  }
  #pragma unroll
  for(int mi = 0; mi < 4; mi++){
    #pragma unroll
    for(int ni = 0; ni < 4; ni++){
      #pragma unroll
      for(int r = 0; r < 4; r++){
        int row = bm + wm + mi * 16 + quad * 4 + r;
        int col = bn + wn + ni * 16 + m16;
        if(col >= Ndim) continue;
        float v = acc[mi][ni][r];
        size_t off = (size_t)row * ldc + col;
        if constexpr(EPI == G2_TANH){
          ((bf16*)Cv)[off] = f2b(tanhf(v));
        } else { // G2_DECAY
          float td = b2f(e_w[col]) + v;
          ((float*)Cv)[off] = fmaxf(-expf(td), -5.2983173665480363f);
        }
      }
    }
  }
}

// ---------------------------------------------------------------- small VALU GEMM (segmented-out fallback only)
constexpr int EPI_OUTV = 5;
#define BM 64
#define BN 64
#define BK 16

template<int EPI>
__global__ __launch_bounds__(256) void gemm_ep(
    const bf16* __restrict__ A, int lda,
    const bf16* __restrict__ Bm, int ldb,
    void* __restrict__ Cv, int ldc,
    int Mdim, int Ndim, int Kdim,
    const bf16* __restrict__ xg, const bf16* __restrict__ e_w,
    int b0, int t0, int Llog2, const int* __restrict__ oflag){
  const int Lm1 = (1 << Llog2) - 1;
  __shared__ float As[BM][BK + 1];
  __shared__ float Bs[BK][BN + 4];
  int tid = threadIdx.x;
  int tx = tid & 15, ty = tid >> 4;
  int bm = blockIdx.y * BM, bn = blockIdx.x * BN;
  float acc[4][4] = {};
  for(int kb = 0; kb < Kdim; kb += BK){
    {
      int lr = tid >> 2;
      int lc = (tid & 3) * 4;
      int gr = bm + lr;
      #pragma unroll
      for(int q = 0; q < 4; q++){
        int gc = kb + lc + q;
        float av = 0.f;
        if(gr < Mdim && gc < Kdim)
          av = b2f(A[(size_t)gr * lda + gc]);
        As[lr][lc + q] = av;
      }
    }
    {
      int lr = tid >> 4;
      int lc = (tid & 15) * 4;
      #pragma unroll
      for(int q = 0; q < 4; q++){
        int gr = kb + lr; int gc = bn + lc + q;
        Bs[lr][lc + q] = (gr < Kdim && gc < Ndim) ? b2f(Bm[(size_t)gr * ldb + gc]) : 0.f;
      }
    }
    __syncthreads();
    #pragma unroll
    for(int kk = 0; kk < BK; kk++){
      float ar[4], br[4];
      #pragma unroll
      for(int q = 0; q < 4; q++) ar[q] = As[ty * 4 + q][kk];
      #pragma unroll
      for(int q = 0; q < 4; q++) br[q] = Bs[kk][tx * 4 + q];
      #pragma unroll
      for(int mi = 0; mi < 4; mi++)
        #pragma unroll
        for(int ni = 0; ni < 4; ni++)
          acc[mi][ni] += ar[mi] * br[ni];
    }
    __syncthreads();
  }
  #pragma unroll
  for(int mi = 0; mi < 4; mi++){
    int row = bm + ty * 4 + mi;
    if(row >= Mdim) continue;
    #pragma unroll
    for(int ni = 0; ni < 4; ni++){
      int col = bn + tx * 4 + ni;
      if(col >= Ndim) continue;
      float vacc = acc[mi][ni];
      size_t grow = seg_grow(row, b0, t0, Llog2, Lm1);
      size_t go = grow * Dd + col;
      if(oflag[0]) ((float*)Cv)[go] = vacc;
      else         ((bf16*)Cv)[go]  = f2b(vacc);
    }
  }
}

// ---------------------------------------------------------------- cumsum (in place wlog->wcum) + wse
__global__ __launch_bounds__(256) void k_cumsum(float* __restrict__ wd,
                                                float* __restrict__ wse,
                                                int nlog2){
  int blk = blockIdx.x;
  int dg = blk & 3; int rest = blk >> 2;
  int nmask = (1 << nlog2) - 1;
  int ln = rest & nmask; int bp = rest >> nlog2;
  int d = dg * 256 + threadIdx.x;
  size_t rowbase = (((size_t)bp << nlog2) + ln) * 128;
  size_t base = rowbase * Dd + d;
  float c = 0.f;
  for(int t = 0; t < 128; t++){
    size_t ix = base + (size_t)t * Dd;
    c += wd[ix];
    wd[ix] = c;
  }
  int h = d >> 6, k0 = d & 63;
  wse[((((size_t)bp * Hh + h) << nlog2) | ln) * 64 + k0] = __expf(fminf(c, 0.f));
}

// ---------------------------------------------------------------- chunk1 (MFMA)
__global__ __launch_bounds__(256) void k_chunk1(const bf16* __restrict__ kb,
                                                const bf16* __restrict__ vb,
                                                const float* __restrict__ wcum,
                                                float* __restrict__ wkv,
                                                int nlog2){
  __shared__ __align__(16) bf16 ktT[64 * 136];
  __shared__ __align__(16) bf16 vT2[64 * 136];
  int tid = threadIdx.x, blk = blockIdx.x;
  int nmask = (1 << nlog2) - 1;
  int ln = blk & nmask; int rest = blk >> nlog2;
  int h = rest & 15; int bp = rest >> 4;
  size_t rowbase = (((size_t)bp << nlog2) + ln) * 128;
  size_t gbase = rowbase * Dd + h * 64;
  for(int r = 0; r < 32; r++){
    int idx = r * 256 + tid;
    int t0 = idx >> 6, k0 = idx & 63;
    size_t gi = gbase + (size_t)t0 * Dd + k0;
    float c  = wcum[gi];
    float cL = wcum[gbase + (size_t)127 * Dd + k0];
    ktT[k0 * 136 + t0] = f2b(b2f(kb[gi]) * __expf(fminf(cL - c, 0.f)));
    vT2[k0 * 136 + t0] = vb[gi];
  }
  __syncthreads();
  int w = tid >> 6, lane = tid & 63;
  int m16 = lane & 15, quad = lane >> 4;
  f32x4 acc[4];
  #pragma unroll
  for(int nt = 0; nt < 4; nt++) acc[nt] = (f32x4){0.f, 0.f, 0.f, 0.f};
  #pragma unroll
  for(int ks = 0; ks < 4; ks++){
    short8 af = *(const short8*)(ktT + (w * 16 + m16) * 136 + ks * 32 + quad * 8);
    #pragma unroll
    for(int nt = 0; nt < 4; nt++){
      short8 bfr = *(const short8*)(vT2 + (nt * 16 + m16) * 136 + ks * 32 + quad * 8);
      acc[nt] = __builtin_amdgcn_mfma_f32_16x16x32_bf16(af, bfr, acc[nt], 0, 0, 0);
    }
  }
  size_t obase = (size_t)blk * 4096;
  #pragma unroll
  for(int nt = 0; nt < 4; nt++)
    #pragma unroll
    for(int r = 0; r < 4; r++)
      wkv[obase + (size_t)(w * 16 + quad * 4 + r) * 64 + nt * 16 + m16] = acc[nt][r];
}

// ---------------------------------------------------------------- state scan, in place, carry in st
__global__ __launch_bounds__(256) void k_scan(float* __restrict__ buf,
                                              const float* __restrict__ wse,
                                              float* __restrict__ st,
                                              int b0, int firstseg, int nlog2){
  int blk = blockIdx.x;
  int h = blk & 15, bp = blk >> 4;
  int tid = threadIdx.x;
  size_t stbase = ((size_t)(b0 + bp) * Hh + h) * 4096;
  int nloc = 1 << nlog2;
  float s[16];
  #pragma unroll
  for(int r = 0; r < 16; r++)
    s[r] = firstseg ? 0.f : st[stbase + r * 256 + tid];
  for(int ln = 0; ln < nloc; ln++){
    size_t idx = (((size_t)bp * Hh + h) << nlog2) | ln;
    size_t base = idx * 4096;
    const float* wsp = wse + idx * 64;
    #pragma unroll
    for(int r = 0; r < 16; r++){
      int e = r * 256 + tid;
      float tmp = buf[base + e];
      buf[base + e] = s[r];
      s[r] = s[r] * wsp[e >> 6] + tmp;
    }
  }
  #pragma unroll
  for(int r = 0; r < 16; r++)
    st[stbase + r * 256 + tid] = s[r];
}

// ---------------------------------------------------------------- chunk2: full-MFMA intra attention (R9, proven)
__global__ __launch_bounds__(256) void k_chunk2(
    const bf16* __restrict__ rb, const bf16* __restrict__ kb,
    const bf16* __restrict__ vb, const float* __restrict__ wcum,
    const float* __restrict__ states, const bf16* __restrict__ u,
    float* __restrict__ outw, int nlog2){
  __shared__ __align__(16) bf16 vT[64 * 136];
  __shared__ __align__(16) bf16 sT[64 * 72];
  __shared__ __align__(16) bf16 ascr[4 * 16 * 136];
  int tid = threadIdx.x, blk = blockIdx.x;
  int nmask = (1 << nlog2) - 1;
  int ln = blk & nmask; int rest = blk >> nlog2;
  int h = rest & 15; int bp = rest >> 4;
  size_t rowbase = (((size_t)bp << nlog2) + ln) * 128;
  size_t gbase = rowbase * Dd + h * 64;
  for(int r = 0; r < 32; r++){
    int idx = r * 256 + tid;
    int t0 = idx >> 6, v0 = idx & 63;
    vT[v0 * 136 + t0] = vb[gbase + (size_t)t0 * Dd + v0];
  }
  for(int r = 0; r < 16; r++){
    int idx = r * 256 + tid;
    int k0 = idx >> 6, v0 = idx & 63;
    sT[v0 * 72 + k0] = f2b(states[(size_t)blk * 4096 + k0 * 64 + v0]);
  }
  __syncthreads();
  int w = tid >> 6, lane = tid & 63;
  int m16 = lane & 15, quad = lane >> 4;
  bf16* scr = ascr + w * (16 * 136);
  f32x4 oacc[2][4];
  #pragma unroll
  for(int a1 = 0; a1 < 2; a1++)
    #pragma unroll
    for(int a2 = 0; a2 < 4; a2++) oacc[a1][a2] = (f32x4){0.f, 0.f, 0.f, 0.f};

  for(int ii = 0; ii < 2; ii++){
    int I = ii ? (7 - w) : w;
    int B = I * 16;
    for(int z = lane; z < 544; z += 64) ((unsigned long long*)scr)[z] = 0ULL;
    int i0 = B + m16;
    size_t rowi = rowbase + i0;
    short8 rf[2], af[2], rw2[2];
    float crv[2][8];
    #pragma unroll
    for(int ks = 0; ks < 2; ks++){
      int koff = h * 64 + ks * 32 + quad * 8;
      rf[ks] = *(const short8*)(rb + rowi * Dd + koff);
      float cp[8];
      if(i0 > 0){
        f32x4 c0 = *(const f32x4*)(wcum + (rowi - 1) * Dd + koff);
        f32x4 c1 = *(const f32x4*)(wcum + (rowi - 1) * Dd + koff + 4);
        #pragma unroll
        for(int c = 0; c < 4; c++){ cp[c] = c0[c]; cp[4 + c] = c1[c]; }
      } else {
        #pragma unroll
        for(int c = 0; c < 8; c++) cp[c] = 0.f;
      }
      if(B > 0){
        f32x4 c0 = *(const f32x4*)(wcum + (rowbase + B - 1) * Dd + koff);
        f32x4 c1 = *(const f32x4*)(wcum + (rowbase + B - 1) * Dd + koff + 4);
        #pragma unroll
        for(int c = 0; c < 4; c++){ crv[ks][c] = c0[c]; crv[ks][4 + c] = c1[c]; }
      } else {
        #pragma unroll
        for(int c = 0; c < 8; c++) crv[ks][c] = 0.f;
      }
      short8 av, wv;
      #pragma unroll
      for(int c = 0; c < 8; c++){
        float rv = b2f(((const bf16*)&rf[ks])[c]);
        ((bf16*)&av)[c] = f2b(rv * __expf(fminf(cp[c] - crv[ks][c], 0.f)));
        ((bf16*)&wv)[c] = f2b(rv * __expf(fminf(cp[c], 0.f)));
      }
      af[ks] = av; rw2[ks] = wv;
    }
    for(int J = 0; J < I; J++){
      f32x4 aacc = (f32x4){0.f, 0.f, 0.f, 0.f};
      #pragma unroll
      for(int ks = 0; ks < 2; ks++){
        int koff = h * 64 + ks * 32 + quad * 8;
        size_t rowj = rowbase + J * 16 + m16;
        short8 k8 = *(const short8*)(kb + rowj * Dd + koff);
        f32x4 c0 = *(const f32x4*)(wcum + rowj * Dd + koff);
        f32x4 c1 = *(const f32x4*)(wcum + rowj * Dd + koff + 4);
        short8 bfrag;
        #pragma unroll
        for(int c = 0; c < 8; c++){
          float kv = b2f(((const bf16*)&k8)[c]);
          float cj = (c < 4) ? c0[c] : c1[c - 4];
          ((bf16*)&bfrag)[c] = f2b(kv * __expf(fminf(crv[ks][c] - cj, 0.f)));
        }
        aacc = __builtin_amdgcn_mfma_f32_16x16x32_bf16(af[ks], bfrag, aacc, 0, 0, 0);
      }
      #pragma unroll
      for(int r = 0; r < 4; r++)
        scr[(quad * 4 + r) * 136 + J * 16 + m16] = f2b(aacc[r]);
    }
    {
      f32x4 aacc = (f32x4){0.f, 0.f, 0.f, 0.f};
      f32x4 dacc = (f32x4){0.f, 0.f, 0.f, 0.f};
      #pragma unroll
      for(int ks = 0; ks < 2; ks++){
        int koff = h * 64 + ks * 32 + quad * 8;
        size_t rowj = rowbase + B + m16;
        short8 k8 = *(const short8*)(kb + rowj * Dd + koff);
        f32x4 c0 = *(const f32x4*)(wcum + rowj * Dd + koff);
        f32x4 c1 = *(const f32x4*)(wcum + rowj * Dd + koff + 4);
        short8 u8 = *(const short8*)(u + h * 64 + ks * 32 + quad * 8);
        short8 bf1, bf2;
        #pragma unroll
        for(int c = 0; c < 8; c++){
          float kv = b2f(((const bf16*)&k8)[c]);
          float cj = (c < 4) ? c0[c] : c1[c - 4];
          ((bf16*)&bf1)[c] = f2b(kv * __expf(crv[ks][c] - cj));
          ((bf16*)&bf2)[c] = f2b(kv * b2f(((const bf16*)&u8)[c]));
        }
        aacc = __builtin_amdgcn_mfma_f32_16x16x32_bf16(af[ks], bf1, aacc, 0, 0, 0);
        dacc = __builtin_amdgcn_mfma_f32_16x16x32_bf16(rf[ks], bf2, dacc, 0, 0, 0);
      }
      #pragma unroll
      for(int r = 0; r < 4; r++){
        int row = quad * 4 + r, col = m16;
        if(col < row)       scr[row * 136 + B + col] = f2b(aacc[r]);
        else if(col == row) scr[row * 136 + B + col] = f2b(dacc[r]);
      }
    }
    asm volatile("s_waitcnt lgkmcnt(0)" ::: "memory");
    int nks = (I + 2) >> 1;
    for(int ks2 = 0; ks2 < nks; ks2++){
      short8 afr = *(const short8*)(scr + m16 * 136 + ks2 * 32 + quad * 8);
      #pragma unroll
      for(int nt = 0; nt < 4; nt++){
        short8 bfr = *(const short8*)(vT + (nt * 16 + m16) * 136 + ks2 * 32 + quad * 8);
        oacc[ii][nt] = __builtin_amdgcn_mfma_f32_16x16x32_bf16(afr, bfr, oacc[ii][nt], 0, 0, 0);
      }
    }
    #pragma unroll
    for(int ks = 0; ks < 2; ks++){
      #pragma unroll
      for(int nt = 0; nt < 4; nt++){
        short8 sfr = *(const short8*)(sT + (nt * 16 + m16) * 72 + ks * 32 + quad * 8);
        oacc[ii][nt] = __builtin_amdgcn_mfma_f32_16x16x32_bf16(rw2[ks], sfr, oacc[ii][nt], 0, 0, 0);
      }
    }
  }
  __syncthreads();
  #pragma unroll
  for(int ii = 0; ii < 2; ii++){
    int I = ii ? (7 - w) : w;
    int B = I * 16;
    #pragma unroll
    for(int nt = 0; nt < 4; nt++){
      #pragma unroll
      for(int r = 0; r < 4; r++){
        int i0 = B + quad * 4 + r;
        int v0 = nt * 16 + m16;
        outw[gbase + (size_t)i0 * Dd + v0] = oacc[ii][nt][r];
      }
    }
  }
}

// ---------------------------------------------------------------- groupnorm(64) + gate
__global__ __launch_bounds__(256) void k_norm(const float* __restrict__ outw,
                                              const bf16* __restrict__ gb,
                                              const bf16* __restrict__ lnw,
                                              const bf16* __restrict__ lnb,
                                              bf16* __restrict__ gated){
  int lr = blockIdx.x;
  int wv = threadIdx.x >> 6, lane = threadIdx.x & 63;
  for(int hh = wv; hh < Hh; hh += 4){
    size_t ix = (size_t)lr * Dd + hh * 64 + lane;
    float xv = outw[ix];
    float s1 = xv, s2 = xv * xv;
    #pragma unroll
    for(int off = 32; off > 0; off >>= 1){
      s1 += __shfl_xor(s1, off);
      s2 += __shfl_xor(s2, off);
    }
    float mu  = s1 * 0.015625f;
    float var = s2 * 0.015625f - mu * mu;
    float inv = rsqrtf(var + 6.4e-4f);
    float og  = (xv - mu) * inv * b2f(lnw[hh * 64 + lane]) + b2f(lnb[hh * 64 + lane]);
    gated[ix] = f2b(og * b2f(gb[ix]));
  }
}

// ---------------------------------------------------------------- host
extern "C" void kernel_launch(void* const* d_in, const int* in_sizes, int n_in,
                              void* d_out, int out_size, void* d_ws, size_t ws_size,
                              hipStream_t stream){
  char* W = (char*)d_ws;
  size_t cur = 0;
  auto carve = [&](size_t bytes) -> char* {
    char* p = W + cur;
    cur = (cur + bytes + 255) & ~(size_t)255;
    return p;
  };

  int* flag = (int*)carve(4096);
  static const int NEL[20] = {8388608, 1024, 1024, 1024, 1024, 1024, 1024,
                              163840, 163840, 1024, 65536, 65536, 1024,
                              1048576, 1048576, 1048576, 1048576, 1048576,
                              1024, 1024};
  bf16* canon[20];
  for(int i = 0; i < 20; i++) canon[i] = (bf16*)carve((size_t)NEL[i] * 2);

  k_detect<<<dim3(1), 256, 0, stream>>>((const unsigned short*)d_in[0], flag);
  for(int i = 0; i < 20; i++)
    k_conv<<<dim3((NEL[i] + 255) / 256), 256, 0, stream>>>(d_in[i], canon[i], NEL[i], flag);

  const bf16* xp   = canon[0];
  const bf16* tmx  = canon[1];
  const bf16* tdec = canon[9];
  const bf16* up   = canon[12];
  const bf16* lnwp = canon[18];
  const bf16* lnbp = canon[19];

  bf16* WrT  = (bf16*)carve(2097152);
  bf16* WkT  = (bf16*)carve(2097152);
  bf16* WvT  = (bf16*)carve(2097152);
  bf16* WgT  = (bf16*)carve(2097152);
  bf16* WoT  = (bf16*)carve(2097152);
  bf16* W1T  = (bf16*)carve(256 * 1024 * 2);    // [256][1024], rows >=160 zero
  bf16* DW1T = (bf16*)carve(128 * 1024 * 2);    // [128][1024], rows >=64 zero
  bf16* DW2T = (bf16*)carve(1024 * 64 * 2);     // [1024][64]
  bf16* W2T  = (bf16*)carve(5 * 1024 * 32 * 2); // [5][1024][32]
  k_transpose<<<dim3(32, 32), 256, 0, stream>>>(canon[13], WrT);
  k_transpose<<<dim3(32, 32), 256, 0, stream>>>(canon[14], WkT);
  k_transpose<<<dim3(32, 32), 256, 0, stream>>>(canon[15], WvT);
  k_transpose<<<dim3(32, 32), 256, 0, stream>>>(canon[16], WgT);
  k_transpose<<<dim3(32, 32), 256, 0, stream>>>(canon[17], WoT);
  k_transposeP<<<dim3(1024), 256, 0, stream>>>(canon[7],  W1T,  1024, 160, 256);
  k_transposeP<<<dim3(512),  256, 0, stream>>>(canon[10], DW1T, 1024, 64, 128);
  k_transposeP<<<dim3(256),  256, 0, stream>>>(canon[11], DW2T, 64, 1024, 1024);
  for(int c = 0; c < 5; c++)
    k_transposeP<<<dim3(128), 256, 0, stream>>>(canon[8] + (size_t)c * 32768,
                                                W2T + (size_t)c * 32768, 32, 1024, 1024);

  float* st = (float*)carve(1u << 20);
  size_t FIXED = cur;

  // per-row bytes: xxx 512 + ww1 128 + wse 32 + xmx 2048 + mix 2048 + k/v/r/g 4*2048
  //              + wdec 4096 + wkvst 2048 = 19104
  const size_t UNIT = 19104, PAD = 65536;
  int nb, L;
  if(ws_size >= FIXED + (size_t)8192 * UNIT + PAD){ nb = 4; L = 2048; }
  else {
    nb = 1; L = 2048;
    while(L > 128 && ws_size < FIXED + (size_t)L * UNIT + PAD) L >>= 1;
  }
  const int Llog2 = __builtin_ctz((unsigned)L);
  const int nlog2 = Llog2 - 7;
  const int M     = nb * L;
  const size_t Mr = (size_t)M;

  bf16*  xxx    = (bf16*) carve(Mr * 512);     // [M][160] ld 256
  bf16*  ww1    = (bf16*) carve(Mr * 128);
  float* wse    = (float*)carve(Mr * 32);
  bf16*  xmx    = (bf16*) carve(Mr * 2048);
  bf16*  mixbuf = (bf16*) carve(Mr * 2048);
  bf16*  kbuf   = (bf16*) carve(Mr * 2048);
  bf16*  vbuf   = (bf16*) carve(Mr * 2048);
  bf16*  rbuf   = (bf16*) carve(Mr * 2048);
  bf16*  gbuf   = (bf16*) carve(Mr * 2048);
  float* wdec   = (float*)carve(Mr * 4096);
  float* wkvst  = (float*)carve(Mr * 2048);
  float* outw   = wdec;   // chunk2 drains wcum reads (barrier) before overwriting
  bf16*  gated  = mixbuf; // mixbuf dead after decay-tanh GEMM

  // channel overlay for the 5 fused-mix outputs (all dead-by-consumer ordering):
  //   mix5[0]=mixbuf (w, consumed by decay tanh), mix5[1]=wdec[0:16M] (k),
  //   mix5[2]=wdec[16M:32M] (v), mix5[3]=wkvst (r), mix5[4]=xmx (g, xmx dead post-LoRA)
  MixP mp;
  mp.maa[0] = canon[2]; mp.maa[1] = canon[3]; mp.maa[2] = canon[4];
  mp.maa[3] = canon[5]; mp.maa[4] = canon[6];
  mp.dst[0] = mixbuf;
  mp.dst[1] = (bf16*)wdec;
  mp.dst[2] = (bf16*)wdec + Mr * 1024;
  mp.dst[3] = (bf16*)wkvst;
  mp.dst[4] = xmx;

  Proj4 pp;
  pp.A[0] = mp.dst[1]; pp.Bt[0] = WkT; pp.C[0] = kbuf;
  pp.A[1] = mp.dst[2]; pp.Bt[1] = WvT; pp.C[1] = vbuf;
  pp.A[2] = mp.dst[3]; pp.Bt[2] = WrT; pp.C[2] = rbuf;
  pp.A[3] = mp.dst[4]; pp.Bt[3] = WgT; pp.C[3] = gbuf;

  for(int b0 = 0; b0 < 4; b0 += nb){
    for(int t0 = 0; t0 < Tt; t0 += L){
      // 1. xmx, then xxx = tanh(xmx @ w1)
      k_prep<<<dim3(M * 4), 256, 0, stream>>>(xp, tmx, xmx, b0, t0, Llog2);
      gemm_mfma2<G2_TANH><<<dim3(2, M/128), 256, 0, stream>>>(
          xmx, W1T, xxx, 256, 160, 1024, nullptr);
      // 2. fused 5-channel mix (xmx dead; overwritten as mix5[4])
      gemm_mix<<<dim3(8, M/128, 5), 256, 0, stream>>>(
          xxx, W2T, xp, mp, b0, t0, Llog2);
      // 3. four projections in one launch
      gemm_proj4<<<dim3(8, M/128, 4), 256, 0, stream>>>(pp);
      // 4. decay chain (consumes mix5[0]; writes wdec over mix5[1,2] — dead)
      gemm_mfma2<G2_TANH><<<dim3(1, M/128), 256, 0, stream>>>(
          mixbuf, DW1T, ww1, 64, 64, 1024, nullptr);
      gemm_mfma2<G2_DECAY><<<dim3(8, M/128), 256, 0, stream>>>(
          ww1, DW2T, wdec, 1024, 1024, 64, tdec);
      // 5. chunked WKV
      int nloc = 1 << nlog2;
      k_cumsum<<<dim3(nb * nloc * 4), 256, 0, stream>>>(wdec, wse, nlog2);
      k_chunk1<<<dim3(nb * 16 * nloc), 256, 0, stream>>>(kbuf, vbuf, wdec, wkvst, nlog2);
      k_scan<<<dim3(nb * 16), 256, 0, stream>>>(wkvst, wse, st, b0, (t0 == 0) ? 1 : 0, nlog2);
      k_chunk2<<<dim3(nb * 16 * nloc), 256, 0, stream>>>(rbuf, kbuf, vbuf, wdec, wkvst, up, outw, nlog2);
      // 6. groupnorm + gate, output projection
      k_norm<<<dim3(M), 256, 0, stream>>>(outw, gbuf, lnwp, lnbp, gated);
      if(L == Tt){
        gemm_mfma<GEPI_OUT><<<dim3(8, M/128), 256, 0, stream>>>(gated, WoT, d_out, flag, b0 * Tt);
      } else {
        gemm_ep<EPI_OUTV><<<dim3(16, M/64), 256, 0, stream>>>(
            gated, 1024, canon[17], 1024, d_out, 1024, M, 1024, 1024,
            nullptr, nullptr, b0, t0, Llog2, flag);
      }
    }
  }
}